// Round 6
// baseline (1921.678 us; speedup 1.0000x reference)
//
#include <hip/hip_runtime.h>
#include <hip/hip_bf16.h>
#include <math.h>

// Problem constants
constexpr int B_ = 8;
constexpr int C_ = 512;
constexpr int M_ = 64;     // C/8
constexpr int N_ = 4096;   // H*W
constexpr float EPS_ = 1e-10f;
constexpr float PARAM_ = 10.0f;

// elus feature map: t>0 ? 10t+1 : exp(10t)
__device__ __forceinline__ float elus(float t) {
    return (t > 0.f) ? fmaf(PARAM_, t, 1.f) : expf(PARAM_ * t);
}

// ---------------------------------------------------------------------------
// Kernel 1: one feature GEMM: out[b][m][n] = elus(sum_k W[m,k]*in[b,k,n] + bias[m])
// Launched once per branch (Q, K1, K2, K3) with the right in/W/bias/out.
// ---------------------------------------------------------------------------
__global__ __launch_bounds__(256) void feat_gemm(
    const float* __restrict__ in, const float* __restrict__ W,
    const float* __restrict__ bias, float* __restrict__ out)
{
    const int n0 = blockIdx.x * 64;
    const int b = blockIdx.z;

    __shared__ float Ws[64][65];
    __shared__ float Xs[64][65];

    const int tid = threadIdx.x;
    const int tx = tid & 15, ty = tid >> 4;
    float acc[4][4] = {};

    const float* inb = in + (size_t)b * C_ * N_;
    for (int k0 = 0; k0 < C_; k0 += 64) {
        for (int l = tid; l < 64 * 64; l += 256) {
            int r = l >> 6, q = l & 63;
            Ws[r][q] = W[(size_t)r * C_ + k0 + q];
            Xs[r][q] = inb[(size_t)(k0 + r) * N_ + n0 + q];
        }
        __syncthreads();
        #pragma unroll 16
        for (int kk = 0; kk < 64; ++kk) {
            float a[4], bb[4];
            #pragma unroll
            for (int i = 0; i < 4; ++i) a[i] = Ws[ty * 4 + i][kk];
            #pragma unroll
            for (int j = 0; j < 4; ++j) bb[j] = Xs[kk][tx * 4 + j];
            #pragma unroll
            for (int i = 0; i < 4; ++i)
                #pragma unroll
                for (int j = 0; j < 4; ++j)
                    acc[i][j] = fmaf(a[i], bb[j], acc[i][j]);
        }
        __syncthreads();
    }

    float* outb = out + (size_t)b * M_ * N_;
    #pragma unroll
    for (int i = 0; i < 4; ++i) {
        int m = ty * 4 + i;
        float bi = bias[m];
        #pragma unroll
        for (int j = 0; j < 4; ++j) {
            int n = n0 + tx * 4 + j;
            outb[(size_t)m * N_ + n] = elus(acc[i][j] + bi);
        }
    }
}

// ---------------------------------------------------------------------------
// Kernel 2: Ksum[b][br][m] = sum_n Kbuf[b][m][n]   (br passed as arg)
// ---------------------------------------------------------------------------
__global__ __launch_bounds__(256) void ksum_kernel(const float* __restrict__ Kbuf,
                                                   float* __restrict__ Ksum, int br)
{
    const int m = blockIdx.x;   // 0..63
    const int b = blockIdx.z;   // 0..7
    const float* row = Kbuf + ((size_t)b * M_ + m) * N_;
    float s = 0.f;
    for (int n = threadIdx.x; n < N_; n += 256) s += row[n];
    __shared__ float red[256];
    red[threadIdx.x] = s;
    __syncthreads();
    for (int off = 128; off > 0; off >>= 1) {
        if (threadIdx.x < off) red[threadIdx.x] += red[threadIdx.x + off];
        __syncthreads();
    }
    if (threadIdx.x == 0) Ksum[((size_t)b * 3 + br) * M_ + m] = red[0];
}

// ---------------------------------------------------------------------------
// Kernel 3: KX[b][br][m][c] = sum_n Kbuf[b][m][n] * x[b][c][n]
// Tile: 64 m x 32 c, loop n in chunks of 64.
// ---------------------------------------------------------------------------
__global__ __launch_bounds__(256) void kx_kernel(const float* __restrict__ Kbuf,
                                                 const float* __restrict__ x,
                                                 float* __restrict__ KX, int br)
{
    const int c0 = blockIdx.x * 32;
    const int b = blockIdx.z;

    __shared__ float Ks[64][65];
    __shared__ float Xs[32][65];

    const int tid = threadIdx.x;
    const int tx = tid & 31;   // c within tile
    const int ty = tid >> 5;   // 0..7 -> 8 m rows each
    float acc[8] = {};

    const float* kb = Kbuf + (size_t)b * M_ * N_;
    const float* xb = x + (size_t)b * C_ * N_;

    for (int n0 = 0; n0 < N_; n0 += 64) {
        for (int l = tid; l < 64 * 64; l += 256) {
            int m = l >> 6, nn = l & 63;
            Ks[m][nn] = kb[(size_t)m * N_ + n0 + nn];
        }
        for (int l = tid; l < 32 * 64; l += 256) {
            int cc = l >> 6, nn = l & 63;
            Xs[cc][nn] = xb[(size_t)(c0 + cc) * N_ + n0 + nn];
        }
        __syncthreads();
        #pragma unroll 8
        for (int nn = 0; nn < 64; ++nn) {
            float xv = Xs[tx][nn];
            #pragma unroll
            for (int i = 0; i < 8; ++i)
                acc[i] = fmaf(Ks[ty * 8 + i][nn], xv, acc[i]);
        }
        __syncthreads();
    }
    #pragma unroll
    for (int i = 0; i < 8; ++i) {
        int m = ty * 8 + i;
        KX[(((size_t)b * 3 + br) * M_ + m) * C_ + c0 + tx] = acc[i];
    }
}

// ---------------------------------------------------------------------------
// Kernel 4: WlWv[c][k] = sum_p Wl[c][p] * Wv[p][k]   (batch-independent)
// ---------------------------------------------------------------------------
__global__ __launch_bounds__(256) void wlwv_kernel(const float* __restrict__ Wl,
                                                   const float* __restrict__ Wv,
                                                   float* __restrict__ WlWv)
{
    const int k0 = blockIdx.x * 64;
    const int c0 = blockIdx.y * 64;
    __shared__ float As[64][65];
    __shared__ float Bs[64][65];
    const int tid = threadIdx.x;
    const int tx = tid & 15, ty = tid >> 4;
    float acc[4][4] = {};

    for (int p0 = 0; p0 < C_; p0 += 64) {
        for (int l = tid; l < 64 * 64; l += 256) {
            int r = l >> 6, q = l & 63;
            As[r][q] = Wl[(size_t)(c0 + r) * C_ + p0 + q];
            Bs[r][q] = Wv[(size_t)(p0 + r) * C_ + k0 + q];
        }
        __syncthreads();
        #pragma unroll 16
        for (int p = 0; p < 64; ++p) {
            float a[4], bb[4];
            #pragma unroll
            for (int i = 0; i < 4; ++i) a[i] = As[ty * 4 + i][p];
            #pragma unroll
            for (int j = 0; j < 4; ++j) bb[j] = Bs[p][tx * 4 + j];
            #pragma unroll
            for (int i = 0; i < 4; ++i)
                #pragma unroll
                for (int j = 0; j < 4; ++j)
                    acc[i][j] = fmaf(a[i], bb[j], acc[i][j]);
        }
        __syncthreads();
    }
    #pragma unroll
    for (int i = 0; i < 4; ++i)
        #pragma unroll
        for (int j = 0; j < 4; ++j)
            WlWv[(size_t)(c0 + ty * 4 + i) * C_ + k0 + tx * 4 + j] = acc[i][j];
}

// Wlbv[c] = sum_p Wl[c][p] * bv[p]
__global__ __launch_bounds__(256) void wlbv_kernel(const float* __restrict__ Wl,
                                                   const float* __restrict__ bv,
                                                   float* __restrict__ Wlbv)
{
    int c = blockIdx.x * 256 + threadIdx.x;
    if (c < C_) {
        float s = 0.f;
        for (int p = 0; p < C_; ++p) s = fmaf(Wl[(size_t)c * C_ + p], bv[p], s);
        Wlbv[c] = s;
    }
}

// ---------------------------------------------------------------------------
// Kernel 5: Wf[b][br][c][m] = sum_k WlWv[c][k]*KX[b][br][m][k] + Ksum[b][br][m]*Wlbv[c]
// ---------------------------------------------------------------------------
__global__ __launch_bounds__(256) void wfused_kernel(const float* __restrict__ WlWv,
                                                     const float* __restrict__ KX,
                                                     const float* __restrict__ Ksum,
                                                     const float* __restrict__ Wlbv,
                                                     float* __restrict__ Wf)
{
    const int c0 = blockIdx.x * 64;
    const int br = blockIdx.y;
    const int b = blockIdx.z;

    __shared__ float As[64][65];   // WlWv[c][k] chunk
    __shared__ float Bs[64][65];   // KX^T: Bs[kk][m]
    const int tid = threadIdx.x;
    const int tx = tid & 15, ty = tid >> 4;
    float acc[4][4] = {};

    const float* kxb = KX + ((size_t)b * 3 + br) * M_ * C_;  // [m][k]
    for (int k0 = 0; k0 < C_; k0 += 64) {
        for (int l = tid; l < 64 * 64; l += 256) {
            int r = l >> 6, q = l & 63;
            As[r][q] = WlWv[(size_t)(c0 + r) * C_ + k0 + q];
            Bs[q][r] = kxb[(size_t)r * C_ + k0 + q];   // r = m, q = kk
        }
        __syncthreads();
        #pragma unroll 16
        for (int kk = 0; kk < 64; ++kk) {
            float a[4], bb[4];
            #pragma unroll
            for (int i = 0; i < 4; ++i) a[i] = As[ty * 4 + i][kk];
            #pragma unroll
            for (int j = 0; j < 4; ++j) bb[j] = Bs[kk][tx * 4 + j];
            #pragma unroll
            for (int i = 0; i < 4; ++i)
                #pragma unroll
                for (int j = 0; j < 4; ++j)
                    acc[i][j] = fmaf(a[i], bb[j], acc[i][j]);
        }
        __syncthreads();
    }
    const float* ks = Ksum + ((size_t)b * 3 + br) * M_;
    #pragma unroll
    for (int i = 0; i < 4; ++i) {
        int c = c0 + ty * 4 + i;
        float wb = Wlbv[c];
        #pragma unroll
        for (int j = 0; j < 4; ++j) {
            int m = tx * 4 + j;
            Wf[(((size_t)b * 3 + br) * C_ + c) * M_ + m] = acc[i][j] + ks[m] * wb;
        }
    }
}

// ---------------------------------------------------------------------------
// Kernel 6: out[b][c][n] = x[b][c][n] + gamma * ( bl[c] +
//      sum_br norm_br[n] * sum_m Wf[b][br][c][m] * Q[b][m][n] )
// norm_br[n] = 1 / sum_m Q[b][m][n] * (Ksum[b][br][m] + EPS)
// ---------------------------------------------------------------------------
__global__ __launch_bounds__(256) void final_kernel(
    const float* __restrict__ Q, const float* __restrict__ Wf,
    const float* __restrict__ Ksum, const float* __restrict__ x,
    const float* __restrict__ bl, const float* __restrict__ gamma,
    float* __restrict__ out)
{
    const int n0 = blockIdx.x * 64;
    const int c0 = blockIdx.y * 64;
    const int b = blockIdx.z;

    __shared__ float Qs[64][65];     // raw Q tile [m][n]
    __shared__ float Ws[64][65];     // Wf tile [c][m]
    __shared__ float norms[3][64];
    __shared__ float kse[3][64];

    const int tid = threadIdx.x;
    const int tx = tid & 15, ty = tid >> 4;

    const float* qb = Q + (size_t)b * M_ * N_;
    for (int l = tid; l < 64 * 64; l += 256) {
        int m = l >> 6, nn = l & 63;
        Qs[m][nn] = qb[(size_t)m * N_ + n0 + nn];
    }
    if (tid < 3 * 64) {
        int br = tid >> 6, m = tid & 63;
        kse[br][m] = Ksum[((size_t)b * 3 + br) * M_ + m] + EPS_;
    }
    __syncthreads();
    if (tid < 192) {
        int br = tid >> 6, nn = tid & 63;
        float s = 0.f;
        #pragma unroll 16
        for (int m = 0; m < 64; ++m) s = fmaf(Qs[m][nn], kse[br][m], s);
        norms[br][nn] = 1.0f / s;
    }

    float acc[4][4] = {};
    for (int br = 0; br < 3; ++br) {
        __syncthreads();
        for (int l = tid; l < 64 * 64; l += 256) {
            int cc = l >> 6, m = l & 63;
            Ws[cc][m] = Wf[(((size_t)b * 3 + br) * C_ + c0 + cc) * M_ + m];
        }
        __syncthreads();
        float S[4][4] = {};
        #pragma unroll 16
        for (int m = 0; m < 64; ++m) {
            float a[4], bb[4];
            #pragma unroll
            for (int i = 0; i < 4; ++i) a[i] = Ws[ty * 4 + i][m];
            #pragma unroll
            for (int j = 0; j < 4; ++j) bb[j] = Qs[m][tx * 4 + j];
            #pragma unroll
            for (int i = 0; i < 4; ++i)
                #pragma unroll
                for (int j = 0; j < 4; ++j)
                    S[i][j] = fmaf(a[i], bb[j], S[i][j]);
        }
        #pragma unroll
        for (int j = 0; j < 4; ++j) {
            float nf = norms[br][tx * 4 + j];
            #pragma unroll
            for (int i = 0; i < 4; ++i) acc[i][j] = fmaf(nf, S[i][j], acc[i][j]);
        }
    }

    const float g = gamma[0];
    const float* xb = x + (size_t)b * C_ * N_;
    float* ob = out + (size_t)b * C_ * N_;
    #pragma unroll
    for (int i = 0; i < 4; ++i) {
        int c = c0 + ty * 4 + i;
        float blc = bl[c];
        #pragma unroll
        for (int j = 0; j < 4; ++j) {
            int n = n0 + tx * 4 + j;
            ob[(size_t)c * N_ + n] = fmaf(g, acc[i][j] + blc, xb[(size_t)c * N_ + n]);
        }
    }
}

// ---------------------------------------------------------------------------
extern "C" void kernel_launch(void* const* d_in, const int* in_sizes, int n_in,
                              void* d_out, int out_size, void* d_ws, size_t ws_size,
                              hipStream_t stream)
{
    const float* x   = (const float*)d_in[0];
    const float* y   = (const float*)d_in[1];
    const float* z   = (const float*)d_in[2];
    const float* Wq  = (const float*)d_in[3];
    const float* bq  = (const float*)d_in[4];
    const float* Wk1 = (const float*)d_in[5];
    const float* bk1 = (const float*)d_in[6];
    const float* Wk2 = (const float*)d_in[7];
    const float* bk2 = (const float*)d_in[8];
    const float* Wk3 = (const float*)d_in[9];
    const float* bk3 = (const float*)d_in[10];
    const float* Wv  = (const float*)d_in[11];
    const float* bv  = (const float*)d_in[12];
    const float* Wl  = (const float*)d_in[13];
    const float* bl  = (const float*)d_in[14];
    const float* gamma = (const float*)d_in[15];
    float* out = (float*)d_out;

    // workspace layout (floats) — total 6,031,360 floats = 23.0 MB
    // (K branches are sequenced through ONE shared Kbuf to keep the footprint
    //  small; previous 39 MB layout risked running past ws_size and corrupting
    //  adjacent input buffers, which showed up as post-timing divergence.)
    float* ws = (float*)d_ws;
    const size_t QSZ  = (size_t)B_ * M_ * N_;        // 2,097,152
    float* Q    = ws;                                 // [B][M][N]
    float* Kbuf = Q + QSZ;                            // [B][M][N] (reused per branch)
    float* KX   = Kbuf + QSZ;                         // [B][3][M][C]
    float* Ksum = KX + (size_t)B_ * 3 * M_ * C_;      // [B][3][M]
    float* WlWv = Ksum + (size_t)B_ * 3 * M_;         // [C][C]
    float* Wlbv = WlWv + (size_t)C_ * C_;             // [C]
    float* Wf   = Wlbv + C_;                          // [B][3][C][M]

    dim3 blk(256);
    const dim3 featGrid(N_ / 64, 1, B_);

    // Q features
    feat_gemm<<<featGrid, blk, 0, stream>>>(x, Wq, bq, Q);

    // K branches, sequenced through Kbuf
    const float* kin[3]  = { x, y, z };
    const float* kW[3]   = { Wk1, Wk2, Wk3 };
    const float* kb_[3]  = { bk1, bk2, bk3 };
    for (int br = 0; br < 3; ++br) {
        feat_gemm<<<featGrid, blk, 0, stream>>>(kin[br], kW[br], kb_[br], Kbuf);
        ksum_kernel<<<dim3(M_, 1, B_), blk, 0, stream>>>(Kbuf, Ksum, br);
        kx_kernel<<<dim3(C_ / 32, 1, B_), blk, 0, stream>>>(Kbuf, x, KX, br);
    }

    // batch-independent fused weights
    wlwv_kernel<<<dim3(C_ / 64, C_ / 64), blk, 0, stream>>>(Wl, Wv, WlWv);
    wlbv_kernel<<<dim3((C_ + 255) / 256), blk, 0, stream>>>(Wl, bv, Wlbv);
    // per-batch fused weights
    wfused_kernel<<<dim3(C_ / 64, 3, B_), blk, 0, stream>>>(WlWv, KX, Ksum, Wlbv, Wf);
    // final: norms + GEMM + bias + residual
    final_kernel<<<dim3(N_ / 64, C_ / 64, B_), blk, 0, stream>>>(
        Q, Wf, Ksum, x, bl, gamma, out);
}

// Round 7
// 899.693 us; speedup vs baseline: 2.1359x; 2.1359x over previous
//
#include <hip/hip_runtime.h>
#include <hip/hip_bf16.h>
#include <math.h>

// Problem constants
constexpr int B_ = 8;
constexpr int C_ = 512;
constexpr int M_ = 64;     // C/8
constexpr int N_ = 4096;   // H*W
constexpr int NCHUNK_ = 4; // split-N factor for kx
constexpr float EPS_ = 1e-10f;
constexpr float PARAM_ = 10.0f;

// elus feature map: t>0 ? 10t+1 : exp(10t)
__device__ __forceinline__ float elus(float t) {
    return (t > 0.f) ? fmaf(PARAM_, t, 1.f) : expf(PARAM_ * t);
}

// ---------------------------------------------------------------------------
// Kernel 1: one feature GEMM: out[b][m][n] = elus(sum_k W[m,k]*in[b,k,n] + bias[m])
// Launched once per branch (Q, K1, K2, K3) with the right in/W/bias/out.
// ---------------------------------------------------------------------------
__global__ __launch_bounds__(256) void feat_gemm(
    const float* __restrict__ in, const float* __restrict__ W,
    const float* __restrict__ bias, float* __restrict__ out)
{
    const int n0 = blockIdx.x * 64;
    const int b = blockIdx.z;

    __shared__ float Ws[64][65];
    __shared__ float Xs[64][65];

    const int tid = threadIdx.x;
    const int tx = tid & 15, ty = tid >> 4;
    float acc[4][4] = {};

    const float* inb = in + (size_t)b * C_ * N_;
    for (int k0 = 0; k0 < C_; k0 += 64) {
        for (int l = tid; l < 64 * 64; l += 256) {
            int r = l >> 6, q = l & 63;
            Ws[r][q] = W[(size_t)r * C_ + k0 + q];
            Xs[r][q] = inb[(size_t)(k0 + r) * N_ + n0 + q];
        }
        __syncthreads();
        #pragma unroll 16
        for (int kk = 0; kk < 64; ++kk) {
            float a[4], bb[4];
            #pragma unroll
            for (int i = 0; i < 4; ++i) a[i] = Ws[ty * 4 + i][kk];
            #pragma unroll
            for (int j = 0; j < 4; ++j) bb[j] = Xs[kk][tx * 4 + j];
            #pragma unroll
            for (int i = 0; i < 4; ++i)
                #pragma unroll
                for (int j = 0; j < 4; ++j)
                    acc[i][j] = fmaf(a[i], bb[j], acc[i][j]);
        }
        __syncthreads();
    }

    float* outb = out + (size_t)b * M_ * N_;
    #pragma unroll
    for (int i = 0; i < 4; ++i) {
        int m = ty * 4 + i;
        float bi = bias[m];
        #pragma unroll
        for (int j = 0; j < 4; ++j) {
            int n = n0 + tx * 4 + j;
            outb[(size_t)m * N_ + n] = elus(acc[i][j] + bi);
        }
    }
}

// ---------------------------------------------------------------------------
// Kernel 2: Ksum[b][br][m] = sum_n Kbuf[b][m][n]   (br passed as arg)
// ---------------------------------------------------------------------------
__global__ __launch_bounds__(256) void ksum_kernel(const float* __restrict__ Kbuf,
                                                   float* __restrict__ Ksum, int br)
{
    const int m = blockIdx.x;   // 0..63
    const int b = blockIdx.z;   // 0..7
    const float* row = Kbuf + ((size_t)b * M_ + m) * N_;
    float s = 0.f;
    for (int n = threadIdx.x; n < N_; n += 256) s += row[n];
    __shared__ float red[256];
    red[threadIdx.x] = s;
    __syncthreads();
    for (int off = 128; off > 0; off >>= 1) {
        if (threadIdx.x < off) red[threadIdx.x] += red[threadIdx.x + off];
        __syncthreads();
    }
    if (threadIdx.x == 0) Ksum[((size_t)b * 3 + br) * M_ + m] = red[0];
}

// ---------------------------------------------------------------------------
// Kernel 3a: split-N partial KX.
// KXpart[nc][b][m][c] = sum_{n in chunk nc} Kbuf[b][m][n] * x[b][c][n]
// Grid: (C/32, NCHUNK, B) = (16, 4, 8) = 512 blocks (vs 128 before — the old
// version was latency-bound at 0.5 blocks/CU, 5.9% occupancy, 8% VALUBusy).
// ---------------------------------------------------------------------------
__global__ __launch_bounds__(256) void kx_split_kernel(const float* __restrict__ Kbuf,
                                                       const float* __restrict__ x,
                                                       float* __restrict__ KXpart)
{
    const int c0 = blockIdx.x * 32;
    const int nc = blockIdx.y;
    const int b = blockIdx.z;
    const int nbeg = nc * (N_ / NCHUNK_);
    const int nend = nbeg + (N_ / NCHUNK_);

    __shared__ float Ks[64][65];
    __shared__ float Xs[32][65];

    const int tid = threadIdx.x;
    const int tx = tid & 31;   // c within tile
    const int ty = tid >> 5;   // 0..7 -> 8 m rows each
    float acc[8] = {};

    const float* kb = Kbuf + (size_t)b * M_ * N_;
    const float* xb = x + (size_t)b * C_ * N_;

    for (int n0 = nbeg; n0 < nend; n0 += 64) {
        for (int l = tid; l < 64 * 64; l += 256) {
            int m = l >> 6, nn = l & 63;
            Ks[m][nn] = kb[(size_t)m * N_ + n0 + nn];
        }
        for (int l = tid; l < 32 * 64; l += 256) {
            int cc = l >> 6, nn = l & 63;
            Xs[cc][nn] = xb[(size_t)(c0 + cc) * N_ + n0 + nn];
        }
        __syncthreads();
        #pragma unroll 8
        for (int nn = 0; nn < 64; ++nn) {
            float xv = Xs[tx][nn];
            #pragma unroll
            for (int i = 0; i < 8; ++i)
                acc[i] = fmaf(Ks[ty * 8 + i][nn], xv, acc[i]);
        }
        __syncthreads();
    }
    #pragma unroll
    for (int i = 0; i < 8; ++i) {
        int m = ty * 8 + i;
        KXpart[(((size_t)nc * B_ + b) * M_ + m) * C_ + c0 + tx] = acc[i];
    }
}

// ---------------------------------------------------------------------------
// Kernel 3b: reduce partials (fixed order — deterministic).
// KX[b][br][m][c] = sum_nc KXpart[nc][b][m][c]
// ---------------------------------------------------------------------------
__global__ __launch_bounds__(256) void kx_reduce_kernel(const float* __restrict__ KXpart,
                                                        float* __restrict__ KX, int br)
{
    const size_t BMC = (size_t)B_ * M_ * C_;
    size_t i = (size_t)blockIdx.x * 256 + threadIdx.x;
    if (i >= BMC) return;
    float s = 0.f;
    #pragma unroll
    for (int nc = 0; nc < NCHUNK_; ++nc) s += KXpart[nc * BMC + i];
    size_t b = i / ((size_t)M_ * C_);
    size_t rem = i - b * (size_t)M_ * C_;
    KX[((size_t)b * 3 + br) * M_ * C_ + rem] = s;
}

// ---------------------------------------------------------------------------
// Kernel 4: WlWv[c][k] = sum_p Wl[c][p] * Wv[p][k]   (batch-independent)
// ---------------------------------------------------------------------------
__global__ __launch_bounds__(256) void wlwv_kernel(const float* __restrict__ Wl,
                                                   const float* __restrict__ Wv,
                                                   float* __restrict__ WlWv)
{
    const int k0 = blockIdx.x * 64;
    const int c0 = blockIdx.y * 64;
    __shared__ float As[64][65];
    __shared__ float Bs[64][65];
    const int tid = threadIdx.x;
    const int tx = tid & 15, ty = tid >> 4;
    float acc[4][4] = {};

    for (int p0 = 0; p0 < C_; p0 += 64) {
        for (int l = tid; l < 64 * 64; l += 256) {
            int r = l >> 6, q = l & 63;
            As[r][q] = Wl[(size_t)(c0 + r) * C_ + p0 + q];
            Bs[r][q] = Wv[(size_t)(p0 + r) * C_ + k0 + q];
        }
        __syncthreads();
        #pragma unroll 16
        for (int p = 0; p < 64; ++p) {
            float a[4], bb[4];
            #pragma unroll
            for (int i = 0; i < 4; ++i) a[i] = As[ty * 4 + i][p];
            #pragma unroll
            for (int j = 0; j < 4; ++j) bb[j] = Bs[p][tx * 4 + j];
            #pragma unroll
            for (int i = 0; i < 4; ++i)
                #pragma unroll
                for (int j = 0; j < 4; ++j)
                    acc[i][j] = fmaf(a[i], bb[j], acc[i][j]);
        }
        __syncthreads();
    }
    #pragma unroll
    for (int i = 0; i < 4; ++i)
        #pragma unroll
        for (int j = 0; j < 4; ++j)
            WlWv[(size_t)(c0 + ty * 4 + i) * C_ + k0 + tx * 4 + j] = acc[i][j];
}

// Wlbv[c] = sum_p Wl[c][p] * bv[p]
__global__ __launch_bounds__(256) void wlbv_kernel(const float* __restrict__ Wl,
                                                   const float* __restrict__ bv,
                                                   float* __restrict__ Wlbv)
{
    int c = blockIdx.x * 256 + threadIdx.x;
    if (c < C_) {
        float s = 0.f;
        for (int p = 0; p < C_; ++p) s = fmaf(Wl[(size_t)c * C_ + p], bv[p], s);
        Wlbv[c] = s;
    }
}

// ---------------------------------------------------------------------------
// Kernel 5: Wf[b][br][c][m] = sum_k WlWv[c][k]*KX[b][br][m][k] + Ksum[b][br][m]*Wlbv[c]
// ---------------------------------------------------------------------------
__global__ __launch_bounds__(256) void wfused_kernel(const float* __restrict__ WlWv,
                                                     const float* __restrict__ KX,
                                                     const float* __restrict__ Ksum,
                                                     const float* __restrict__ Wlbv,
                                                     float* __restrict__ Wf)
{
    const int c0 = blockIdx.x * 64;
    const int br = blockIdx.y;
    const int b = blockIdx.z;

    __shared__ float As[64][65];   // WlWv[c][k] chunk
    __shared__ float Bs[64][65];   // KX^T: Bs[kk][m]
    const int tid = threadIdx.x;
    const int tx = tid & 15, ty = tid >> 4;
    float acc[4][4] = {};

    const float* kxb = KX + ((size_t)b * 3 + br) * M_ * C_;  // [m][k]
    for (int k0 = 0; k0 < C_; k0 += 64) {
        for (int l = tid; l < 64 * 64; l += 256) {
            int r = l >> 6, q = l & 63;
            As[r][q] = WlWv[(size_t)(c0 + r) * C_ + k0 + q];
            Bs[q][r] = kxb[(size_t)r * C_ + k0 + q];   // r = m, q = kk
        }
        __syncthreads();
        #pragma unroll 16
        for (int kk = 0; kk < 64; ++kk) {
            float a[4], bb[4];
            #pragma unroll
            for (int i = 0; i < 4; ++i) a[i] = As[ty * 4 + i][kk];
            #pragma unroll
            for (int j = 0; j < 4; ++j) bb[j] = Bs[kk][tx * 4 + j];
            #pragma unroll
            for (int i = 0; i < 4; ++i)
                #pragma unroll
                for (int j = 0; j < 4; ++j)
                    acc[i][j] = fmaf(a[i], bb[j], acc[i][j]);
        }
        __syncthreads();
    }
    const float* ks = Ksum + ((size_t)b * 3 + br) * M_;
    #pragma unroll
    for (int i = 0; i < 4; ++i) {
        int c = c0 + ty * 4 + i;
        float wb = Wlbv[c];
        #pragma unroll
        for (int j = 0; j < 4; ++j) {
            int m = tx * 4 + j;
            Wf[(((size_t)b * 3 + br) * C_ + c) * M_ + m] = acc[i][j] + ks[m] * wb;
        }
    }
}

// ---------------------------------------------------------------------------
// Kernel 6: out[b][c][n] = x[b][c][n] + gamma * ( bl[c] +
//      sum_br norm_br[n] * sum_m Wf[b][br][c][m] * Q[b][m][n] )
// norm_br[n] = 1 / sum_m Q[b][m][n] * (Ksum[b][br][m] + EPS)
// ---------------------------------------------------------------------------
__global__ __launch_bounds__(256) void final_kernel(
    const float* __restrict__ Q, const float* __restrict__ Wf,
    const float* __restrict__ Ksum, const float* __restrict__ x,
    const float* __restrict__ bl, const float* __restrict__ gamma,
    float* __restrict__ out)
{
    const int n0 = blockIdx.x * 64;
    const int c0 = blockIdx.y * 64;
    const int b = blockIdx.z;

    __shared__ float Qs[64][65];     // raw Q tile [m][n]
    __shared__ float Ws[64][65];     // Wf tile [c][m]
    __shared__ float norms[3][64];
    __shared__ float kse[3][64];

    const int tid = threadIdx.x;
    const int tx = tid & 15, ty = tid >> 4;

    const float* qb = Q + (size_t)b * M_ * N_;
    for (int l = tid; l < 64 * 64; l += 256) {
        int m = l >> 6, nn = l & 63;
        Qs[m][nn] = qb[(size_t)m * N_ + n0 + nn];
    }
    if (tid < 3 * 64) {
        int br = tid >> 6, m = tid & 63;
        kse[br][m] = Ksum[((size_t)b * 3 + br) * M_ + m] + EPS_;
    }
    __syncthreads();
    if (tid < 192) {
        int br = tid >> 6, nn = tid & 63;
        float s = 0.f;
        #pragma unroll 16
        for (int m = 0; m < 64; ++m) s = fmaf(Qs[m][nn], kse[br][m], s);
        norms[br][nn] = 1.0f / s;
    }

    float acc[4][4] = {};
    for (int br = 0; br < 3; ++br) {
        __syncthreads();
        for (int l = tid; l < 64 * 64; l += 256) {
            int cc = l >> 6, m = l & 63;
            Ws[cc][m] = Wf[(((size_t)b * 3 + br) * C_ + c0 + cc) * M_ + m];
        }
        __syncthreads();
        float S[4][4] = {};
        #pragma unroll 16
        for (int m = 0; m < 64; ++m) {
            float a[4], bb[4];
            #pragma unroll
            for (int i = 0; i < 4; ++i) a[i] = Ws[ty * 4 + i][m];
            #pragma unroll
            for (int j = 0; j < 4; ++j) bb[j] = Qs[m][tx * 4 + j];
            #pragma unroll
            for (int i = 0; i < 4; ++i)
                #pragma unroll
                for (int j = 0; j < 4; ++j)
                    S[i][j] = fmaf(a[i], bb[j], S[i][j]);
        }
        #pragma unroll
        for (int j = 0; j < 4; ++j) {
            float nf = norms[br][tx * 4 + j];
            #pragma unroll
            for (int i = 0; i < 4; ++i) acc[i][j] = fmaf(nf, S[i][j], acc[i][j]);
        }
    }

    const float g = gamma[0];
    const float* xb = x + (size_t)b * C_ * N_;
    float* ob = out + (size_t)b * C_ * N_;
    #pragma unroll
    for (int i = 0; i < 4; ++i) {
        int c = c0 + ty * 4 + i;
        float blc = bl[c];
        #pragma unroll
        for (int j = 0; j < 4; ++j) {
            int n = n0 + tx * 4 + j;
            ob[(size_t)c * N_ + n] = fmaf(g, acc[i][j] + blc, xb[(size_t)c * N_ + n]);
        }
    }
}

// ---------------------------------------------------------------------------
extern "C" void kernel_launch(void* const* d_in, const int* in_sizes, int n_in,
                              void* d_out, int out_size, void* d_ws, size_t ws_size,
                              hipStream_t stream)
{
    const float* x   = (const float*)d_in[0];
    const float* y   = (const float*)d_in[1];
    const float* z   = (const float*)d_in[2];
    const float* Wq  = (const float*)d_in[3];
    const float* bq  = (const float*)d_in[4];
    const float* Wk1 = (const float*)d_in[5];
    const float* bk1 = (const float*)d_in[6];
    const float* Wk2 = (const float*)d_in[7];
    const float* bk2 = (const float*)d_in[8];
    const float* Wk3 = (const float*)d_in[9];
    const float* bk3 = (const float*)d_in[10];
    const float* Wv  = (const float*)d_in[11];
    const float* bv  = (const float*)d_in[12];
    const float* Wl  = (const float*)d_in[13];
    const float* bl  = (const float*)d_in[14];
    const float* gamma = (const float*)d_in[15];
    float* out = (float*)d_out;

    // workspace layout (floats) — total 6,293,504 floats = 25.2 MB.
    // KXpart (4 MB, used only during the K-branch loop) is aliased with Wf
    // (3 MB, written only afterwards by wfused) via a shared max-size slot.
    float* ws = (float*)d_ws;
    const size_t QSZ  = (size_t)B_ * M_ * N_;        // 2,097,152
    const size_t BMC  = (size_t)B_ * M_ * C_;        //   262,144
    float* Q    = ws;                                 // [B][M][N]
    float* Kbuf = Q + QSZ;                            // [B][M][N] (reused per branch)
    float* KX   = Kbuf + QSZ;                         // [B][3][M][C]
    float* Ksum = KX + 3 * BMC;                       // [B][3][M]
    float* WlWv = Ksum + (size_t)B_ * 3 * M_;         // [C][C]
    float* Wlbv = WlWv + (size_t)C_ * C_;             // [C]
    float* KXpart = Wlbv + C_;                        // [NCHUNK][B][M][C]  (4 MB)
    float* Wf   = KXpart;                             // [B][3][C][M]       (3 MB, aliased)

    dim3 blk(256);
    const dim3 featGrid(N_ / 64, 1, B_);

    // Q features
    feat_gemm<<<featGrid, blk, 0, stream>>>(x, Wq, bq, Q);

    // K branches, sequenced through Kbuf
    const float* kin[3]  = { x, y, z };
    const float* kW[3]   = { Wk1, Wk2, Wk3 };
    const float* kb_[3]  = { bk1, bk2, bk3 };
    for (int br = 0; br < 3; ++br) {
        feat_gemm<<<featGrid, blk, 0, stream>>>(kin[br], kW[br], kb_[br], Kbuf);
        ksum_kernel<<<dim3(M_, 1, B_), blk, 0, stream>>>(Kbuf, Ksum, br);
        kx_split_kernel<<<dim3(C_ / 32, NCHUNK_, B_), blk, 0, stream>>>(Kbuf, x, KXpart);
        kx_reduce_kernel<<<dim3((BMC + 255) / 256), blk, 0, stream>>>(KXpart, KX, br);
    }

    // batch-independent fused weights
    wlwv_kernel<<<dim3(C_ / 64, C_ / 64), blk, 0, stream>>>(Wl, Wv, WlWv);
    wlbv_kernel<<<dim3((C_ + 255) / 256), blk, 0, stream>>>(Wl, bv, Wlbv);
    // per-batch fused weights (reads KX/Ksum; writes Wf — KXpart no longer needed)
    wfused_kernel<<<dim3(C_ / 64, 3, B_), blk, 0, stream>>>(WlWv, KX, Ksum, Wlbv, Wf);
    // final: norms + GEMM + bias + residual
    final_kernel<<<dim3(N_ / 64, C_ / 64, B_), blk, 0, stream>>>(
        Q, Wf, Ksum, x, bl, gamma, out);
}

// Round 8
// 529.620 us; speedup vs baseline: 3.6284x; 1.6988x over previous
//
#include <hip/hip_runtime.h>
#include <hip/hip_bf16.h>
#include <math.h>

// Problem constants
constexpr int B_ = 8;
constexpr int C_ = 512;
constexpr int M_ = 64;     // C/8
constexpr int N_ = 4096;   // H*W
constexpr int NCHUNK_ = 4; // split-N factor for kx
constexpr float EPS_ = 1e-10f;
constexpr float PARAM_ = 10.0f;

typedef __attribute__((ext_vector_type(4))) float f32x4;
typedef __attribute__((ext_vector_type(8))) short bf16x8;   // 8 bf16 in 4 VGPRs

// elus feature map: t>0 ? 10t+1 : exp(10t)
__device__ __forceinline__ float elus(float t) {
    return (t > 0.f) ? fmaf(PARAM_, t, 1.f) : expf(PARAM_ * t);
}

// fp32 -> bf16 round-to-nearest-even (finite inputs only)
__device__ __forceinline__ short f2bf(float f) {
    unsigned u = __builtin_bit_cast(unsigned, f);
    u += 0x7FFFu + ((u >> 16) & 1u);
    return (short)(u >> 16);
}

// ---------------------------------------------------------------------------
// Kernel 1: one feature GEMM: out[b][m][n] = elus(sum_k W[m,k]*in[b,k,n] + bias[m])
// ---------------------------------------------------------------------------
__global__ __launch_bounds__(256) void feat_gemm(
    const float* __restrict__ in, const float* __restrict__ W,
    const float* __restrict__ bias, float* __restrict__ out)
{
    const int n0 = blockIdx.x * 64;
    const int b = blockIdx.z;

    __shared__ float Ws[64][65];
    __shared__ float Xs[64][65];

    const int tid = threadIdx.x;
    const int tx = tid & 15, ty = tid >> 4;
    float acc[4][4] = {};

    const float* inb = in + (size_t)b * C_ * N_;
    for (int k0 = 0; k0 < C_; k0 += 64) {
        for (int l = tid; l < 64 * 64; l += 256) {
            int r = l >> 6, q = l & 63;
            Ws[r][q] = W[(size_t)r * C_ + k0 + q];
            Xs[r][q] = inb[(size_t)(k0 + r) * N_ + n0 + q];
        }
        __syncthreads();
        #pragma unroll 16
        for (int kk = 0; kk < 64; ++kk) {
            float a[4], bb[4];
            #pragma unroll
            for (int i = 0; i < 4; ++i) a[i] = Ws[ty * 4 + i][kk];
            #pragma unroll
            for (int j = 0; j < 4; ++j) bb[j] = Xs[kk][tx * 4 + j];
            #pragma unroll
            for (int i = 0; i < 4; ++i)
                #pragma unroll
                for (int j = 0; j < 4; ++j)
                    acc[i][j] = fmaf(a[i], bb[j], acc[i][j]);
        }
        __syncthreads();
    }

    float* outb = out + (size_t)b * M_ * N_;
    #pragma unroll
    for (int i = 0; i < 4; ++i) {
        int m = ty * 4 + i;
        float bi = bias[m];
        #pragma unroll
        for (int j = 0; j < 4; ++j) {
            int n = n0 + tx * 4 + j;
            outb[(size_t)m * N_ + n] = elus(acc[i][j] + bi);
        }
    }
}

// ---------------------------------------------------------------------------
// Kernel 2: Ksum[b][br][m] = sum_n Kbuf[b][m][n]
// ---------------------------------------------------------------------------
__global__ __launch_bounds__(256) void ksum_kernel(const float* __restrict__ Kbuf,
                                                   float* __restrict__ Ksum, int br)
{
    const int m = blockIdx.x;   // 0..63
    const int b = blockIdx.z;   // 0..7
    const float* row = Kbuf + ((size_t)b * M_ + m) * N_;
    float s = 0.f;
    for (int n = threadIdx.x; n < N_; n += 256) s += row[n];
    __shared__ float red[256];
    red[threadIdx.x] = s;
    __syncthreads();
    for (int off = 128; off > 0; off >>= 1) {
        if (threadIdx.x < off) red[threadIdx.x] += red[threadIdx.x + off];
        __syncthreads();
    }
    if (threadIdx.x == 0) Ksum[((size_t)b * 3 + br) * M_ + m] = red[0];
}

// ---------------------------------------------------------------------------
// Kernel 3a (MFMA): split-N partial KX via bf16 matrix cores.
// KXpart[nc][b][m][c] = sum_{n in chunk nc} Kbuf[b][m][n] * x[b][c][n]
// D[m][c] = A[m][k]·B[k][c]: A-frag lane{row=l&15, kgrp=l>>4} reads 8 contiguous
// n from Kbuf row; B-frag lane{col=l&15, kgrp=l>>4} reads 8 contiguous n from
// x row — native layouts, no transpose. fp32->bf16 staged in LDS (+8 pad).
// Block: 256 thr / 4 waves; tile [64 m][32 c]; grid (16 c-tiles, NCHUNK, B).
// ---------------------------------------------------------------------------
__global__ __launch_bounds__(256) void kx_mfma_kernel(const float* __restrict__ Kbuf,
                                                      const float* __restrict__ x,
                                                      float* __restrict__ KXpart)
{
    const int c0 = blockIdx.x * 32;
    const int nc = blockIdx.y;
    const int b  = blockIdx.z;
    const int nbeg = nc * (N_ / NCHUNK_);

    __shared__ short Klds[64][72];   // 64 bf16 + 8 pad per row (144 B stride)
    __shared__ short Xlds[32][72];

    const int tid  = threadIdx.x;
    const int lane = tid & 63;
    const int w    = tid >> 6;       // wave id 0..3 -> m-tile base w*16
    const int lrow = lane & 15;
    const int lkg  = lane >> 4;      // 0..3 k-group

    const float* kb = Kbuf + (size_t)b * M_ * N_;
    const float* xb = x + ((size_t)b * C_ + c0) * N_;

    f32x4 acc0 = {0.f, 0.f, 0.f, 0.f};
    f32x4 acc1 = {0.f, 0.f, 0.f, 0.f};

    for (int it = 0; it < (N_ / NCHUNK_) / 64; ++it) {
        const int n0 = nbeg + it * 64;
        __syncthreads();   // previous iteration's frag reads done
        // stage K tile: 64 rows x 64 n (fp32 -> bf16), 4 float4 per thread
        #pragma unroll
        for (int i = 0; i < 4; ++i) {
            int f = tid + i * 256;               // 0..1023
            int r = f >> 4, c4 = (f & 15) * 4;
            float4 v = *reinterpret_cast<const float4*>(&kb[(size_t)r * N_ + n0 + c4]);
            short4 s;
            s.x = f2bf(v.x); s.y = f2bf(v.y); s.z = f2bf(v.z); s.w = f2bf(v.w);
            *reinterpret_cast<short4*>(&Klds[r][c4]) = s;
        }
        // stage X tile: 32 rows x 64 n, 2 float4 per thread
        #pragma unroll
        for (int i = 0; i < 2; ++i) {
            int f = tid + i * 256;               // 0..511
            int r = f >> 4, c4 = (f & 15) * 4;
            float4 v = *reinterpret_cast<const float4*>(&xb[(size_t)r * N_ + n0 + c4]);
            short4 s;
            s.x = f2bf(v.x); s.y = f2bf(v.y); s.z = f2bf(v.z); s.w = f2bf(v.w);
            *reinterpret_cast<short4*>(&Xlds[r][c4]) = s;
        }
        __syncthreads();
        // 2 k-steps of 32 over the staged 64-n tile
        #pragma unroll
        for (int s = 0; s < 2; ++s) {
            bf16x8 a  = *reinterpret_cast<const bf16x8*>(&Klds[w * 16 + lrow][s * 32 + lkg * 8]);
            bf16x8 b0 = *reinterpret_cast<const bf16x8*>(&Xlds[lrow][s * 32 + lkg * 8]);
            bf16x8 b1 = *reinterpret_cast<const bf16x8*>(&Xlds[16 + lrow][s * 32 + lkg * 8]);
            acc0 = __builtin_amdgcn_mfma_f32_16x16x32_bf16(a, b0, acc0, 0, 0, 0);
            acc1 = __builtin_amdgcn_mfma_f32_16x16x32_bf16(a, b1, acc1, 0, 0, 0);
        }
    }

    // D layout: lane holds D[row=(lane>>4)*4+r][col=lane&15]
    float* outp = KXpart + ((size_t)nc * B_ + b) * M_ * C_;
    #pragma unroll
    for (int r = 0; r < 4; ++r) {
        int m = w * 16 + lkg * 4 + r;
        outp[(size_t)m * C_ + c0 + lrow]      = acc0[r];
        outp[(size_t)m * C_ + c0 + 16 + lrow] = acc1[r];
    }
}

// ---------------------------------------------------------------------------
// Kernel 3b: reduce partials (fixed order — deterministic).
// ---------------------------------------------------------------------------
__global__ __launch_bounds__(256) void kx_reduce_kernel(const float* __restrict__ KXpart,
                                                        float* __restrict__ KX, int br)
{
    const size_t BMC = (size_t)B_ * M_ * C_;
    size_t i = (size_t)blockIdx.x * 256 + threadIdx.x;
    if (i >= BMC) return;
    float s = 0.f;
    #pragma unroll
    for (int nc = 0; nc < NCHUNK_; ++nc) s += KXpart[nc * BMC + i];
    size_t b = i / ((size_t)M_ * C_);
    size_t rem = i - b * (size_t)M_ * C_;
    KX[((size_t)b * 3 + br) * M_ * C_ + rem] = s;
}

// ---------------------------------------------------------------------------
// Kernel 4: WlWv[c][k] = sum_p Wl[c][p] * Wv[p][k]   (batch-independent)
// ---------------------------------------------------------------------------
__global__ __launch_bounds__(256) void wlwv_kernel(const float* __restrict__ Wl,
                                                   const float* __restrict__ Wv,
                                                   float* __restrict__ WlWv)
{
    const int k0 = blockIdx.x * 64;
    const int c0 = blockIdx.y * 64;
    __shared__ float As[64][65];
    __shared__ float Bs[64][65];
    const int tid = threadIdx.x;
    const int tx = tid & 15, ty = tid >> 4;
    float acc[4][4] = {};

    for (int p0 = 0; p0 < C_; p0 += 64) {
        for (int l = tid; l < 64 * 64; l += 256) {
            int r = l >> 6, q = l & 63;
            As[r][q] = Wl[(size_t)(c0 + r) * C_ + p0 + q];
            Bs[r][q] = Wv[(size_t)(p0 + r) * C_ + k0 + q];
        }
        __syncthreads();
        #pragma unroll 16
        for (int p = 0; p < 64; ++p) {
            float a[4], bb[4];
            #pragma unroll
            for (int i = 0; i < 4; ++i) a[i] = As[ty * 4 + i][p];
            #pragma unroll
            for (int j = 0; j < 4; ++j) bb[j] = Bs[p][tx * 4 + j];
            #pragma unroll
            for (int i = 0; i < 4; ++i)
                #pragma unroll
                for (int j = 0; j < 4; ++j)
                    acc[i][j] = fmaf(a[i], bb[j], acc[i][j]);
        }
        __syncthreads();
    }
    #pragma unroll
    for (int i = 0; i < 4; ++i)
        #pragma unroll
        for (int j = 0; j < 4; ++j)
            WlWv[(size_t)(c0 + ty * 4 + i) * C_ + k0 + tx * 4 + j] = acc[i][j];
}

// Wlbv[c] = sum_p Wl[c][p] * bv[p]
__global__ __launch_bounds__(256) void wlbv_kernel(const float* __restrict__ Wl,
                                                   const float* __restrict__ bv,
                                                   float* __restrict__ Wlbv)
{
    int c = blockIdx.x * 256 + threadIdx.x;
    if (c < C_) {
        float s = 0.f;
        for (int p = 0; p < C_; ++p) s = fmaf(Wl[(size_t)c * C_ + p], bv[p], s);
        Wlbv[c] = s;
    }
}

// ---------------------------------------------------------------------------
// Kernel 5: Wf[b][br][c][m] = sum_k WlWv[c][k]*KX[b][br][m][k] + Ksum[b][br][m]*Wlbv[c]
// ---------------------------------------------------------------------------
__global__ __launch_bounds__(256) void wfused_kernel(const float* __restrict__ WlWv,
                                                     const float* __restrict__ KX,
                                                     const float* __restrict__ Ksum,
                                                     const float* __restrict__ Wlbv,
                                                     float* __restrict__ Wf)
{
    const int c0 = blockIdx.x * 64;
    const int br = blockIdx.y;
    const int b = blockIdx.z;

    __shared__ float As[64][65];   // WlWv[c][k] chunk
    __shared__ float Bs[64][65];   // KX^T: Bs[kk][m]
    const int tid = threadIdx.x;
    const int tx = tid & 15, ty = tid >> 4;
    float acc[4][4] = {};

    const float* kxb = KX + ((size_t)b * 3 + br) * M_ * C_;  // [m][k]
    for (int k0 = 0; k0 < C_; k0 += 64) {
        for (int l = tid; l < 64 * 64; l += 256) {
            int r = l >> 6, q = l & 63;
            As[r][q] = WlWv[(size_t)(c0 + r) * C_ + k0 + q];
            Bs[q][r] = kxb[(size_t)r * C_ + k0 + q];   // r = m, q = kk
        }
        __syncthreads();
        #pragma unroll 16
        for (int kk = 0; kk < 64; ++kk) {
            float a[4], bb[4];
            #pragma unroll
            for (int i = 0; i < 4; ++i) a[i] = As[ty * 4 + i][kk];
            #pragma unroll
            for (int j = 0; j < 4; ++j) bb[j] = Bs[kk][tx * 4 + j];
            #pragma unroll
            for (int i = 0; i < 4; ++i)
                #pragma unroll
                for (int j = 0; j < 4; ++j)
                    acc[i][j] = fmaf(a[i], bb[j], acc[i][j]);
        }
        __syncthreads();
    }
    const float* ks = Ksum + ((size_t)b * 3 + br) * M_;
    #pragma unroll
    for (int i = 0; i < 4; ++i) {
        int c = c0 + ty * 4 + i;
        float wb = Wlbv[c];
        #pragma unroll
        for (int j = 0; j < 4; ++j) {
            int m = tx * 4 + j;
            Wf[(((size_t)b * 3 + br) * C_ + c) * M_ + m] = acc[i][j] + ks[m] * wb;
        }
    }
}

// ---------------------------------------------------------------------------
// Kernel 6: out[b][c][n] = x[b][c][n] + gamma * ( bl[c] +
//      sum_br norm_br[n] * sum_m Wf[b][br][c][m] * Q[b][m][n] )
// ---------------------------------------------------------------------------
__global__ __launch_bounds__(256) void final_kernel(
    const float* __restrict__ Q, const float* __restrict__ Wf,
    const float* __restrict__ Ksum, const float* __restrict__ x,
    const float* __restrict__ bl, const float* __restrict__ gamma,
    float* __restrict__ out)
{
    const int n0 = blockIdx.x * 64;
    const int c0 = blockIdx.y * 64;
    const int b = blockIdx.z;

    __shared__ float Qs[64][65];     // raw Q tile [m][n]
    __shared__ float Ws[64][65];     // Wf tile [c][m]
    __shared__ float norms[3][64];
    __shared__ float kse[3][64];

    const int tid = threadIdx.x;
    const int tx = tid & 15, ty = tid >> 4;

    const float* qb = Q + (size_t)b * M_ * N_;
    for (int l = tid; l < 64 * 64; l += 256) {
        int m = l >> 6, nn = l & 63;
        Qs[m][nn] = qb[(size_t)m * N_ + n0 + nn];
    }
    if (tid < 3 * 64) {
        int br = tid >> 6, m = tid & 63;
        kse[br][m] = Ksum[((size_t)b * 3 + br) * M_ + m] + EPS_;
    }
    __syncthreads();
    if (tid < 192) {
        int br = tid >> 6, nn = tid & 63;
        float s = 0.f;
        #pragma unroll 16
        for (int m = 0; m < 64; ++m) s = fmaf(Qs[m][nn], kse[br][m], s);
        norms[br][nn] = 1.0f / s;
    }

    float acc[4][4] = {};
    for (int br = 0; br < 3; ++br) {
        __syncthreads();
        for (int l = tid; l < 64 * 64; l += 256) {
            int cc = l >> 6, m = l & 63;
            Ws[cc][m] = Wf[(((size_t)b * 3 + br) * C_ + c0 + cc) * M_ + m];
        }
        __syncthreads();
        float S[4][4] = {};
        #pragma unroll 16
        for (int m = 0; m < 64; ++m) {
            float a[4], bb[4];
            #pragma unroll
            for (int i = 0; i < 4; ++i) a[i] = Ws[ty * 4 + i][m];
            #pragma unroll
            for (int j = 0; j < 4; ++j) bb[j] = Qs[m][tx * 4 + j];
            #pragma unroll
            for (int i = 0; i < 4; ++i)
                #pragma unroll
                for (int j = 0; j < 4; ++j)
                    S[i][j] = fmaf(a[i], bb[j], S[i][j]);
        }
        #pragma unroll
        for (int j = 0; j < 4; ++j) {
            float nf = norms[br][tx * 4 + j];
            #pragma unroll
            for (int i = 0; i < 4; ++i) acc[i][j] = fmaf(nf, S[i][j], acc[i][j]);
        }
    }

    const float g = gamma[0];
    const float* xb = x + (size_t)b * C_ * N_;
    float* ob = out + (size_t)b * C_ * N_;
    #pragma unroll
    for (int i = 0; i < 4; ++i) {
        int c = c0 + ty * 4 + i;
        float blc = bl[c];
        #pragma unroll
        for (int j = 0; j < 4; ++j) {
            int n = n0 + tx * 4 + j;
            ob[(size_t)c * N_ + n] = fmaf(g, acc[i][j] + blc, xb[(size_t)c * N_ + n]);
        }
    }
}

// ---------------------------------------------------------------------------
extern "C" void kernel_launch(void* const* d_in, const int* in_sizes, int n_in,
                              void* d_out, int out_size, void* d_ws, size_t ws_size,
                              hipStream_t stream)
{
    const float* x   = (const float*)d_in[0];
    const float* y   = (const float*)d_in[1];
    const float* z   = (const float*)d_in[2];
    const float* Wq  = (const float*)d_in[3];
    const float* bq  = (const float*)d_in[4];
    const float* Wk1 = (const float*)d_in[5];
    const float* bk1 = (const float*)d_in[6];
    const float* Wk2 = (const float*)d_in[7];
    const float* bk2 = (const float*)d_in[8];
    const float* Wk3 = (const float*)d_in[9];
    const float* bk3 = (const float*)d_in[10];
    const float* Wv  = (const float*)d_in[11];
    const float* bv  = (const float*)d_in[12];
    const float* Wl  = (const float*)d_in[13];
    const float* bl  = (const float*)d_in[14];
    const float* gamma = (const float*)d_in[15];
    float* out = (float*)d_out;

    // workspace layout (floats) — total 6,293,504 floats = 25.2 MB (unchanged).
    float* ws = (float*)d_ws;
    const size_t QSZ  = (size_t)B_ * M_ * N_;        // 2,097,152
    const size_t BMC  = (size_t)B_ * M_ * C_;        //   262,144
    float* Q    = ws;                                 // [B][M][N]
    float* Kbuf = Q + QSZ;                            // [B][M][N] (reused per branch)
    float* KX   = Kbuf + QSZ;                         // [B][3][M][C]
    float* Ksum = KX + 3 * BMC;                       // [B][3][M]
    float* WlWv = Ksum + (size_t)B_ * 3 * M_;         // [C][C]
    float* Wlbv = WlWv + (size_t)C_ * C_;             // [C]
    float* KXpart = Wlbv + C_;                        // [NCHUNK][B][M][C]  (4 MB)
    float* Wf   = KXpart;                             // [B][3][C][M]       (3 MB, aliased)

    dim3 blk(256);
    const dim3 featGrid(N_ / 64, 1, B_);

    // Q features
    feat_gemm<<<featGrid, blk, 0, stream>>>(x, Wq, bq, Q);

    // K branches, sequenced through Kbuf
    const float* kin[3]  = { x, y, z };
    const float* kW[3]   = { Wk1, Wk2, Wk3 };
    const float* kb_[3]  = { bk1, bk2, bk3 };
    for (int br = 0; br < 3; ++br) {
        feat_gemm<<<featGrid, blk, 0, stream>>>(kin[br], kW[br], kb_[br], Kbuf);
        ksum_kernel<<<dim3(M_, 1, B_), blk, 0, stream>>>(Kbuf, Ksum, br);
        kx_mfma_kernel<<<dim3(C_ / 32, NCHUNK_, B_), blk, 0, stream>>>(Kbuf, x, KXpart);
        kx_reduce_kernel<<<dim3((BMC + 255) / 256), blk, 0, stream>>>(KXpart, KX, br);
    }

    // batch-independent fused weights
    wlwv_kernel<<<dim3(C_ / 64, C_ / 64), blk, 0, stream>>>(Wl, Wv, WlWv);
    wlbv_kernel<<<dim3((C_ + 255) / 256), blk, 0, stream>>>(Wl, bv, Wlbv);
    // per-batch fused weights (reads KX/Ksum; writes Wf — KXpart no longer needed)
    wfused_kernel<<<dim3(C_ / 64, 3, B_), blk, 0, stream>>>(WlWv, KX, Ksum, Wlbv, Wf);
    // final: norms + GEMM + bias + residual
    final_kernel<<<dim3(N_ / 64, C_ / 64, B_), blk, 0, stream>>>(
        Q, Wf, Ksum, x, bl, gamma, out);
}

// Round 9
// 430.285 us; speedup vs baseline: 4.4661x; 1.2309x over previous
//
#include <hip/hip_runtime.h>
#include <hip/hip_bf16.h>
#include <math.h>

// Problem constants
constexpr int B_ = 8;
constexpr int C_ = 512;
constexpr int M_ = 64;     // C/8
constexpr int N_ = 4096;   // H*W
constexpr int NCHUNK_ = 4; // split-N factor for kx
constexpr float EPS_ = 1e-10f;
constexpr float PARAM_ = 10.0f;

typedef __attribute__((ext_vector_type(4))) float f32x4;
typedef __attribute__((ext_vector_type(8))) short bf16x8;   // 8 bf16 in 4 VGPRs

// elus feature map: t>0 ? 10t+1 : exp(10t)
__device__ __forceinline__ float elus(float t) {
    return (t > 0.f) ? fmaf(PARAM_, t, 1.f) : expf(PARAM_ * t);
}

// fp32 -> bf16 round-to-nearest-even (finite inputs only)
__device__ __forceinline__ short f2bf(float f) {
    unsigned u = __builtin_bit_cast(unsigned, f);
    u += 0x7FFFu + ((u >> 16) & 1u);
    return (short)(u >> 16);
}
// bf16 bits -> fp32
__device__ __forceinline__ float bf2f(short s) {
    unsigned u = ((unsigned)(unsigned short)s) << 16;
    return __builtin_bit_cast(float, u);
}

// ---------------------------------------------------------------------------
// Kernel 1: feature GEMM: out = elus(W @ in + bias).
// tq=0: out[b][m][n] (row-major n).  tq=1: out[b][n][m] (transposed, for Q —
// m-contiguous so the final MFMA B-frag reads are 16B contiguous).
// ---------------------------------------------------------------------------
__global__ __launch_bounds__(256) void feat_gemm(
    const float* __restrict__ in, const float* __restrict__ W,
    const float* __restrict__ bias, float* __restrict__ out, int tq)
{
    const int n0 = blockIdx.x * 64;
    const int b = blockIdx.z;

    __shared__ float Ws[64][65];
    __shared__ float Xs[64][65];

    const int tid = threadIdx.x;
    const int tx = tid & 15, ty = tid >> 4;
    float acc[4][4] = {};

    const float* inb = in + (size_t)b * C_ * N_;
    for (int k0 = 0; k0 < C_; k0 += 64) {
        for (int l = tid; l < 64 * 64; l += 256) {
            int r = l >> 6, q = l & 63;
            Ws[r][q] = W[(size_t)r * C_ + k0 + q];
            Xs[r][q] = inb[(size_t)(k0 + r) * N_ + n0 + q];
        }
        __syncthreads();
        #pragma unroll 16
        for (int kk = 0; kk < 64; ++kk) {
            float a[4], bb[4];
            #pragma unroll
            for (int i = 0; i < 4; ++i) a[i] = Ws[ty * 4 + i][kk];
            #pragma unroll
            for (int j = 0; j < 4; ++j) bb[j] = Xs[kk][tx * 4 + j];
            #pragma unroll
            for (int i = 0; i < 4; ++i)
                #pragma unroll
                for (int j = 0; j < 4; ++j)
                    acc[i][j] = fmaf(a[i], bb[j], acc[i][j]);
        }
        __syncthreads();
    }

    if (!tq) {
        float* outb = out + (size_t)b * M_ * N_;
        #pragma unroll
        for (int i = 0; i < 4; ++i) {
            int m = ty * 4 + i;
            float bi = bias[m];
            #pragma unroll
            for (int j = 0; j < 4; ++j) {
                int n = n0 + tx * 4 + j;
                outb[(size_t)m * N_ + n] = elus(acc[i][j] + bi);
            }
        }
    } else {
        // QT[b][n][m]: float4 along m (16B-aligned: ty*4 floats)
        float* outb = out + (size_t)b * N_ * M_;
        float bi[4];
        #pragma unroll
        for (int i = 0; i < 4; ++i) bi[i] = bias[ty * 4 + i];
        #pragma unroll
        for (int j = 0; j < 4; ++j) {
            int n = n0 + tx * 4 + j;
            float4 v;
            v.x = elus(acc[0][j] + bi[0]);
            v.y = elus(acc[1][j] + bi[1]);
            v.z = elus(acc[2][j] + bi[2]);
            v.w = elus(acc[3][j] + bi[3]);
            *reinterpret_cast<float4*>(&outb[(size_t)n * M_ + ty * 4]) = v;
        }
    }
}

// ---------------------------------------------------------------------------
// Kernel 2: Ksum[b][br][m] = sum_n Kbuf[b][m][n]
// ---------------------------------------------------------------------------
__global__ __launch_bounds__(256) void ksum_kernel(const float* __restrict__ Kbuf,
                                                   float* __restrict__ Ksum, int br)
{
    const int m = blockIdx.x;   // 0..63
    const int b = blockIdx.z;   // 0..7
    const float* row = Kbuf + ((size_t)b * M_ + m) * N_;
    float s = 0.f;
    for (int n = threadIdx.x; n < N_; n += 256) s += row[n];
    __shared__ float red[256];
    red[threadIdx.x] = s;
    __syncthreads();
    for (int off = 128; off > 0; off >>= 1) {
        if (threadIdx.x < off) red[threadIdx.x] += red[threadIdx.x + off];
        __syncthreads();
    }
    if (threadIdx.x == 0) Ksum[((size_t)b * 3 + br) * M_ + m] = red[0];
}

// ---------------------------------------------------------------------------
// Kernel 3a (MFMA): split-N partial KX via bf16 matrix cores.
// ---------------------------------------------------------------------------
__global__ __launch_bounds__(256) void kx_mfma_kernel(const float* __restrict__ Kbuf,
                                                      const float* __restrict__ x,
                                                      float* __restrict__ KXpart)
{
    const int c0 = blockIdx.x * 32;
    const int nc = blockIdx.y;
    const int b  = blockIdx.z;
    const int nbeg = nc * (N_ / NCHUNK_);

    __shared__ short Klds[64][72];   // 64 bf16 + 8 pad per row (144 B stride)
    __shared__ short Xlds[32][72];

    const int tid  = threadIdx.x;
    const int lane = tid & 63;
    const int w    = tid >> 6;       // wave id 0..3 -> m-tile base w*16
    const int lrow = lane & 15;
    const int lkg  = lane >> 4;      // 0..3 k-group

    const float* kb = Kbuf + (size_t)b * M_ * N_;
    const float* xb = x + ((size_t)b * C_ + c0) * N_;

    f32x4 acc0 = {0.f, 0.f, 0.f, 0.f};
    f32x4 acc1 = {0.f, 0.f, 0.f, 0.f};

    for (int it = 0; it < (N_ / NCHUNK_) / 64; ++it) {
        const int n0 = nbeg + it * 64;
        __syncthreads();   // previous iteration's frag reads done
        #pragma unroll
        for (int i = 0; i < 4; ++i) {
            int f = tid + i * 256;               // 0..1023
            int r = f >> 4, c4 = (f & 15) * 4;
            float4 v = *reinterpret_cast<const float4*>(&kb[(size_t)r * N_ + n0 + c4]);
            short4 s;
            s.x = f2bf(v.x); s.y = f2bf(v.y); s.z = f2bf(v.z); s.w = f2bf(v.w);
            *reinterpret_cast<short4*>(&Klds[r][c4]) = s;
        }
        #pragma unroll
        for (int i = 0; i < 2; ++i) {
            int f = tid + i * 256;               // 0..511
            int r = f >> 4, c4 = (f & 15) * 4;
            float4 v = *reinterpret_cast<const float4*>(&xb[(size_t)r * N_ + n0 + c4]);
            short4 s;
            s.x = f2bf(v.x); s.y = f2bf(v.y); s.z = f2bf(v.z); s.w = f2bf(v.w);
            *reinterpret_cast<short4*>(&Xlds[r][c4]) = s;
        }
        __syncthreads();
        #pragma unroll
        for (int s = 0; s < 2; ++s) {
            bf16x8 a  = *reinterpret_cast<const bf16x8*>(&Klds[w * 16 + lrow][s * 32 + lkg * 8]);
            bf16x8 b0 = *reinterpret_cast<const bf16x8*>(&Xlds[lrow][s * 32 + lkg * 8]);
            bf16x8 b1 = *reinterpret_cast<const bf16x8*>(&Xlds[16 + lrow][s * 32 + lkg * 8]);
            acc0 = __builtin_amdgcn_mfma_f32_16x16x32_bf16(a, b0, acc0, 0, 0, 0);
            acc1 = __builtin_amdgcn_mfma_f32_16x16x32_bf16(a, b1, acc1, 0, 0, 0);
        }
    }

    float* outp = KXpart + ((size_t)nc * B_ + b) * M_ * C_;
    #pragma unroll
    for (int r = 0; r < 4; ++r) {
        int m = w * 16 + lkg * 4 + r;
        outp[(size_t)m * C_ + c0 + lrow]      = acc0[r];
        outp[(size_t)m * C_ + c0 + 16 + lrow] = acc1[r];
    }
}

// ---------------------------------------------------------------------------
// Kernel 3b: reduce partials (fixed order — deterministic).
// ---------------------------------------------------------------------------
__global__ __launch_bounds__(256) void kx_reduce_kernel(const float* __restrict__ KXpart,
                                                        float* __restrict__ KX, int br)
{
    const size_t BMC = (size_t)B_ * M_ * C_;
    size_t i = (size_t)blockIdx.x * 256 + threadIdx.x;
    if (i >= BMC) return;
    float s = 0.f;
    #pragma unroll
    for (int nc = 0; nc < NCHUNK_; ++nc) s += KXpart[nc * BMC + i];
    size_t b = i / ((size_t)M_ * C_);
    size_t rem = i - b * (size_t)M_ * C_;
    KX[((size_t)b * 3 + br) * M_ * C_ + rem] = s;
}

// ---------------------------------------------------------------------------
// Kernel 4: WlWv[c][k] = sum_p Wl[c][p] * Wv[p][k]
// ---------------------------------------------------------------------------
__global__ __launch_bounds__(256) void wlwv_kernel(const float* __restrict__ Wl,
                                                   const float* __restrict__ Wv,
                                                   float* __restrict__ WlWv)
{
    const int k0 = blockIdx.x * 64;
    const int c0 = blockIdx.y * 64;
    __shared__ float As[64][65];
    __shared__ float Bs[64][65];
    const int tid = threadIdx.x;
    const int tx = tid & 15, ty = tid >> 4;
    float acc[4][4] = {};

    for (int p0 = 0; p0 < C_; p0 += 64) {
        for (int l = tid; l < 64 * 64; l += 256) {
            int r = l >> 6, q = l & 63;
            As[r][q] = Wl[(size_t)(c0 + r) * C_ + p0 + q];
            Bs[r][q] = Wv[(size_t)(p0 + r) * C_ + k0 + q];
        }
        __syncthreads();
        #pragma unroll 16
        for (int p = 0; p < 64; ++p) {
            float a[4], bb[4];
            #pragma unroll
            for (int i = 0; i < 4; ++i) a[i] = As[ty * 4 + i][p];
            #pragma unroll
            for (int j = 0; j < 4; ++j) bb[j] = Bs[p][tx * 4 + j];
            #pragma unroll
            for (int i = 0; i < 4; ++i)
                #pragma unroll
                for (int j = 0; j < 4; ++j)
                    acc[i][j] = fmaf(a[i], bb[j], acc[i][j]);
        }
        __syncthreads();
    }
    #pragma unroll
    for (int i = 0; i < 4; ++i)
        #pragma unroll
        for (int j = 0; j < 4; ++j)
            WlWv[(size_t)(c0 + ty * 4 + i) * C_ + k0 + tx * 4 + j] = acc[i][j];
}

// Wlbv[c] = sum_p Wl[c][p] * bv[p]
__global__ __launch_bounds__(256) void wlbv_kernel(const float* __restrict__ Wl,
                                                   const float* __restrict__ bv,
                                                   float* __restrict__ Wlbv)
{
    int c = blockIdx.x * 256 + threadIdx.x;
    if (c < C_) {
        float s = 0.f;
        for (int p = 0; p < C_; ++p) s = fmaf(Wl[(size_t)c * C_ + p], bv[p], s);
        Wlbv[c] = s;
    }
}

// ---------------------------------------------------------------------------
// Kernel 5: Wf[b][br][c][m] = sum_k WlWv[c][k]*KX[b][br][m][k] + Ksum[b][br][m]*Wlbv[c]
// ---------------------------------------------------------------------------
__global__ __launch_bounds__(256) void wfused_kernel(const float* __restrict__ WlWv,
                                                     const float* __restrict__ KX,
                                                     const float* __restrict__ Ksum,
                                                     const float* __restrict__ Wlbv,
                                                     float* __restrict__ Wf)
{
    const int c0 = blockIdx.x * 64;
    const int br = blockIdx.y;
    const int b = blockIdx.z;

    __shared__ float As[64][65];   // WlWv[c][k] chunk
    __shared__ float Bs[64][65];   // KX^T: Bs[kk][m]
    const int tid = threadIdx.x;
    const int tx = tid & 15, ty = tid >> 4;
    float acc[4][4] = {};

    const float* kxb = KX + ((size_t)b * 3 + br) * M_ * C_;  // [m][k]
    for (int k0 = 0; k0 < C_; k0 += 64) {
        for (int l = tid; l < 64 * 64; l += 256) {
            int r = l >> 6, q = l & 63;
            As[r][q] = WlWv[(size_t)(c0 + r) * C_ + k0 + q];
            Bs[q][r] = kxb[(size_t)r * C_ + k0 + q];   // r = m, q = kk
        }
        __syncthreads();
        #pragma unroll 16
        for (int kk = 0; kk < 64; ++kk) {
            float a[4], bb[4];
            #pragma unroll
            for (int i = 0; i < 4; ++i) a[i] = As[ty * 4 + i][kk];
            #pragma unroll
            for (int j = 0; j < 4; ++j) bb[j] = Bs[kk][tx * 4 + j];
            #pragma unroll
            for (int i = 0; i < 4; ++i)
                #pragma unroll
                for (int j = 0; j < 4; ++j)
                    acc[i][j] = fmaf(a[i], bb[j], acc[i][j]);
        }
        __syncthreads();
    }
    const float* ks = Ksum + ((size_t)b * 3 + br) * M_;
    #pragma unroll
    for (int i = 0; i < 4; ++i) {
        int c = c0 + ty * 4 + i;
        float wb = Wlbv[c];
        #pragma unroll
        for (int j = 0; j < 4; ++j) {
            int m = tx * 4 + j;
            Wf[(((size_t)b * 3 + br) * C_ + c) * M_ + m] = acc[i][j] + ks[m] * wb;
        }
    }
}

// ---------------------------------------------------------------------------
// Kernel 6 (MFMA): out[b][c][n] = x[b][c][n] + gamma*( bl[c] +
//    sum_br norm_br[n] * sum_m Wf[b][br][c][m] * QT[b][n][m] )
// norm_br[n] = 1 / sum_m QT[n][m]*(Ksum[br][m]+EPS)
// A-frag = Wf[c][m] (m-contig), B-frag = QT[n][m] (m-contig) — both native.
// LDS tiles [64][72] bf16 (144B stride) — same 0-conflict pattern as kx.
// Block: 256 thr / 4 waves; tile 64c x 64n; wave w owns c rows w*16..+16.
// ---------------------------------------------------------------------------
__global__ __launch_bounds__(256) void final_mfma_kernel(
    const float* __restrict__ QT, const float* __restrict__ Wf,
    const float* __restrict__ Ksum, const float* __restrict__ x,
    const float* __restrict__ bl, const float* __restrict__ gamma,
    float* __restrict__ out)
{
    const int n0 = blockIdx.x * 64;
    const int c0 = blockIdx.y * 64;
    const int b  = blockIdx.z;

    __shared__ short Qs[64][72];      // [n][m] bf16
    __shared__ short Wfs[3][64][72];  // [br][c][m] bf16
    __shared__ float norms[3][64];
    __shared__ float ksef[3][64];

    const int tid  = threadIdx.x;
    const int lane = tid & 63;
    const int w    = tid >> 6;
    const int lrow = lane & 15;
    const int lkg  = lane >> 4;

    // stage QT tile (64 n x 64 m, fp32->bf16): 16 threads per 256B row
    const float* qtb = QT + (size_t)b * N_ * M_;
    #pragma unroll
    for (int i = 0; i < 4; ++i) {
        int f = tid + i * 256;
        int r = f >> 4, m4 = (f & 15) * 4;
        float4 v = *reinterpret_cast<const float4*>(&qtb[(size_t)(n0 + r) * M_ + m4]);
        short4 s;
        s.x = f2bf(v.x); s.y = f2bf(v.y); s.z = f2bf(v.z); s.w = f2bf(v.w);
        *reinterpret_cast<short4*>(&Qs[r][m4]) = s;
    }
    // stage Wf tiles for 3 branches
    #pragma unroll
    for (int br = 0; br < 3; ++br) {
        const float* wfb = Wf + (((size_t)b * 3 + br) * C_ + c0) * M_;
        #pragma unroll
        for (int i = 0; i < 4; ++i) {
            int f = tid + i * 256;
            int r = f >> 4, m4 = (f & 15) * 4;
            float4 v = *reinterpret_cast<const float4*>(&wfb[(size_t)r * M_ + m4]);
            short4 s;
            s.x = f2bf(v.x); s.y = f2bf(v.y); s.z = f2bf(v.z); s.w = f2bf(v.w);
            *reinterpret_cast<short4*>(&Wfs[br][r][m4]) = s;
        }
    }
    if (tid < 192) {
        int br = tid >> 6, m = tid & 63;
        ksef[br][m] = Ksum[((size_t)b * 3 + br) * M_ + m] + EPS_;
    }
    __syncthreads();
    // norms from the staged (bf16) Q tile
    if (tid < 192) {
        int br = tid >> 6, n = tid & 63;
        float s = 0.f;
        #pragma unroll 16
        for (int m = 0; m < 64; ++m) s = fmaf(bf2f(Qs[n][m]), ksef[br][m], s);
        norms[br][n] = 1.0f / s;
    }
    __syncthreads();

    // MFMA: 3 branches x 2 k-steps x 4 n-subtiles
    f32x4 tot[4] = {{0.f,0.f,0.f,0.f},{0.f,0.f,0.f,0.f},{0.f,0.f,0.f,0.f},{0.f,0.f,0.f,0.f}};
    for (int br = 0; br < 3; ++br) {
        f32x4 acc[4] = {{0.f,0.f,0.f,0.f},{0.f,0.f,0.f,0.f},{0.f,0.f,0.f,0.f},{0.f,0.f,0.f,0.f}};
        #pragma unroll
        for (int ks = 0; ks < 2; ++ks) {
            bf16x8 a = *reinterpret_cast<const bf16x8*>(&Wfs[br][w * 16 + lrow][ks * 32 + lkg * 8]);
            #pragma unroll
            for (int ns = 0; ns < 4; ++ns) {
                bf16x8 bq = *reinterpret_cast<const bf16x8*>(&Qs[ns * 16 + lrow][ks * 32 + lkg * 8]);
                acc[ns] = __builtin_amdgcn_mfma_f32_16x16x32_bf16(a, bq, acc[ns], 0, 0, 0);
            }
        }
        #pragma unroll
        for (int ns = 0; ns < 4; ++ns) {
            float nf = norms[br][ns * 16 + lrow];   // col = n = lane&15
            #pragma unroll
            for (int r = 0; r < 4; ++r) tot[ns][r] = fmaf(nf, acc[ns][r], tot[ns][r]);
        }
    }

    // epilogue: bias + residual.  D rows: c = c0 + w*16 + lkg*4 + r; col n = lrow.
    const float g = gamma[0];
    const float* xb = x + (size_t)b * C_ * N_;
    float* ob = out + (size_t)b * C_ * N_;
    #pragma unroll
    for (int r = 0; r < 4; ++r) {
        int c = c0 + w * 16 + lkg * 4 + r;
        float blc = bl[c];
        #pragma unroll
        for (int ns = 0; ns < 4; ++ns) {
            int n = n0 + ns * 16 + lrow;
            ob[(size_t)c * N_ + n] = fmaf(g, tot[ns][r] + blc, xb[(size_t)c * N_ + n]);
        }
    }
}

// ---------------------------------------------------------------------------
extern "C" void kernel_launch(void* const* d_in, const int* in_sizes, int n_in,
                              void* d_out, int out_size, void* d_ws, size_t ws_size,
                              hipStream_t stream)
{
    const float* x   = (const float*)d_in[0];
    const float* y   = (const float*)d_in[1];
    const float* z   = (const float*)d_in[2];
    const float* Wq  = (const float*)d_in[3];
    const float* bq  = (const float*)d_in[4];
    const float* Wk1 = (const float*)d_in[5];
    const float* bk1 = (const float*)d_in[6];
    const float* Wk2 = (const float*)d_in[7];
    const float* bk2 = (const float*)d_in[8];
    const float* Wk3 = (const float*)d_in[9];
    const float* bk3 = (const float*)d_in[10];
    const float* Wv  = (const float*)d_in[11];
    const float* bv  = (const float*)d_in[12];
    const float* Wl  = (const float*)d_in[13];
    const float* bl  = (const float*)d_in[14];
    const float* gamma = (const float*)d_in[15];
    float* out = (float*)d_out;

    // workspace layout (floats) — total 6,293,504 floats = 25.2 MB (unchanged).
    // Q slot now holds QT[b][n][m].
    float* ws = (float*)d_ws;
    const size_t QSZ  = (size_t)B_ * M_ * N_;        // 2,097,152
    const size_t BMC  = (size_t)B_ * M_ * C_;        //   262,144
    float* QT   = ws;                                 // [B][N][M]
    float* Kbuf = QT + QSZ;                           // [B][M][N] (reused per branch)
    float* KX   = Kbuf + QSZ;                         // [B][3][M][C]
    float* Ksum = KX + 3 * BMC;                       // [B][3][M]
    float* WlWv = Ksum + (size_t)B_ * 3 * M_;         // [C][C]
    float* Wlbv = WlWv + (size_t)C_ * C_;             // [C]
    float* KXpart = Wlbv + C_;                        // [NCHUNK][B][M][C]  (4 MB)
    float* Wf   = KXpart;                             // [B][3][C][M]       (3 MB, aliased)

    dim3 blk(256);
    const dim3 featGrid(N_ / 64, 1, B_);

    // Q features (transposed output)
    feat_gemm<<<featGrid, blk, 0, stream>>>(x, Wq, bq, QT, 1);

    // K branches, sequenced through Kbuf
    const float* kin[3]  = { x, y, z };
    const float* kW[3]   = { Wk1, Wk2, Wk3 };
    const float* kb_[3]  = { bk1, bk2, bk3 };
    for (int br = 0; br < 3; ++br) {
        feat_gemm<<<featGrid, blk, 0, stream>>>(kin[br], kW[br], kb_[br], Kbuf, 0);
        ksum_kernel<<<dim3(M_, 1, B_), blk, 0, stream>>>(Kbuf, Ksum, br);
        kx_mfma_kernel<<<dim3(C_ / 32, NCHUNK_, B_), blk, 0, stream>>>(Kbuf, x, KXpart);
        kx_reduce_kernel<<<dim3((BMC + 255) / 256), blk, 0, stream>>>(KXpart, KX, br);
    }

    // batch-independent fused weights
    wlwv_kernel<<<dim3(C_ / 64, C_ / 64), blk, 0, stream>>>(Wl, Wv, WlWv);
    wlbv_kernel<<<dim3((C_ + 255) / 256), blk, 0, stream>>>(Wl, bv, Wlbv);
    // per-batch fused weights
    wfused_kernel<<<dim3(C_ / 64, 3, B_), blk, 0, stream>>>(WlWv, KX, Ksum, Wlbv, Wf);
    // final: norms + MFMA GEMM + bias + residual
    final_mfma_kernel<<<dim3(N_ / 64, C_ / 64, B_), blk, 0, stream>>>(
        QT, Wf, Ksum, x, bl, gamma, out);
}

// Round 10
// 280.569 us; speedup vs baseline: 6.8492x; 1.5336x over previous
//
#include <hip/hip_runtime.h>
#include <hip/hip_bf16.h>
#include <math.h>

// Problem constants
constexpr int B_ = 8;
constexpr int C_ = 512;
constexpr int M_ = 64;     // C/8
constexpr int N_ = 4096;   // H*W
constexpr int NCHUNK_ = 4; // split-N factor for kx
constexpr float EPS_ = 1e-10f;
constexpr float PARAM_ = 10.0f;

typedef __attribute__((ext_vector_type(4))) float f32x4;
typedef __attribute__((ext_vector_type(8))) short bf16x8;   // 8 bf16 in 4 VGPRs

// elus feature map: t>0 ? 10t+1 : exp(10t)
__device__ __forceinline__ float elus(float t) {
    return (t > 0.f) ? fmaf(PARAM_, t, 1.f) : expf(PARAM_ * t);
}

// fp32 -> bf16 round-to-nearest-even (finite inputs only)
__device__ __forceinline__ short f2bf(float f) {
    unsigned u = __builtin_bit_cast(unsigned, f);
    u += 0x7FFFu + ((u >> 16) & 1u);
    return (short)(u >> 16);
}
// bf16 bits -> fp32
__device__ __forceinline__ float bf2f(short s) {
    unsigned u = ((unsigned)(unsigned short)s) << 16;
    return __builtin_bit_cast(float, u);
}

// ---------------------------------------------------------------------------
// Kernel 1 (MFMA): feature GEMM out = elus(W @ in + bias).
// D[m][n] = sum_k W[m][k] * in[k][n].  A = Wlds[m][k] (k-contig, native);
// B = Xlds[n][k] built via in-register 4x4 transpose of the n-contiguous
// input (4 float4 loads along n -> 4 short4 writes along k).
// tq=0: out[b][m][n].  tq=1: out[b][n][m] (QT, float4 along m).
// Block 256 thr / 4 waves; tile 64m x 64n; k-chunks of 64 (8 chunks).
// ---------------------------------------------------------------------------
__global__ __launch_bounds__(256) void feat_mfma(
    const float* __restrict__ in, const float* __restrict__ W,
    const float* __restrict__ bias, float* __restrict__ out, int tq)
{
    const int n0 = blockIdx.x * 64;
    const int b  = blockIdx.z;

    __shared__ short Wlds[64][72];   // [m][k] bf16, 144B row stride
    __shared__ short Xlds[64][72];   // [n][k] bf16 (transposed tile)

    const int tid  = threadIdx.x;
    const int lane = tid & 63;
    const int w    = tid >> 6;       // wave id 0..3 -> m rows w*16..+15
    const int lrow = lane & 15;
    const int lkg  = lane >> 4;

    const float* inb = in + (size_t)b * C_ * N_;

    f32x4 acc[4] = {{0.f,0.f,0.f,0.f},{0.f,0.f,0.f,0.f},{0.f,0.f,0.f,0.f},{0.f,0.f,0.f,0.f}};

    const int kq = tid >> 4;   // 0..15 -> k base kq*4 (X transpose staging)
    const int nq = tid & 15;   // 0..15 -> n base nq*4

    for (int kc = 0; kc < C_ / 64; ++kc) {
        const int k0 = kc * 64;
        __syncthreads();   // previous chunk's frag reads done
        // stage W tile [64 m][64 k] (k-contiguous, same pattern as kx: 0-conflict)
        #pragma unroll
        for (int i = 0; i < 4; ++i) {
            int f = tid + i * 256;
            int r = f >> 4, c4 = (f & 15) * 4;
            f32x4 v = *reinterpret_cast<const f32x4*>(&W[(size_t)r * C_ + k0 + c4]);
            short4 s;
            s.x = f2bf(v[0]); s.y = f2bf(v[1]); s.z = f2bf(v[2]); s.w = f2bf(v[3]);
            *reinterpret_cast<short4*>(&Wlds[r][c4]) = s;
        }
        // stage X tile transposed: load 4x4 micro-tile (4 k rows x 4 n), write along k
        f32x4 v0 = *reinterpret_cast<const f32x4*>(&inb[(size_t)(k0 + kq * 4 + 0) * N_ + n0 + nq * 4]);
        f32x4 v1 = *reinterpret_cast<const f32x4*>(&inb[(size_t)(k0 + kq * 4 + 1) * N_ + n0 + nq * 4]);
        f32x4 v2 = *reinterpret_cast<const f32x4*>(&inb[(size_t)(k0 + kq * 4 + 2) * N_ + n0 + nq * 4]);
        f32x4 v3 = *reinterpret_cast<const f32x4*>(&inb[(size_t)(k0 + kq * 4 + 3) * N_ + n0 + nq * 4]);
        #pragma unroll
        for (int c = 0; c < 4; ++c) {
            short4 s;
            s.x = f2bf(v0[c]); s.y = f2bf(v1[c]); s.z = f2bf(v2[c]); s.w = f2bf(v3[c]);
            *reinterpret_cast<short4*>(&Xlds[nq * 4 + c][kq * 4]) = s;
        }
        __syncthreads();
        // 2 k-steps of 32 over the staged chunk
        #pragma unroll
        for (int ks = 0; ks < 2; ++ks) {
            bf16x8 a = *reinterpret_cast<const bf16x8*>(&Wlds[w * 16 + lrow][ks * 32 + lkg * 8]);
            #pragma unroll
            for (int ns = 0; ns < 4; ++ns) {
                bf16x8 bx = *reinterpret_cast<const bf16x8*>(&Xlds[ns * 16 + lrow][ks * 32 + lkg * 8]);
                acc[ns] = __builtin_amdgcn_mfma_f32_16x16x32_bf16(a, bx, acc[ns], 0, 0, 0);
            }
        }
    }

    // epilogue: bias + elus.  D: lane holds rows m = w*16 + lkg*4 + r, col n = ns*16 + lrow.
    if (!tq) {
        float* outb = out + (size_t)b * M_ * N_;
        #pragma unroll
        for (int r = 0; r < 4; ++r) {
            int m = w * 16 + lkg * 4 + r;
            float bi = bias[m];
            #pragma unroll
            for (int ns = 0; ns < 4; ++ns) {
                int n = n0 + ns * 16 + lrow;
                outb[(size_t)m * N_ + n] = elus(acc[ns][r] + bi);
            }
        }
    } else {
        // QT[b][n][m]: 4 consecutive m per lane -> float4 store
        float* outb = out + (size_t)b * N_ * M_;
        int mbase = w * 16 + lkg * 4;
        float bi[4];
        #pragma unroll
        for (int r = 0; r < 4; ++r) bi[r] = bias[mbase + r];
        #pragma unroll
        for (int ns = 0; ns < 4; ++ns) {
            int n = n0 + ns * 16 + lrow;
            f32x4 v;
            #pragma unroll
            for (int r = 0; r < 4; ++r) v[r] = elus(acc[ns][r] + bi[r]);
            *reinterpret_cast<f32x4*>(&outb[(size_t)n * M_ + mbase]) = v;
        }
    }
}

// ---------------------------------------------------------------------------
// Kernel 2: Ksum[b][br][m] = sum_n Kbuf[b][m][n]
// ---------------------------------------------------------------------------
__global__ __launch_bounds__(256) void ksum_kernel(const float* __restrict__ Kbuf,
                                                   float* __restrict__ Ksum, int br)
{
    const int m = blockIdx.x;   // 0..63
    const int b = blockIdx.z;   // 0..7
    const float* row = Kbuf + ((size_t)b * M_ + m) * N_;
    float s = 0.f;
    for (int n = threadIdx.x; n < N_; n += 256) s += row[n];
    __shared__ float red[256];
    red[threadIdx.x] = s;
    __syncthreads();
    for (int off = 128; off > 0; off >>= 1) {
        if (threadIdx.x < off) red[threadIdx.x] += red[threadIdx.x + off];
        __syncthreads();
    }
    if (threadIdx.x == 0) Ksum[((size_t)b * 3 + br) * M_ + m] = red[0];
}

// ---------------------------------------------------------------------------
// Kernel 3a (MFMA): split-N partial KX via bf16 matrix cores.
// ---------------------------------------------------------------------------
__global__ __launch_bounds__(256) void kx_mfma_kernel(const float* __restrict__ Kbuf,
                                                      const float* __restrict__ x,
                                                      float* __restrict__ KXpart)
{
    const int c0 = blockIdx.x * 32;
    const int nc = blockIdx.y;
    const int b  = blockIdx.z;
    const int nbeg = nc * (N_ / NCHUNK_);

    __shared__ short Klds[64][72];   // 64 bf16 + 8 pad per row (144 B stride)
    __shared__ short Xlds[32][72];

    const int tid  = threadIdx.x;
    const int lane = tid & 63;
    const int w    = tid >> 6;       // wave id 0..3 -> m-tile base w*16
    const int lrow = lane & 15;
    const int lkg  = lane >> 4;      // 0..3 k-group

    const float* kb = Kbuf + (size_t)b * M_ * N_;
    const float* xb = x + ((size_t)b * C_ + c0) * N_;

    f32x4 acc0 = {0.f, 0.f, 0.f, 0.f};
    f32x4 acc1 = {0.f, 0.f, 0.f, 0.f};

    for (int it = 0; it < (N_ / NCHUNK_) / 64; ++it) {
        const int n0 = nbeg + it * 64;
        __syncthreads();   // previous iteration's frag reads done
        #pragma unroll
        for (int i = 0; i < 4; ++i) {
            int f = tid + i * 256;               // 0..1023
            int r = f >> 4, c4 = (f & 15) * 4;
            float4 v = *reinterpret_cast<const float4*>(&kb[(size_t)r * N_ + n0 + c4]);
            short4 s;
            s.x = f2bf(v.x); s.y = f2bf(v.y); s.z = f2bf(v.z); s.w = f2bf(v.w);
            *reinterpret_cast<short4*>(&Klds[r][c4]) = s;
        }
        #pragma unroll
        for (int i = 0; i < 2; ++i) {
            int f = tid + i * 256;               // 0..511
            int r = f >> 4, c4 = (f & 15) * 4;
            float4 v = *reinterpret_cast<const float4*>(&xb[(size_t)r * N_ + n0 + c4]);
            short4 s;
            s.x = f2bf(v.x); s.y = f2bf(v.y); s.z = f2bf(v.z); s.w = f2bf(v.w);
            *reinterpret_cast<short4*>(&Xlds[r][c4]) = s;
        }
        __syncthreads();
        #pragma unroll
        for (int s = 0; s < 2; ++s) {
            bf16x8 a  = *reinterpret_cast<const bf16x8*>(&Klds[w * 16 + lrow][s * 32 + lkg * 8]);
            bf16x8 b0 = *reinterpret_cast<const bf16x8*>(&Xlds[lrow][s * 32 + lkg * 8]);
            bf16x8 b1 = *reinterpret_cast<const bf16x8*>(&Xlds[16 + lrow][s * 32 + lkg * 8]);
            acc0 = __builtin_amdgcn_mfma_f32_16x16x32_bf16(a, b0, acc0, 0, 0, 0);
            acc1 = __builtin_amdgcn_mfma_f32_16x16x32_bf16(a, b1, acc1, 0, 0, 0);
        }
    }

    float* outp = KXpart + ((size_t)nc * B_ + b) * M_ * C_;
    #pragma unroll
    for (int r = 0; r < 4; ++r) {
        int m = w * 16 + lkg * 4 + r;
        outp[(size_t)m * C_ + c0 + lrow]      = acc0[r];
        outp[(size_t)m * C_ + c0 + 16 + lrow] = acc1[r];
    }
}

// ---------------------------------------------------------------------------
// Kernel 3b: reduce partials (fixed order — deterministic).
// ---------------------------------------------------------------------------
__global__ __launch_bounds__(256) void kx_reduce_kernel(const float* __restrict__ KXpart,
                                                        float* __restrict__ KX, int br)
{
    const size_t BMC = (size_t)B_ * M_ * C_;
    size_t i = (size_t)blockIdx.x * 256 + threadIdx.x;
    if (i >= BMC) return;
    float s = 0.f;
    #pragma unroll
    for (int nc = 0; nc < NCHUNK_; ++nc) s += KXpart[nc * BMC + i];
    size_t b = i / ((size_t)M_ * C_);
    size_t rem = i - b * (size_t)M_ * C_;
    KX[((size_t)b * 3 + br) * M_ * C_ + rem] = s;
}

// ---------------------------------------------------------------------------
// Kernel 4: WlWv[c][k] = sum_p Wl[c][p] * Wv[p][k]
// ---------------------------------------------------------------------------
__global__ __launch_bounds__(256) void wlwv_kernel(const float* __restrict__ Wl,
                                                   const float* __restrict__ Wv,
                                                   float* __restrict__ WlWv)
{
    const int k0 = blockIdx.x * 64;
    const int c0 = blockIdx.y * 64;
    __shared__ float As[64][65];
    __shared__ float Bs[64][65];
    const int tid = threadIdx.x;
    const int tx = tid & 15, ty = tid >> 4;
    float acc[4][4] = {};

    for (int p0 = 0; p0 < C_; p0 += 64) {
        for (int l = tid; l < 64 * 64; l += 256) {
            int r = l >> 6, q = l & 63;
            As[r][q] = Wl[(size_t)(c0 + r) * C_ + p0 + q];
            Bs[r][q] = Wv[(size_t)(p0 + r) * C_ + k0 + q];
        }
        __syncthreads();
        #pragma unroll 16
        for (int p = 0; p < 64; ++p) {
            float a[4], bb[4];
            #pragma unroll
            for (int i = 0; i < 4; ++i) a[i] = As[ty * 4 + i][p];
            #pragma unroll
            for (int j = 0; j < 4; ++j) bb[j] = Bs[p][tx * 4 + j];
            #pragma unroll
            for (int i = 0; i < 4; ++i)
                #pragma unroll
                for (int j = 0; j < 4; ++j)
                    acc[i][j] = fmaf(a[i], bb[j], acc[i][j]);
        }
        __syncthreads();
    }
    #pragma unroll
    for (int i = 0; i < 4; ++i)
        #pragma unroll
        for (int j = 0; j < 4; ++j)
            WlWv[(size_t)(c0 + ty * 4 + i) * C_ + k0 + tx * 4 + j] = acc[i][j];
}

// Wlbv[c] = sum_p Wl[c][p] * bv[p]
__global__ __launch_bounds__(256) void wlbv_kernel(const float* __restrict__ Wl,
                                                   const float* __restrict__ bv,
                                                   float* __restrict__ Wlbv)
{
    int c = blockIdx.x * 256 + threadIdx.x;
    if (c < C_) {
        float s = 0.f;
        for (int p = 0; p < C_; ++p) s = fmaf(Wl[(size_t)c * C_ + p], bv[p], s);
        Wlbv[c] = s;
    }
}

// ---------------------------------------------------------------------------
// Kernel 5: Wf[b][br][c][m] = sum_k WlWv[c][k]*KX[b][br][m][k] + Ksum[b][br][m]*Wlbv[c]
// ---------------------------------------------------------------------------
__global__ __launch_bounds__(256) void wfused_kernel(const float* __restrict__ WlWv,
                                                     const float* __restrict__ KX,
                                                     const float* __restrict__ Ksum,
                                                     const float* __restrict__ Wlbv,
                                                     float* __restrict__ Wf)
{
    const int c0 = blockIdx.x * 64;
    const int br = blockIdx.y;
    const int b = blockIdx.z;

    __shared__ float As[64][65];   // WlWv[c][k] chunk
    __shared__ float Bs[64][65];   // KX^T: Bs[kk][m]
    const int tid = threadIdx.x;
    const int tx = tid & 15, ty = tid >> 4;
    float acc[4][4] = {};

    const float* kxb = KX + ((size_t)b * 3 + br) * M_ * C_;  // [m][k]
    for (int k0 = 0; k0 < C_; k0 += 64) {
        for (int l = tid; l < 64 * 64; l += 256) {
            int r = l >> 6, q = l & 63;
            As[r][q] = WlWv[(size_t)(c0 + r) * C_ + k0 + q];
            Bs[q][r] = kxb[(size_t)r * C_ + k0 + q];   // r = m, q = kk
        }
        __syncthreads();
        #pragma unroll 16
        for (int kk = 0; kk < 64; ++kk) {
            float a[4], bb[4];
            #pragma unroll
            for (int i = 0; i < 4; ++i) a[i] = As[ty * 4 + i][kk];
            #pragma unroll
            for (int j = 0; j < 4; ++j) bb[j] = Bs[kk][tx * 4 + j];
            #pragma unroll
            for (int i = 0; i < 4; ++i)
                #pragma unroll
                for (int j = 0; j < 4; ++j)
                    acc[i][j] = fmaf(a[i], bb[j], acc[i][j]);
        }
        __syncthreads();
    }
    const float* ks = Ksum + ((size_t)b * 3 + br) * M_;
    #pragma unroll
    for (int i = 0; i < 4; ++i) {
        int c = c0 + ty * 4 + i;
        float wb = Wlbv[c];
        #pragma unroll
        for (int j = 0; j < 4; ++j) {
            int m = tx * 4 + j;
            Wf[(((size_t)b * 3 + br) * C_ + c) * M_ + m] = acc[i][j] + ks[m] * wb;
        }
    }
}

// ---------------------------------------------------------------------------
// Kernel 6 (MFMA): out[b][c][n] = x[b][c][n] + gamma*( bl[c] +
//    sum_br norm_br[n] * sum_m Wf[b][br][c][m] * QT[b][n][m] )
// ---------------------------------------------------------------------------
__global__ __launch_bounds__(256) void final_mfma_kernel(
    const float* __restrict__ QT, const float* __restrict__ Wf,
    const float* __restrict__ Ksum, const float* __restrict__ x,
    const float* __restrict__ bl, const float* __restrict__ gamma,
    float* __restrict__ out)
{
    const int n0 = blockIdx.x * 64;
    const int c0 = blockIdx.y * 64;
    const int b  = blockIdx.z;

    __shared__ short Qs[64][72];      // [n][m] bf16
    __shared__ short Wfs[3][64][72];  // [br][c][m] bf16
    __shared__ float norms[3][64];
    __shared__ float ksef[3][64];

    const int tid  = threadIdx.x;
    const int lane = tid & 63;
    const int w    = tid >> 6;
    const int lrow = lane & 15;
    const int lkg  = lane >> 4;

    const float* qtb = QT + (size_t)b * N_ * M_;
    #pragma unroll
    for (int i = 0; i < 4; ++i) {
        int f = tid + i * 256;
        int r = f >> 4, m4 = (f & 15) * 4;
        float4 v = *reinterpret_cast<const float4*>(&qtb[(size_t)(n0 + r) * M_ + m4]);
        short4 s;
        s.x = f2bf(v.x); s.y = f2bf(v.y); s.z = f2bf(v.z); s.w = f2bf(v.w);
        *reinterpret_cast<short4*>(&Qs[r][m4]) = s;
    }
    #pragma unroll
    for (int br = 0; br < 3; ++br) {
        const float* wfb = Wf + (((size_t)b * 3 + br) * C_ + c0) * M_;
        #pragma unroll
        for (int i = 0; i < 4; ++i) {
            int f = tid + i * 256;
            int r = f >> 4, m4 = (f & 15) * 4;
            float4 v = *reinterpret_cast<const float4*>(&wfb[(size_t)r * M_ + m4]);
            short4 s;
            s.x = f2bf(v.x); s.y = f2bf(v.y); s.z = f2bf(v.z); s.w = f2bf(v.w);
            *reinterpret_cast<short4*>(&Wfs[br][r][m4]) = s;
        }
    }
    if (tid < 192) {
        int br = tid >> 6, m = tid & 63;
        ksef[br][m] = Ksum[((size_t)b * 3 + br) * M_ + m] + EPS_;
    }
    __syncthreads();
    if (tid < 192) {
        int br = tid >> 6, n = tid & 63;
        float s = 0.f;
        #pragma unroll 16
        for (int m = 0; m < 64; ++m) s = fmaf(bf2f(Qs[n][m]), ksef[br][m], s);
        norms[br][n] = 1.0f / s;
    }
    __syncthreads();

    f32x4 tot[4] = {{0.f,0.f,0.f,0.f},{0.f,0.f,0.f,0.f},{0.f,0.f,0.f,0.f},{0.f,0.f,0.f,0.f}};
    for (int br = 0; br < 3; ++br) {
        f32x4 acc[4] = {{0.f,0.f,0.f,0.f},{0.f,0.f,0.f,0.f},{0.f,0.f,0.f,0.f},{0.f,0.f,0.f,0.f}};
        #pragma unroll
        for (int ks = 0; ks < 2; ++ks) {
            bf16x8 a = *reinterpret_cast<const bf16x8*>(&Wfs[br][w * 16 + lrow][ks * 32 + lkg * 8]);
            #pragma unroll
            for (int ns = 0; ns < 4; ++ns) {
                bf16x8 bq = *reinterpret_cast<const bf16x8*>(&Qs[ns * 16 + lrow][ks * 32 + lkg * 8]);
                acc[ns] = __builtin_amdgcn_mfma_f32_16x16x32_bf16(a, bq, acc[ns], 0, 0, 0);
            }
        }
        #pragma unroll
        for (int ns = 0; ns < 4; ++ns) {
            float nf = norms[br][ns * 16 + lrow];
            #pragma unroll
            for (int r = 0; r < 4; ++r) tot[ns][r] = fmaf(nf, acc[ns][r], tot[ns][r]);
        }
    }

    const float g = gamma[0];
    const float* xb = x + (size_t)b * C_ * N_;
    float* ob = out + (size_t)b * C_ * N_;
    #pragma unroll
    for (int r = 0; r < 4; ++r) {
        int c = c0 + w * 16 + lkg * 4 + r;
        float blc = bl[c];
        #pragma unroll
        for (int ns = 0; ns < 4; ++ns) {
            int n = n0 + ns * 16 + lrow;
            ob[(size_t)c * N_ + n] = fmaf(g, tot[ns][r] + blc, xb[(size_t)c * N_ + n]);
        }
    }
}

// ---------------------------------------------------------------------------
extern "C" void kernel_launch(void* const* d_in, const int* in_sizes, int n_in,
                              void* d_out, int out_size, void* d_ws, size_t ws_size,
                              hipStream_t stream)
{
    const float* x   = (const float*)d_in[0];
    const float* y   = (const float*)d_in[1];
    const float* z   = (const float*)d_in[2];
    const float* Wq  = (const float*)d_in[3];
    const float* bq  = (const float*)d_in[4];
    const float* Wk1 = (const float*)d_in[5];
    const float* bk1 = (const float*)d_in[6];
    const float* Wk2 = (const float*)d_in[7];
    const float* bk2 = (const float*)d_in[8];
    const float* Wk3 = (const float*)d_in[9];
    const float* bk3 = (const float*)d_in[10];
    const float* Wv  = (const float*)d_in[11];
    const float* bv  = (const float*)d_in[12];
    const float* Wl  = (const float*)d_in[13];
    const float* bl  = (const float*)d_in[14];
    const float* gamma = (const float*)d_in[15];
    float* out = (float*)d_out;

    // workspace layout (floats) — total 6,293,504 floats = 25.2 MB (unchanged).
    float* ws = (float*)d_ws;
    const size_t QSZ  = (size_t)B_ * M_ * N_;        // 2,097,152
    const size_t BMC  = (size_t)B_ * M_ * C_;        //   262,144
    float* QT   = ws;                                 // [B][N][M]
    float* Kbuf = QT + QSZ;                           // [B][M][N] (reused per branch)
    float* KX   = Kbuf + QSZ;                         // [B][3][M][C]
    float* Ksum = KX + 3 * BMC;                       // [B][3][M]
    float* WlWv = Ksum + (size_t)B_ * 3 * M_;         // [C][C]
    float* Wlbv = WlWv + (size_t)C_ * C_;             // [C]
    float* KXpart = Wlbv + C_;                        // [NCHUNK][B][M][C]  (4 MB)
    float* Wf   = KXpart;                             // [B][3][C][M]       (3 MB, aliased)

    dim3 blk(256);
    const dim3 featGrid(N_ / 64, 1, B_);

    // Q features (transposed output)
    feat_mfma<<<featGrid, blk, 0, stream>>>(x, Wq, bq, QT, 1);

    // K branches, sequenced through Kbuf
    const float* kin[3]  = { x, y, z };
    const float* kW[3]   = { Wk1, Wk2, Wk3 };
    const float* kb_[3]  = { bk1, bk2, bk3 };
    for (int br = 0; br < 3; ++br) {
        feat_mfma<<<featGrid, blk, 0, stream>>>(kin[br], kW[br], kb_[br], Kbuf, 0);
        ksum_kernel<<<dim3(M_, 1, B_), blk, 0, stream>>>(Kbuf, Ksum, br);
        kx_mfma_kernel<<<dim3(C_ / 32, NCHUNK_, B_), blk, 0, stream>>>(Kbuf, x, KXpart);
        kx_reduce_kernel<<<dim3((BMC + 255) / 256), blk, 0, stream>>>(KXpart, KX, br);
    }

    // batch-independent fused weights
    wlwv_kernel<<<dim3(C_ / 64, C_ / 64), blk, 0, stream>>>(Wl, Wv, WlWv);
    wlbv_kernel<<<dim3((C_ + 255) / 256), blk, 0, stream>>>(Wl, bv, Wlbv);
    // per-batch fused weights
    wfused_kernel<<<dim3(C_ / 64, 3, B_), blk, 0, stream>>>(WlWv, KX, Ksum, Wlbv, Wf);
    // final: norms + MFMA GEMM + bias + residual
    final_mfma_kernel<<<dim3(N_ / 64, C_ / 64, B_), blk, 0, stream>>>(
        QT, Wf, Ksum, x, bl, gamma, out);
}

// Round 11
// 248.212 us; speedup vs baseline: 7.7421x; 1.1304x over previous
//
#include <hip/hip_runtime.h>
#include <hip/hip_bf16.h>
#include <math.h>

// Problem constants
constexpr int B_ = 8;
constexpr int C_ = 512;
constexpr int M_ = 64;     // C/8
constexpr int N_ = 4096;   // H*W
constexpr int NCHUNK_ = 4; // split-N factor for kx
constexpr float EPS_ = 1e-10f;
constexpr float PARAM_ = 10.0f;

typedef __attribute__((ext_vector_type(4))) float f32x4;
typedef __attribute__((ext_vector_type(8))) short bf16x8;   // 8 bf16 in 4 VGPRs

// elus feature map: t>0 ? 10t+1 : exp(10t)
__device__ __forceinline__ float elus(float t) {
    return (t > 0.f) ? fmaf(PARAM_, t, 1.f) : expf(PARAM_ * t);
}

// fp32 -> bf16 round-to-nearest-even (finite inputs only)
__device__ __forceinline__ short f2bf(float f) {
    unsigned u = __builtin_bit_cast(unsigned, f);
    u += 0x7FFFu + ((u >> 16) & 1u);
    return (short)(u >> 16);
}
// bf16 bits -> fp32
__device__ __forceinline__ float bf2f(short s) {
    unsigned u = ((unsigned)(unsigned short)s) << 16;
    return __builtin_bit_cast(float, u);
}

// ---------------------------------------------------------------------------
// Kernel 1 (MFMA): feature GEMM out = elus(W @ in + bias).
// tq=0: out[b][m][n].  tq=1: out[b][n][m] (QT, float4 along m).
// ---------------------------------------------------------------------------
__global__ __launch_bounds__(256) void feat_mfma(
    const float* __restrict__ in, const float* __restrict__ W,
    const float* __restrict__ bias, float* __restrict__ out, int tq)
{
    const int n0 = blockIdx.x * 64;
    const int b  = blockIdx.z;

    __shared__ short Wlds[64][72];   // [m][k] bf16, 144B row stride
    __shared__ short Xlds[64][72];   // [n][k] bf16 (transposed tile)

    const int tid  = threadIdx.x;
    const int lane = tid & 63;
    const int w    = tid >> 6;       // wave id 0..3 -> m rows w*16..+15
    const int lrow = lane & 15;
    const int lkg  = lane >> 4;

    const float* inb = in + (size_t)b * C_ * N_;

    f32x4 acc[4] = {{0.f,0.f,0.f,0.f},{0.f,0.f,0.f,0.f},{0.f,0.f,0.f,0.f},{0.f,0.f,0.f,0.f}};

    const int kq = tid >> 4;   // 0..15 -> k base kq*4 (X transpose staging)
    const int nq = tid & 15;   // 0..15 -> n base nq*4

    for (int kc = 0; kc < C_ / 64; ++kc) {
        const int k0 = kc * 64;
        __syncthreads();   // previous chunk's frag reads done
        #pragma unroll
        for (int i = 0; i < 4; ++i) {
            int f = tid + i * 256;
            int r = f >> 4, c4 = (f & 15) * 4;
            f32x4 v = *reinterpret_cast<const f32x4*>(&W[(size_t)r * C_ + k0 + c4]);
            short4 s;
            s.x = f2bf(v[0]); s.y = f2bf(v[1]); s.z = f2bf(v[2]); s.w = f2bf(v[3]);
            *reinterpret_cast<short4*>(&Wlds[r][c4]) = s;
        }
        f32x4 v0 = *reinterpret_cast<const f32x4*>(&inb[(size_t)(k0 + kq * 4 + 0) * N_ + n0 + nq * 4]);
        f32x4 v1 = *reinterpret_cast<const f32x4*>(&inb[(size_t)(k0 + kq * 4 + 1) * N_ + n0 + nq * 4]);
        f32x4 v2 = *reinterpret_cast<const f32x4*>(&inb[(size_t)(k0 + kq * 4 + 2) * N_ + n0 + nq * 4]);
        f32x4 v3 = *reinterpret_cast<const f32x4*>(&inb[(size_t)(k0 + kq * 4 + 3) * N_ + n0 + nq * 4]);
        #pragma unroll
        for (int c = 0; c < 4; ++c) {
            short4 s;
            s.x = f2bf(v0[c]); s.y = f2bf(v1[c]); s.z = f2bf(v2[c]); s.w = f2bf(v3[c]);
            *reinterpret_cast<short4*>(&Xlds[nq * 4 + c][kq * 4]) = s;
        }
        __syncthreads();
        #pragma unroll
        for (int ks = 0; ks < 2; ++ks) {
            bf16x8 a = *reinterpret_cast<const bf16x8*>(&Wlds[w * 16 + lrow][ks * 32 + lkg * 8]);
            #pragma unroll
            for (int ns = 0; ns < 4; ++ns) {
                bf16x8 bx = *reinterpret_cast<const bf16x8*>(&Xlds[ns * 16 + lrow][ks * 32 + lkg * 8]);
                acc[ns] = __builtin_amdgcn_mfma_f32_16x16x32_bf16(a, bx, acc[ns], 0, 0, 0);
            }
        }
    }

    if (!tq) {
        float* outb = out + (size_t)b * M_ * N_;
        #pragma unroll
        for (int r = 0; r < 4; ++r) {
            int m = w * 16 + lkg * 4 + r;
            float bi = bias[m];
            #pragma unroll
            for (int ns = 0; ns < 4; ++ns) {
                int n = n0 + ns * 16 + lrow;
                outb[(size_t)m * N_ + n] = elus(acc[ns][r] + bi);
            }
        }
    } else {
        float* outb = out + (size_t)b * N_ * M_;
        int mbase = w * 16 + lkg * 4;
        float bi[4];
        #pragma unroll
        for (int r = 0; r < 4; ++r) bi[r] = bias[mbase + r];
        #pragma unroll
        for (int ns = 0; ns < 4; ++ns) {
            int n = n0 + ns * 16 + lrow;
            f32x4 v;
            #pragma unroll
            for (int r = 0; r < 4; ++r) v[r] = elus(acc[ns][r] + bi[r]);
            *reinterpret_cast<f32x4*>(&outb[(size_t)n * M_ + mbase]) = v;
        }
    }
}

// ---------------------------------------------------------------------------
// Kernel 2: Ksum[b][br][m] = sum_n Kbuf[b][m][n]
// ---------------------------------------------------------------------------
__global__ __launch_bounds__(256) void ksum_kernel(const float* __restrict__ Kbuf,
                                                   float* __restrict__ Ksum, int br)
{
    const int m = blockIdx.x;   // 0..63
    const int b = blockIdx.z;   // 0..7
    const float* row = Kbuf + ((size_t)b * M_ + m) * N_;
    float s = 0.f;
    for (int n = threadIdx.x; n < N_; n += 256) s += row[n];
    __shared__ float red[256];
    red[threadIdx.x] = s;
    __syncthreads();
    for (int off = 128; off > 0; off >>= 1) {
        if (threadIdx.x < off) red[threadIdx.x] += red[threadIdx.x + off];
        __syncthreads();
    }
    if (threadIdx.x == 0) Ksum[((size_t)b * 3 + br) * M_ + m] = red[0];
}

// ---------------------------------------------------------------------------
// Kernel 3a (MFMA): split-N partial KX via bf16 matrix cores.
// ---------------------------------------------------------------------------
__global__ __launch_bounds__(256) void kx_mfma_kernel(const float* __restrict__ Kbuf,
                                                      const float* __restrict__ x,
                                                      float* __restrict__ KXpart)
{
    const int c0 = blockIdx.x * 32;
    const int nc = blockIdx.y;
    const int b  = blockIdx.z;
    const int nbeg = nc * (N_ / NCHUNK_);

    __shared__ short Klds[64][72];   // 64 bf16 + 8 pad per row (144 B stride)
    __shared__ short Xlds[32][72];

    const int tid  = threadIdx.x;
    const int lane = tid & 63;
    const int w    = tid >> 6;       // wave id 0..3 -> m-tile base w*16
    const int lrow = lane & 15;
    const int lkg  = lane >> 4;      // 0..3 k-group

    const float* kb = Kbuf + (size_t)b * M_ * N_;
    const float* xb = x + ((size_t)b * C_ + c0) * N_;

    f32x4 acc0 = {0.f, 0.f, 0.f, 0.f};
    f32x4 acc1 = {0.f, 0.f, 0.f, 0.f};

    for (int it = 0; it < (N_ / NCHUNK_) / 64; ++it) {
        const int n0 = nbeg + it * 64;
        __syncthreads();   // previous iteration's frag reads done
        #pragma unroll
        for (int i = 0; i < 4; ++i) {
            int f = tid + i * 256;               // 0..1023
            int r = f >> 4, c4 = (f & 15) * 4;
            float4 v = *reinterpret_cast<const float4*>(&kb[(size_t)r * N_ + n0 + c4]);
            short4 s;
            s.x = f2bf(v.x); s.y = f2bf(v.y); s.z = f2bf(v.z); s.w = f2bf(v.w);
            *reinterpret_cast<short4*>(&Klds[r][c4]) = s;
        }
        #pragma unroll
        for (int i = 0; i < 2; ++i) {
            int f = tid + i * 256;               // 0..511
            int r = f >> 4, c4 = (f & 15) * 4;
            float4 v = *reinterpret_cast<const float4*>(&xb[(size_t)r * N_ + n0 + c4]);
            short4 s;
            s.x = f2bf(v.x); s.y = f2bf(v.y); s.z = f2bf(v.z); s.w = f2bf(v.w);
            *reinterpret_cast<short4*>(&Xlds[r][c4]) = s;
        }
        __syncthreads();
        #pragma unroll
        for (int s = 0; s < 2; ++s) {
            bf16x8 a  = *reinterpret_cast<const bf16x8*>(&Klds[w * 16 + lrow][s * 32 + lkg * 8]);
            bf16x8 b0 = *reinterpret_cast<const bf16x8*>(&Xlds[lrow][s * 32 + lkg * 8]);
            bf16x8 b1 = *reinterpret_cast<const bf16x8*>(&Xlds[16 + lrow][s * 32 + lkg * 8]);
            acc0 = __builtin_amdgcn_mfma_f32_16x16x32_bf16(a, b0, acc0, 0, 0, 0);
            acc1 = __builtin_amdgcn_mfma_f32_16x16x32_bf16(a, b1, acc1, 0, 0, 0);
        }
    }

    float* outp = KXpart + ((size_t)nc * B_ + b) * M_ * C_;
    #pragma unroll
    for (int r = 0; r < 4; ++r) {
        int m = w * 16 + lkg * 4 + r;
        outp[(size_t)m * C_ + c0 + lrow]      = acc0[r];
        outp[(size_t)m * C_ + c0 + 16 + lrow] = acc1[r];
    }
}

// ---------------------------------------------------------------------------
// Kernel 3b: reduce partials (fixed order — deterministic).
// ---------------------------------------------------------------------------
__global__ __launch_bounds__(256) void kx_reduce_kernel(const float* __restrict__ KXpart,
                                                        float* __restrict__ KX, int br)
{
    const size_t BMC = (size_t)B_ * M_ * C_;
    size_t i = (size_t)blockIdx.x * 256 + threadIdx.x;
    if (i >= BMC) return;
    float s = 0.f;
    #pragma unroll
    for (int nc = 0; nc < NCHUNK_; ++nc) s += KXpart[nc * BMC + i];
    size_t b = i / ((size_t)M_ * C_);
    size_t rem = i - b * (size_t)M_ * C_;
    KX[((size_t)b * 3 + br) * M_ * C_ + rem] = s;
}

// ---------------------------------------------------------------------------
// Kernel 4a (MFMA): WlWvPart[pc][c][k] = sum_{p in chunk pc} Wl[c][p]*Wv[p][k]
// Grid (C/64 k-tiles, C/64 c-tiles, 4 pc) = 256 blocks (old fp32 version: 64
// blocks, 2.5% occupancy, 45 us — latency-bound).  A = Wl (p-contig native);
// B = WvT via in-register 4x4 transpose.  Proven [64][72] 0-conflict pattern.
// ---------------------------------------------------------------------------
__global__ __launch_bounds__(256) void wlwv_mfma(const float* __restrict__ Wl,
                                                 const float* __restrict__ Wv,
                                                 float* __restrict__ part)
{
    const int k0 = blockIdx.x * 64;
    const int c0 = blockIdx.y * 64;
    const int pc = blockIdx.z;       // p chunk: p = pc*128 .. +128

    __shared__ short Al[64][72];     // Wl[c][p] bf16
    __shared__ short Bt[64][72];     // WvT[k][p] bf16

    const int tid  = threadIdx.x;
    const int lane = tid & 63;
    const int w    = tid >> 6;
    const int lrow = lane & 15;
    const int lkg  = lane >> 4;
    const int pq = tid >> 4;   // 0..15: p base pq*4 (transpose staging)
    const int nq = tid & 15;   // 0..15: k base nq*4

    f32x4 acc[4] = {{0.f,0.f,0.f,0.f},{0.f,0.f,0.f,0.f},{0.f,0.f,0.f,0.f},{0.f,0.f,0.f,0.f}};

    for (int it = 0; it < 2; ++it) {
        const int p0 = pc * 128 + it * 64;
        __syncthreads();
        #pragma unroll
        for (int i = 0; i < 4; ++i) {
            int f = tid + i * 256;
            int r = f >> 4, c4 = (f & 15) * 4;
            f32x4 v = *reinterpret_cast<const f32x4*>(&Wl[(size_t)(c0 + r) * C_ + p0 + c4]);
            short4 s;
            s.x = f2bf(v[0]); s.y = f2bf(v[1]); s.z = f2bf(v[2]); s.w = f2bf(v[3]);
            *reinterpret_cast<short4*>(&Al[r][c4]) = s;
        }
        f32x4 v0 = *reinterpret_cast<const f32x4*>(&Wv[(size_t)(p0 + pq * 4 + 0) * C_ + k0 + nq * 4]);
        f32x4 v1 = *reinterpret_cast<const f32x4*>(&Wv[(size_t)(p0 + pq * 4 + 1) * C_ + k0 + nq * 4]);
        f32x4 v2 = *reinterpret_cast<const f32x4*>(&Wv[(size_t)(p0 + pq * 4 + 2) * C_ + k0 + nq * 4]);
        f32x4 v3 = *reinterpret_cast<const f32x4*>(&Wv[(size_t)(p0 + pq * 4 + 3) * C_ + k0 + nq * 4]);
        #pragma unroll
        for (int c = 0; c < 4; ++c) {
            short4 s;
            s.x = f2bf(v0[c]); s.y = f2bf(v1[c]); s.z = f2bf(v2[c]); s.w = f2bf(v3[c]);
            *reinterpret_cast<short4*>(&Bt[nq * 4 + c][pq * 4]) = s;
        }
        __syncthreads();
        #pragma unroll
        for (int ks = 0; ks < 2; ++ks) {
            bf16x8 a = *reinterpret_cast<const bf16x8*>(&Al[w * 16 + lrow][ks * 32 + lkg * 8]);
            #pragma unroll
            for (int ns = 0; ns < 4; ++ns) {
                bf16x8 bx = *reinterpret_cast<const bf16x8*>(&Bt[ns * 16 + lrow][ks * 32 + lkg * 8]);
                acc[ns] = __builtin_amdgcn_mfma_f32_16x16x32_bf16(a, bx, acc[ns], 0, 0, 0);
            }
        }
    }

    float* pp = part + (size_t)pc * C_ * C_;
    #pragma unroll
    for (int r = 0; r < 4; ++r) {
        int c = c0 + w * 16 + lkg * 4 + r;
        #pragma unroll
        for (int ns = 0; ns < 4; ++ns) {
            int k = k0 + ns * 16 + lrow;
            pp[(size_t)c * C_ + k] = acc[ns][r];
        }
    }
}

// Kernel 4b: WlWv[i] = sum_pc part[pc][i]  (fixed order — deterministic)
__global__ __launch_bounds__(256) void wlwv_reduce(const float* __restrict__ part,
                                                   float* __restrict__ WlWv)
{
    const size_t CC = (size_t)C_ * C_;
    size_t i = (size_t)blockIdx.x * 256 + threadIdx.x;
    if (i >= CC) return;
    float s = 0.f;
    #pragma unroll
    for (int pc = 0; pc < 4; ++pc) s += part[pc * CC + i];
    WlWv[i] = s;
}

// Wlbv[c] = sum_p Wl[c][p] * bv[p]
__global__ __launch_bounds__(256) void wlbv_kernel(const float* __restrict__ Wl,
                                                   const float* __restrict__ bv,
                                                   float* __restrict__ Wlbv)
{
    int c = blockIdx.x * 256 + threadIdx.x;
    if (c < C_) {
        float s = 0.f;
        for (int p = 0; p < C_; ++p) s = fmaf(Wl[(size_t)c * C_ + p], bv[p], s);
        Wlbv[c] = s;
    }
}

// ---------------------------------------------------------------------------
// Kernel 5: Wf[b][br][c][m] = sum_k WlWv[c][k]*KX[b][br][m][k] + Ksum[b][br][m]*Wlbv[c]
// ---------------------------------------------------------------------------
__global__ __launch_bounds__(256) void wfused_kernel(const float* __restrict__ WlWv,
                                                     const float* __restrict__ KX,
                                                     const float* __restrict__ Ksum,
                                                     const float* __restrict__ Wlbv,
                                                     float* __restrict__ Wf)
{
    const int c0 = blockIdx.x * 64;
    const int br = blockIdx.y;
    const int b = blockIdx.z;

    __shared__ float As[64][65];   // WlWv[c][k] chunk
    __shared__ float Bs[64][65];   // KX^T: Bs[kk][m]
    const int tid = threadIdx.x;
    const int tx = tid & 15, ty = tid >> 4;
    float acc[4][4] = {};

    const float* kxb = KX + ((size_t)b * 3 + br) * M_ * C_;  // [m][k]
    for (int k0 = 0; k0 < C_; k0 += 64) {
        for (int l = tid; l < 64 * 64; l += 256) {
            int r = l >> 6, q = l & 63;
            As[r][q] = WlWv[(size_t)(c0 + r) * C_ + k0 + q];
            Bs[q][r] = kxb[(size_t)r * C_ + k0 + q];   // r = m, q = kk
        }
        __syncthreads();
        #pragma unroll 16
        for (int kk = 0; kk < 64; ++kk) {
            float a[4], bb[4];
            #pragma unroll
            for (int i = 0; i < 4; ++i) a[i] = As[ty * 4 + i][kk];
            #pragma unroll
            for (int j = 0; j < 4; ++j) bb[j] = Bs[kk][tx * 4 + j];
            #pragma unroll
            for (int i = 0; i < 4; ++i)
                #pragma unroll
                for (int j = 0; j < 4; ++j)
                    acc[i][j] = fmaf(a[i], bb[j], acc[i][j]);
        }
        __syncthreads();
    }
    const float* ks = Ksum + ((size_t)b * 3 + br) * M_;
    #pragma unroll
    for (int i = 0; i < 4; ++i) {
        int c = c0 + ty * 4 + i;
        float wb = Wlbv[c];
        #pragma unroll
        for (int j = 0; j < 4; ++j) {
            int m = tx * 4 + j;
            Wf[(((size_t)b * 3 + br) * C_ + c) * M_ + m] = acc[i][j] + ks[m] * wb;
        }
    }
}

// ---------------------------------------------------------------------------
// Kernel 6 (MFMA): out[b][c][n] = x[b][c][n] + gamma*( bl[c] +
//    sum_br norm_br[n] * sum_m Wf[b][br][c][m] * QT[b][n][m] )
// ---------------------------------------------------------------------------
__global__ __launch_bounds__(256) void final_mfma_kernel(
    const float* __restrict__ QT, const float* __restrict__ Wf,
    const float* __restrict__ Ksum, const float* __restrict__ x,
    const float* __restrict__ bl, const float* __restrict__ gamma,
    float* __restrict__ out)
{
    const int n0 = blockIdx.x * 64;
    const int c0 = blockIdx.y * 64;
    const int b  = blockIdx.z;

    __shared__ short Qs[64][72];      // [n][m] bf16
    __shared__ short Wfs[3][64][72];  // [br][c][m] bf16
    __shared__ float norms[3][64];
    __shared__ float ksef[3][64];

    const int tid  = threadIdx.x;
    const int lane = tid & 63;
    const int w    = tid >> 6;
    const int lrow = lane & 15;
    const int lkg  = lane >> 4;

    const float* qtb = QT + (size_t)b * N_ * M_;
    #pragma unroll
    for (int i = 0; i < 4; ++i) {
        int f = tid + i * 256;
        int r = f >> 4, m4 = (f & 15) * 4;
        float4 v = *reinterpret_cast<const float4*>(&qtb[(size_t)(n0 + r) * M_ + m4]);
        short4 s;
        s.x = f2bf(v.x); s.y = f2bf(v.y); s.z = f2bf(v.z); s.w = f2bf(v.w);
        *reinterpret_cast<short4*>(&Qs[r][m4]) = s;
    }
    #pragma unroll
    for (int br = 0; br < 3; ++br) {
        const float* wfb = Wf + (((size_t)b * 3 + br) * C_ + c0) * M_;
        #pragma unroll
        for (int i = 0; i < 4; ++i) {
            int f = tid + i * 256;
            int r = f >> 4, m4 = (f & 15) * 4;
            float4 v = *reinterpret_cast<const float4*>(&wfb[(size_t)r * M_ + m4]);
            short4 s;
            s.x = f2bf(v.x); s.y = f2bf(v.y); s.z = f2bf(v.z); s.w = f2bf(v.w);
            *reinterpret_cast<short4*>(&Wfs[br][r][m4]) = s;
        }
    }
    if (tid < 192) {
        int br = tid >> 6, m = tid & 63;
        ksef[br][m] = Ksum[((size_t)b * 3 + br) * M_ + m] + EPS_;
    }
    __syncthreads();
    if (tid < 192) {
        int br = tid >> 6, n = tid & 63;
        float s = 0.f;
        #pragma unroll 16
        for (int m = 0; m < 64; ++m) s = fmaf(bf2f(Qs[n][m]), ksef[br][m], s);
        norms[br][n] = 1.0f / s;
    }
    __syncthreads();

    f32x4 tot[4] = {{0.f,0.f,0.f,0.f},{0.f,0.f,0.f,0.f},{0.f,0.f,0.f,0.f},{0.f,0.f,0.f,0.f}};
    for (int br = 0; br < 3; ++br) {
        f32x4 acc[4] = {{0.f,0.f,0.f,0.f},{0.f,0.f,0.f,0.f},{0.f,0.f,0.f,0.f},{0.f,0.f,0.f,0.f}};
        #pragma unroll
        for (int ks = 0; ks < 2; ++ks) {
            bf16x8 a = *reinterpret_cast<const bf16x8*>(&Wfs[br][w * 16 + lrow][ks * 32 + lkg * 8]);
            #pragma unroll
            for (int ns = 0; ns < 4; ++ns) {
                bf16x8 bq = *reinterpret_cast<const bf16x8*>(&Qs[ns * 16 + lrow][ks * 32 + lkg * 8]);
                acc[ns] = __builtin_amdgcn_mfma_f32_16x16x32_bf16(a, bq, acc[ns], 0, 0, 0);
            }
        }
        #pragma unroll
        for (int ns = 0; ns < 4; ++ns) {
            float nf = norms[br][ns * 16 + lrow];
            #pragma unroll
            for (int r = 0; r < 4; ++r) tot[ns][r] = fmaf(nf, acc[ns][r], tot[ns][r]);
        }
    }

    const float g = gamma[0];
    const float* xb = x + (size_t)b * C_ * N_;
    float* ob = out + (size_t)b * C_ * N_;
    #pragma unroll
    for (int r = 0; r < 4; ++r) {
        int c = c0 + w * 16 + lkg * 4 + r;
        float blc = bl[c];
        #pragma unroll
        for (int ns = 0; ns < 4; ++ns) {
            int n = n0 + ns * 16 + lrow;
            ob[(size_t)c * N_ + n] = fmaf(g, tot[ns][r] + blc, xb[(size_t)c * N_ + n]);
        }
    }
}

// ---------------------------------------------------------------------------
extern "C" void kernel_launch(void* const* d_in, const int* in_sizes, int n_in,
                              void* d_out, int out_size, void* d_ws, size_t ws_size,
                              hipStream_t stream)
{
    const float* x   = (const float*)d_in[0];
    const float* y   = (const float*)d_in[1];
    const float* z   = (const float*)d_in[2];
    const float* Wq  = (const float*)d_in[3];
    const float* bq  = (const float*)d_in[4];
    const float* Wk1 = (const float*)d_in[5];
    const float* bk1 = (const float*)d_in[6];
    const float* Wk2 = (const float*)d_in[7];
    const float* bk2 = (const float*)d_in[8];
    const float* Wk3 = (const float*)d_in[9];
    const float* bk3 = (const float*)d_in[10];
    const float* Wv  = (const float*)d_in[11];
    const float* bv  = (const float*)d_in[12];
    const float* Wl  = (const float*)d_in[13];
    const float* bl  = (const float*)d_in[14];
    const float* gamma = (const float*)d_in[15];
    float* out = (float*)d_out;

    // workspace layout (floats) — total 6,293,504 floats = 25.2 MB (unchanged).
    // KXpart slot (1,048,576 floats) is time-multiplexed:
    //   branch loop:   KXpart[NCHUNK][B][M][C]   (kx partials)
    //   wlwv phase:    WlWvPart[4][C][C]         (exactly the same size)
    //   wfused/final:  Wf[B][3][C][M]            (3 MB)
    float* ws = (float*)d_ws;
    const size_t QSZ  = (size_t)B_ * M_ * N_;        // 2,097,152
    const size_t BMC  = (size_t)B_ * M_ * C_;        //   262,144
    float* QT   = ws;                                 // [B][N][M]
    float* Kbuf = QT + QSZ;                           // [B][M][N] (reused per branch)
    float* KX   = Kbuf + QSZ;                         // [B][3][M][C]
    float* Ksum = KX + 3 * BMC;                       // [B][3][M]
    float* WlWv = Ksum + (size_t)B_ * 3 * M_;         // [C][C]
    float* Wlbv = WlWv + (size_t)C_ * C_;             // [C]
    float* KXpart = Wlbv + C_;                        // shared slot (4 MB)
    float* WlWvPart = KXpart;                         // alias
    float* Wf   = KXpart;                             // alias

    dim3 blk(256);
    const dim3 featGrid(N_ / 64, 1, B_);

    // Q features (transposed output)
    feat_mfma<<<featGrid, blk, 0, stream>>>(x, Wq, bq, QT, 1);

    // K branches, sequenced through Kbuf
    const float* kin[3]  = { x, y, z };
    const float* kW[3]   = { Wk1, Wk2, Wk3 };
    const float* kb_[3]  = { bk1, bk2, bk3 };
    for (int br = 0; br < 3; ++br) {
        feat_mfma<<<featGrid, blk, 0, stream>>>(kin[br], kW[br], kb_[br], Kbuf, 0);
        ksum_kernel<<<dim3(M_, 1, B_), blk, 0, stream>>>(Kbuf, Ksum, br);
        kx_mfma_kernel<<<dim3(C_ / 32, NCHUNK_, B_), blk, 0, stream>>>(Kbuf, x, KXpart);
        kx_reduce_kernel<<<dim3((BMC + 255) / 256), blk, 0, stream>>>(KXpart, KX, br);
    }

    // batch-independent fused weights (MFMA + split-p; partials reuse KXpart slot,
    // which is dead after the last kx_reduce)
    wlwv_mfma<<<dim3(C_ / 64, C_ / 64, 4), blk, 0, stream>>>(Wl, Wv, WlWvPart);
    wlwv_reduce<<<dim3(((int)((size_t)C_ * C_) + 255) / 256), blk, 0, stream>>>(WlWvPart, WlWv);
    wlbv_kernel<<<dim3((C_ + 255) / 256), blk, 0, stream>>>(Wl, bv, Wlbv);
    // per-batch fused weights (overwrites the shared slot with Wf — partials dead)
    wfused_kernel<<<dim3(C_ / 64, 3, B_), blk, 0, stream>>>(WlWv, KX, Ksum, Wlbv, Wf);
    // final: norms + MFMA GEMM + bias + residual
    final_mfma_kernel<<<dim3(N_ / 64, C_ / 64, B_), blk, 0, stream>>>(
        QT, Wf, Ksum, x, bl, gamma, out);
}

// Round 12
// 235.227 us; speedup vs baseline: 8.1695x; 1.0552x over previous
//
#include <hip/hip_runtime.h>
#include <hip/hip_bf16.h>
#include <math.h>

// Problem constants
constexpr int B_ = 8;
constexpr int C_ = 512;
constexpr int M_ = 64;     // C/8
constexpr int N_ = 4096;   // H*W
constexpr int NCHUNK_ = 4; // split-N factor for kx
constexpr float EPS_ = 1e-10f;
constexpr float PARAM_ = 10.0f;

typedef __attribute__((ext_vector_type(4))) float f32x4;
typedef __attribute__((ext_vector_type(8))) short bf16x8;   // 8 bf16 in 4 VGPRs

// elus feature map: t>0 ? 10t+1 : exp(10t)
__device__ __forceinline__ float elus(float t) {
    return (t > 0.f) ? fmaf(PARAM_, t, 1.f) : expf(PARAM_ * t);
}

// fp32 -> bf16 round-to-nearest-even (finite inputs only)
__device__ __forceinline__ short f2bf(float f) {
    unsigned u = __builtin_bit_cast(unsigned, f);
    u += 0x7FFFu + ((u >> 16) & 1u);
    return (short)(u >> 16);
}
// bf16 bits -> fp32
__device__ __forceinline__ float bf2f(short s) {
    unsigned u = ((unsigned)(unsigned short)s) << 16;
    return __builtin_bit_cast(float, u);
}

// ---------------------------------------------------------------------------
// Kernel 1 (MFMA): feature GEMM out = elus(W @ in + bias).
// tq=0: out[b][m][n].  tq=1: out[b][n][m] (QT, float4 along m).
// ---------------------------------------------------------------------------
__global__ __launch_bounds__(256) void feat_mfma(
    const float* __restrict__ in, const float* __restrict__ W,
    const float* __restrict__ bias, float* __restrict__ out, int tq)
{
    const int n0 = blockIdx.x * 64;
    const int b  = blockIdx.z;

    __shared__ short Wlds[64][72];   // [m][k] bf16, 144B row stride
    __shared__ short Xlds[64][72];   // [n][k] bf16 (transposed tile)

    const int tid  = threadIdx.x;
    const int lane = tid & 63;
    const int w    = tid >> 6;       // wave id 0..3 -> m rows w*16..+15
    const int lrow = lane & 15;
    const int lkg  = lane >> 4;

    const float* inb = in + (size_t)b * C_ * N_;

    f32x4 acc[4] = {{0.f,0.f,0.f,0.f},{0.f,0.f,0.f,0.f},{0.f,0.f,0.f,0.f},{0.f,0.f,0.f,0.f}};

    const int kq = tid >> 4;   // 0..15 -> k base kq*4 (X transpose staging)
    const int nq = tid & 15;   // 0..15 -> n base nq*4

    for (int kc = 0; kc < C_ / 64; ++kc) {
        const int k0 = kc * 64;
        __syncthreads();   // previous chunk's frag reads done
        #pragma unroll
        for (int i = 0; i < 4; ++i) {
            int f = tid + i * 256;
            int r = f >> 4, c4 = (f & 15) * 4;
            f32x4 v = *reinterpret_cast<const f32x4*>(&W[(size_t)r * C_ + k0 + c4]);
            short4 s;
            s.x = f2bf(v[0]); s.y = f2bf(v[1]); s.z = f2bf(v[2]); s.w = f2bf(v[3]);
            *reinterpret_cast<short4*>(&Wlds[r][c4]) = s;
        }
        f32x4 v0 = *reinterpret_cast<const f32x4*>(&inb[(size_t)(k0 + kq * 4 + 0) * N_ + n0 + nq * 4]);
        f32x4 v1 = *reinterpret_cast<const f32x4*>(&inb[(size_t)(k0 + kq * 4 + 1) * N_ + n0 + nq * 4]);
        f32x4 v2 = *reinterpret_cast<const f32x4*>(&inb[(size_t)(k0 + kq * 4 + 2) * N_ + n0 + nq * 4]);
        f32x4 v3 = *reinterpret_cast<const f32x4*>(&inb[(size_t)(k0 + kq * 4 + 3) * N_ + n0 + nq * 4]);
        #pragma unroll
        for (int c = 0; c < 4; ++c) {
            short4 s;
            s.x = f2bf(v0[c]); s.y = f2bf(v1[c]); s.z = f2bf(v2[c]); s.w = f2bf(v3[c]);
            *reinterpret_cast<short4*>(&Xlds[nq * 4 + c][kq * 4]) = s;
        }
        __syncthreads();
        #pragma unroll
        for (int ks = 0; ks < 2; ++ks) {
            bf16x8 a = *reinterpret_cast<const bf16x8*>(&Wlds[w * 16 + lrow][ks * 32 + lkg * 8]);
            #pragma unroll
            for (int ns = 0; ns < 4; ++ns) {
                bf16x8 bx = *reinterpret_cast<const bf16x8*>(&Xlds[ns * 16 + lrow][ks * 32 + lkg * 8]);
                acc[ns] = __builtin_amdgcn_mfma_f32_16x16x32_bf16(a, bx, acc[ns], 0, 0, 0);
            }
        }
    }

    if (!tq) {
        float* outb = out + (size_t)b * M_ * N_;
        #pragma unroll
        for (int r = 0; r < 4; ++r) {
            int m = w * 16 + lkg * 4 + r;
            float bi = bias[m];
            #pragma unroll
            for (int ns = 0; ns < 4; ++ns) {
                int n = n0 + ns * 16 + lrow;
                outb[(size_t)m * N_ + n] = elus(acc[ns][r] + bi);
            }
        }
    } else {
        float* outb = out + (size_t)b * N_ * M_;
        int mbase = w * 16 + lkg * 4;
        float bi[4];
        #pragma unroll
        for (int r = 0; r < 4; ++r) bi[r] = bias[mbase + r];
        #pragma unroll
        for (int ns = 0; ns < 4; ++ns) {
            int n = n0 + ns * 16 + lrow;
            f32x4 v;
            #pragma unroll
            for (int r = 0; r < 4; ++r) v[r] = elus(acc[ns][r] + bi[r]);
            *reinterpret_cast<f32x4*>(&outb[(size_t)n * M_ + mbase]) = v;
        }
    }
}

// ---------------------------------------------------------------------------
// Kernel 2: Ksum[b][br][m] = sum_n Kbuf[b][m][n]
// ---------------------------------------------------------------------------
__global__ __launch_bounds__(256) void ksum_kernel(const float* __restrict__ Kbuf,
                                                   float* __restrict__ Ksum, int br)
{
    const int m = blockIdx.x;   // 0..63
    const int b = blockIdx.z;   // 0..7
    const float* row = Kbuf + ((size_t)b * M_ + m) * N_;
    float s = 0.f;
    for (int n = threadIdx.x; n < N_; n += 256) s += row[n];
    __shared__ float red[256];
    red[threadIdx.x] = s;
    __syncthreads();
    for (int off = 128; off > 0; off >>= 1) {
        if (threadIdx.x < off) red[threadIdx.x] += red[threadIdx.x + off];
        __syncthreads();
    }
    if (threadIdx.x == 0) Ksum[((size_t)b * 3 + br) * M_ + m] = red[0];
}

// ---------------------------------------------------------------------------
// Kernel 3a (MFMA): split-N partial KX via bf16 matrix cores.
// ---------------------------------------------------------------------------
__global__ __launch_bounds__(256) void kx_mfma_kernel(const float* __restrict__ Kbuf,
                                                      const float* __restrict__ x,
                                                      float* __restrict__ KXpart)
{
    const int c0 = blockIdx.x * 32;
    const int nc = blockIdx.y;
    const int b  = blockIdx.z;
    const int nbeg = nc * (N_ / NCHUNK_);

    __shared__ short Klds[64][72];   // 64 bf16 + 8 pad per row (144 B stride)
    __shared__ short Xlds[32][72];

    const int tid  = threadIdx.x;
    const int lane = tid & 63;
    const int w    = tid >> 6;       // wave id 0..3 -> m-tile base w*16
    const int lrow = lane & 15;
    const int lkg  = lane >> 4;      // 0..3 k-group

    const float* kb = Kbuf + (size_t)b * M_ * N_;
    const float* xb = x + ((size_t)b * C_ + c0) * N_;

    f32x4 acc0 = {0.f, 0.f, 0.f, 0.f};
    f32x4 acc1 = {0.f, 0.f, 0.f, 0.f};

    for (int it = 0; it < (N_ / NCHUNK_) / 64; ++it) {
        const int n0 = nbeg + it * 64;
        __syncthreads();   // previous iteration's frag reads done
        #pragma unroll
        for (int i = 0; i < 4; ++i) {
            int f = tid + i * 256;               // 0..1023
            int r = f >> 4, c4 = (f & 15) * 4;
            float4 v = *reinterpret_cast<const float4*>(&kb[(size_t)r * N_ + n0 + c4]);
            short4 s;
            s.x = f2bf(v.x); s.y = f2bf(v.y); s.z = f2bf(v.z); s.w = f2bf(v.w);
            *reinterpret_cast<short4*>(&Klds[r][c4]) = s;
        }
        #pragma unroll
        for (int i = 0; i < 2; ++i) {
            int f = tid + i * 256;               // 0..511
            int r = f >> 4, c4 = (f & 15) * 4;
            float4 v = *reinterpret_cast<const float4*>(&xb[(size_t)r * N_ + n0 + c4]);
            short4 s;
            s.x = f2bf(v.x); s.y = f2bf(v.y); s.z = f2bf(v.z); s.w = f2bf(v.w);
            *reinterpret_cast<short4*>(&Xlds[r][c4]) = s;
        }
        __syncthreads();
        #pragma unroll
        for (int s = 0; s < 2; ++s) {
            bf16x8 a  = *reinterpret_cast<const bf16x8*>(&Klds[w * 16 + lrow][s * 32 + lkg * 8]);
            bf16x8 b0 = *reinterpret_cast<const bf16x8*>(&Xlds[lrow][s * 32 + lkg * 8]);
            bf16x8 b1 = *reinterpret_cast<const bf16x8*>(&Xlds[16 + lrow][s * 32 + lkg * 8]);
            acc0 = __builtin_amdgcn_mfma_f32_16x16x32_bf16(a, b0, acc0, 0, 0, 0);
            acc1 = __builtin_amdgcn_mfma_f32_16x16x32_bf16(a, b1, acc1, 0, 0, 0);
        }
    }

    float* outp = KXpart + ((size_t)nc * B_ + b) * M_ * C_;
    #pragma unroll
    for (int r = 0; r < 4; ++r) {
        int m = w * 16 + lkg * 4 + r;
        outp[(size_t)m * C_ + c0 + lrow]      = acc0[r];
        outp[(size_t)m * C_ + c0 + 16 + lrow] = acc1[r];
    }
}

// ---------------------------------------------------------------------------
// Kernel 3b: reduce partials (fixed order — deterministic).
// ---------------------------------------------------------------------------
__global__ __launch_bounds__(256) void kx_reduce_kernel(const float* __restrict__ KXpart,
                                                        float* __restrict__ KX, int br)
{
    const size_t BMC = (size_t)B_ * M_ * C_;
    size_t i = (size_t)blockIdx.x * 256 + threadIdx.x;
    if (i >= BMC) return;
    float s = 0.f;
    #pragma unroll
    for (int nc = 0; nc < NCHUNK_; ++nc) s += KXpart[nc * BMC + i];
    size_t b = i / ((size_t)M_ * C_);
    size_t rem = i - b * (size_t)M_ * C_;
    KX[((size_t)b * 3 + br) * M_ * C_ + rem] = s;
}

// ---------------------------------------------------------------------------
// Kernel 4a (MFMA): WlWvPart[pc][c][k] = sum_{p in chunk pc} Wl[c][p]*Wv[p][k]
// ---------------------------------------------------------------------------
__global__ __launch_bounds__(256) void wlwv_mfma(const float* __restrict__ Wl,
                                                 const float* __restrict__ Wv,
                                                 float* __restrict__ part)
{
    const int k0 = blockIdx.x * 64;
    const int c0 = blockIdx.y * 64;
    const int pc = blockIdx.z;       // p chunk: p = pc*128 .. +128

    __shared__ short Al[64][72];     // Wl[c][p] bf16
    __shared__ short Bt[64][72];     // WvT[k][p] bf16

    const int tid  = threadIdx.x;
    const int lane = tid & 63;
    const int w    = tid >> 6;
    const int lrow = lane & 15;
    const int lkg  = lane >> 4;
    const int pq = tid >> 4;   // 0..15: p base pq*4 (transpose staging)
    const int nq = tid & 15;   // 0..15: k base nq*4

    f32x4 acc[4] = {{0.f,0.f,0.f,0.f},{0.f,0.f,0.f,0.f},{0.f,0.f,0.f,0.f},{0.f,0.f,0.f,0.f}};

    for (int it = 0; it < 2; ++it) {
        const int p0 = pc * 128 + it * 64;
        __syncthreads();
        #pragma unroll
        for (int i = 0; i < 4; ++i) {
            int f = tid + i * 256;
            int r = f >> 4, c4 = (f & 15) * 4;
            f32x4 v = *reinterpret_cast<const f32x4*>(&Wl[(size_t)(c0 + r) * C_ + p0 + c4]);
            short4 s;
            s.x = f2bf(v[0]); s.y = f2bf(v[1]); s.z = f2bf(v[2]); s.w = f2bf(v[3]);
            *reinterpret_cast<short4*>(&Al[r][c4]) = s;
        }
        f32x4 v0 = *reinterpret_cast<const f32x4*>(&Wv[(size_t)(p0 + pq * 4 + 0) * C_ + k0 + nq * 4]);
        f32x4 v1 = *reinterpret_cast<const f32x4*>(&Wv[(size_t)(p0 + pq * 4 + 1) * C_ + k0 + nq * 4]);
        f32x4 v2 = *reinterpret_cast<const f32x4*>(&Wv[(size_t)(p0 + pq * 4 + 2) * C_ + k0 + nq * 4]);
        f32x4 v3 = *reinterpret_cast<const f32x4*>(&Wv[(size_t)(p0 + pq * 4 + 3) * C_ + k0 + nq * 4]);
        #pragma unroll
        for (int c = 0; c < 4; ++c) {
            short4 s;
            s.x = f2bf(v0[c]); s.y = f2bf(v1[c]); s.z = f2bf(v2[c]); s.w = f2bf(v3[c]);
            *reinterpret_cast<short4*>(&Bt[nq * 4 + c][pq * 4]) = s;
        }
        __syncthreads();
        #pragma unroll
        for (int ks = 0; ks < 2; ++ks) {
            bf16x8 a = *reinterpret_cast<const bf16x8*>(&Al[w * 16 + lrow][ks * 32 + lkg * 8]);
            #pragma unroll
            for (int ns = 0; ns < 4; ++ns) {
                bf16x8 bx = *reinterpret_cast<const bf16x8*>(&Bt[ns * 16 + lrow][ks * 32 + lkg * 8]);
                acc[ns] = __builtin_amdgcn_mfma_f32_16x16x32_bf16(a, bx, acc[ns], 0, 0, 0);
            }
        }
    }

    float* pp = part + (size_t)pc * C_ * C_;
    #pragma unroll
    for (int r = 0; r < 4; ++r) {
        int c = c0 + w * 16 + lkg * 4 + r;
        #pragma unroll
        for (int ns = 0; ns < 4; ++ns) {
            int k = k0 + ns * 16 + lrow;
            pp[(size_t)c * C_ + k] = acc[ns][r];
        }
    }
}

// Kernel 4b: WlWv[i] = sum_pc part[pc][i]  (fixed order — deterministic)
__global__ __launch_bounds__(256) void wlwv_reduce(const float* __restrict__ part,
                                                   float* __restrict__ WlWv)
{
    const size_t CC = (size_t)C_ * C_;
    size_t i = (size_t)blockIdx.x * 256 + threadIdx.x;
    if (i >= CC) return;
    float s = 0.f;
    #pragma unroll
    for (int pc = 0; pc < 4; ++pc) s += part[pc * CC + i];
    WlWv[i] = s;
}

// Wlbv[c] = sum_p Wl[c][p] * bv[p]
__global__ __launch_bounds__(256) void wlbv_kernel(const float* __restrict__ Wl,
                                                   const float* __restrict__ bv,
                                                   float* __restrict__ Wlbv)
{
    int c = blockIdx.x * 256 + threadIdx.x;
    if (c < C_) {
        float s = 0.f;
        for (int p = 0; p < C_; ++p) s = fmaf(Wl[(size_t)c * C_ + p], bv[p], s);
        Wlbv[c] = s;
    }
}

// ---------------------------------------------------------------------------
// Kernel 5 (MFMA): Wf[b][br][c][m] = sum_k WlWv[c][k]*KX[b][br][m][k]
//                                    + Ksum[b][br][m]*Wlbv[c]
// Both operands k-contiguous (this is why KX is stored [m][k] row-major):
// A = WlWv[c][k], B = KX[m][k] — native staging, no transpose, 0-conflict.
// Block 256 thr / 4 waves; tile 64c x 64m; k-chunks of 64 (8 chunks).
// ---------------------------------------------------------------------------
__global__ __launch_bounds__(256) void wfused_mfma(const float* __restrict__ WlWv,
                                                   const float* __restrict__ KX,
                                                   const float* __restrict__ Ksum,
                                                   const float* __restrict__ Wlbv,
                                                   float* __restrict__ Wf)
{
    const int c0 = blockIdx.x * 64;
    const int br = blockIdx.y;
    const int b  = blockIdx.z;

    __shared__ short Al[64][72];   // WlWv[c][k] bf16
    __shared__ short Bl[64][72];   // KX[m][k] bf16

    const int tid  = threadIdx.x;
    const int lane = tid & 63;
    const int w    = tid >> 6;
    const int lrow = lane & 15;
    const int lkg  = lane >> 4;

    const float* kxb = KX + ((size_t)b * 3 + br) * M_ * C_;  // [m][k]

    f32x4 acc[4] = {{0.f,0.f,0.f,0.f},{0.f,0.f,0.f,0.f},{0.f,0.f,0.f,0.f},{0.f,0.f,0.f,0.f}};

    for (int kc = 0; kc < C_ / 64; ++kc) {
        const int k0 = kc * 64;
        __syncthreads();
        #pragma unroll
        for (int i = 0; i < 4; ++i) {
            int f = tid + i * 256;
            int r = f >> 4, c4 = (f & 15) * 4;
            f32x4 v = *reinterpret_cast<const f32x4*>(&WlWv[(size_t)(c0 + r) * C_ + k0 + c4]);
            short4 s;
            s.x = f2bf(v[0]); s.y = f2bf(v[1]); s.z = f2bf(v[2]); s.w = f2bf(v[3]);
            *reinterpret_cast<short4*>(&Al[r][c4]) = s;
        }
        #pragma unroll
        for (int i = 0; i < 4; ++i) {
            int f = tid + i * 256;
            int r = f >> 4, c4 = (f & 15) * 4;
            f32x4 v = *reinterpret_cast<const f32x4*>(&kxb[(size_t)r * C_ + k0 + c4]);
            short4 s;
            s.x = f2bf(v[0]); s.y = f2bf(v[1]); s.z = f2bf(v[2]); s.w = f2bf(v[3]);
            *reinterpret_cast<short4*>(&Bl[r][c4]) = s;
        }
        __syncthreads();
        #pragma unroll
        for (int ks = 0; ks < 2; ++ks) {
            bf16x8 a = *reinterpret_cast<const bf16x8*>(&Al[w * 16 + lrow][ks * 32 + lkg * 8]);
            #pragma unroll
            for (int ns = 0; ns < 4; ++ns) {
                bf16x8 bx = *reinterpret_cast<const bf16x8*>(&Bl[ns * 16 + lrow][ks * 32 + lkg * 8]);
                acc[ns] = __builtin_amdgcn_mfma_f32_16x16x32_bf16(a, bx, acc[ns], 0, 0, 0);
            }
        }
    }

    // epilogue: + Ksum[m]*Wlbv[c]; lane rows c = c0+w*16+lkg*4+r, cols m = ns*16+lrow
    const float* ks_ = Ksum + ((size_t)b * 3 + br) * M_;
    float* wfb = Wf + (((size_t)b * 3 + br) * C_) * M_;
    #pragma unroll
    for (int r = 0; r < 4; ++r) {
        int c = c0 + w * 16 + lkg * 4 + r;
        float wb = Wlbv[c];
        #pragma unroll
        for (int ns = 0; ns < 4; ++ns) {
            int m = ns * 16 + lrow;
            wfb[(size_t)c * M_ + m] = acc[ns][r] + ks_[m] * wb;
        }
    }
}

// ---------------------------------------------------------------------------
// Kernel 6 (MFMA): out[b][c][n] = x[b][c][n] + gamma*( bl[c] +
//    sum_br norm_br[n] * sum_m Wf[b][br][c][m] * QT[b][n][m] )
// ---------------------------------------------------------------------------
__global__ __launch_bounds__(256) void final_mfma_kernel(
    const float* __restrict__ QT, const float* __restrict__ Wf,
    const float* __restrict__ Ksum, const float* __restrict__ x,
    const float* __restrict__ bl, const float* __restrict__ gamma,
    float* __restrict__ out)
{
    const int n0 = blockIdx.x * 64;
    const int c0 = blockIdx.y * 64;
    const int b  = blockIdx.z;

    __shared__ short Qs[64][72];      // [n][m] bf16
    __shared__ short Wfs[3][64][72];  // [br][c][m] bf16
    __shared__ float norms[3][64];
    __shared__ float ksef[3][64];

    const int tid  = threadIdx.x;
    const int lane = tid & 63;
    const int w    = tid >> 6;
    const int lrow = lane & 15;
    const int lkg  = lane >> 4;

    const float* qtb = QT + (size_t)b * N_ * M_;
    #pragma unroll
    for (int i = 0; i < 4; ++i) {
        int f = tid + i * 256;
        int r = f >> 4, m4 = (f & 15) * 4;
        float4 v = *reinterpret_cast<const float4*>(&qtb[(size_t)(n0 + r) * M_ + m4]);
        short4 s;
        s.x = f2bf(v.x); s.y = f2bf(v.y); s.z = f2bf(v.z); s.w = f2bf(v.w);
        *reinterpret_cast<short4*>(&Qs[r][m4]) = s;
    }
    #pragma unroll
    for (int br = 0; br < 3; ++br) {
        const float* wfb = Wf + (((size_t)b * 3 + br) * C_ + c0) * M_;
        #pragma unroll
        for (int i = 0; i < 4; ++i) {
            int f = tid + i * 256;
            int r = f >> 4, m4 = (f & 15) * 4;
            float4 v = *reinterpret_cast<const float4*>(&wfb[(size_t)r * M_ + m4]);
            short4 s;
            s.x = f2bf(v.x); s.y = f2bf(v.y); s.z = f2bf(v.z); s.w = f2bf(v.w);
            *reinterpret_cast<short4*>(&Wfs[br][r][m4]) = s;
        }
    }
    if (tid < 192) {
        int br = tid >> 6, m = tid & 63;
        ksef[br][m] = Ksum[((size_t)b * 3 + br) * M_ + m] + EPS_;
    }
    __syncthreads();
    if (tid < 192) {
        int br = tid >> 6, n = tid & 63;
        float s = 0.f;
        #pragma unroll 16
        for (int m = 0; m < 64; ++m) s = fmaf(bf2f(Qs[n][m]), ksef[br][m], s);
        norms[br][n] = 1.0f / s;
    }
    __syncthreads();

    f32x4 tot[4] = {{0.f,0.f,0.f,0.f},{0.f,0.f,0.f,0.f},{0.f,0.f,0.f,0.f},{0.f,0.f,0.f,0.f}};
    for (int br = 0; br < 3; ++br) {
        f32x4 acc[4] = {{0.f,0.f,0.f,0.f},{0.f,0.f,0.f,0.f},{0.f,0.f,0.f,0.f},{0.f,0.f,0.f,0.f}};
        #pragma unroll
        for (int ks = 0; ks < 2; ++ks) {
            bf16x8 a = *reinterpret_cast<const bf16x8*>(&Wfs[br][w * 16 + lrow][ks * 32 + lkg * 8]);
            #pragma unroll
            for (int ns = 0; ns < 4; ++ns) {
                bf16x8 bq = *reinterpret_cast<const bf16x8*>(&Qs[ns * 16 + lrow][ks * 32 + lkg * 8]);
                acc[ns] = __builtin_amdgcn_mfma_f32_16x16x32_bf16(a, bq, acc[ns], 0, 0, 0);
            }
        }
        #pragma unroll
        for (int ns = 0; ns < 4; ++ns) {
            float nf = norms[br][ns * 16 + lrow];
            #pragma unroll
            for (int r = 0; r < 4; ++r) tot[ns][r] = fmaf(nf, acc[ns][r], tot[ns][r]);
        }
    }

    const float g = gamma[0];
    const float* xb = x + (size_t)b * C_ * N_;
    float* ob = out + (size_t)b * C_ * N_;
    #pragma unroll
    for (int r = 0; r < 4; ++r) {
        int c = c0 + w * 16 + lkg * 4 + r;
        float blc = bl[c];
        #pragma unroll
        for (int ns = 0; ns < 4; ++ns) {
            int n = n0 + ns * 16 + lrow;
            ob[(size_t)c * N_ + n] = fmaf(g, tot[ns][r] + blc, xb[(size_t)c * N_ + n]);
        }
    }
}

// ---------------------------------------------------------------------------
extern "C" void kernel_launch(void* const* d_in, const int* in_sizes, int n_in,
                              void* d_out, int out_size, void* d_ws, size_t ws_size,
                              hipStream_t stream)
{
    const float* x   = (const float*)d_in[0];
    const float* y   = (const float*)d_in[1];
    const float* z   = (const float*)d_in[2];
    const float* Wq  = (const float*)d_in[3];
    const float* bq  = (const float*)d_in[4];
    const float* Wk1 = (const float*)d_in[5];
    const float* bk1 = (const float*)d_in[6];
    const float* Wk2 = (const float*)d_in[7];
    const float* bk2 = (const float*)d_in[8];
    const float* Wk3 = (const float*)d_in[9];
    const float* bk3 = (const float*)d_in[10];
    const float* Wv  = (const float*)d_in[11];
    const float* bv  = (const float*)d_in[12];
    const float* Wl  = (const float*)d_in[13];
    const float* bl  = (const float*)d_in[14];
    const float* gamma = (const float*)d_in[15];
    float* out = (float*)d_out;

    // workspace layout (floats) — total 6,293,504 floats = 25.2 MB (unchanged).
    // KXpart slot (1,048,576 floats) is time-multiplexed:
    //   branch loop:   KXpart[NCHUNK][B][M][C]   (kx partials)
    //   wlwv phase:    WlWvPart[4][C][C]         (exactly the same size)
    //   wfused/final:  Wf[B][3][C][M]            (3 MB)
    float* ws = (float*)d_ws;
    const size_t QSZ  = (size_t)B_ * M_ * N_;        // 2,097,152
    const size_t BMC  = (size_t)B_ * M_ * C_;        //   262,144
    float* QT   = ws;                                 // [B][N][M]
    float* Kbuf = QT + QSZ;                           // [B][M][N] (reused per branch)
    float* KX   = Kbuf + QSZ;                         // [B][3][M][C]
    float* Ksum = KX + 3 * BMC;                       // [B][3][M]
    float* WlWv = Ksum + (size_t)B_ * 3 * M_;         // [C][C]
    float* Wlbv = WlWv + (size_t)C_ * C_;             // [C]
    float* KXpart = Wlbv + C_;                        // shared slot (4 MB)
    float* WlWvPart = KXpart;                         // alias
    float* Wf   = KXpart;                             // alias

    dim3 blk(256);
    const dim3 featGrid(N_ / 64, 1, B_);

    // Q features (transposed output)
    feat_mfma<<<featGrid, blk, 0, stream>>>(x, Wq, bq, QT, 1);

    // K branches, sequenced through Kbuf
    const float* kin[3]  = { x, y, z };
    const float* kW[3]   = { Wk1, Wk2, Wk3 };
    const float* kb_[3]  = { bk1, bk2, bk3 };
    for (int br = 0; br < 3; ++br) {
        feat_mfma<<<featGrid, blk, 0, stream>>>(kin[br], kW[br], kb_[br], Kbuf, 0);
        ksum_kernel<<<dim3(M_, 1, B_), blk, 0, stream>>>(Kbuf, Ksum, br);
        kx_mfma_kernel<<<dim3(C_ / 32, NCHUNK_, B_), blk, 0, stream>>>(Kbuf, x, KXpart);
        kx_reduce_kernel<<<dim3((BMC + 255) / 256), blk, 0, stream>>>(KXpart, KX, br);
    }

    // batch-independent fused weights
    wlwv_mfma<<<dim3(C_ / 64, C_ / 64, 4), blk, 0, stream>>>(Wl, Wv, WlWvPart);
    wlwv_reduce<<<dim3(((int)((size_t)C_ * C_) + 255) / 256), blk, 0, stream>>>(WlWvPart, WlWv);
    wlbv_kernel<<<dim3((C_ + 255) / 256), blk, 0, stream>>>(Wl, bv, Wlbv);
    // per-batch fused weights (MFMA; overwrites the shared slot with Wf)
    wfused_mfma<<<dim3(C_ / 64, 3, B_), blk, 0, stream>>>(WlWv, KX, Ksum, Wlbv, Wf);
    // final: norms + MFMA GEMM + bias + residual
    final_mfma_kernel<<<dim3(N_ / 64, C_ / 64, B_), blk, 0, stream>>>(
        QT, Wf, Ksum, x, bl, gamma, out);
}

// Round 13
// 214.177 us; speedup vs baseline: 8.9724x; 1.0983x over previous
//
#include <hip/hip_runtime.h>
#include <hip/hip_bf16.h>
#include <math.h>

// Problem constants
constexpr int B_ = 8;
constexpr int C_ = 512;
constexpr int M_ = 64;     // C/8
constexpr int N_ = 4096;   // H*W
constexpr int NCHUNK_ = 4; // split-N factor for kx
constexpr float EPS_ = 1e-10f;
constexpr float PARAM_ = 10.0f;

typedef __attribute__((ext_vector_type(4))) float f32x4;
typedef __attribute__((ext_vector_type(8))) short bf16x8;   // 8 bf16 in 4 VGPRs

// elus feature map: t>0 ? 10t+1 : exp(10t)
__device__ __forceinline__ float elus(float t) {
    return (t > 0.f) ? fmaf(PARAM_, t, 1.f) : expf(PARAM_ * t);
}

// fp32 -> bf16 round-to-nearest-even (finite inputs only)
__device__ __forceinline__ short f2bf(float f) {
    unsigned u = __builtin_bit_cast(unsigned, f);
    u += 0x7FFFu + ((u >> 16) & 1u);
    return (short)(u >> 16);
}
// bf16 bits -> fp32
__device__ __forceinline__ float bf2f(short s) {
    unsigned u = ((unsigned)(unsigned short)s) << 16;
    return __builtin_bit_cast(float, u);
}

// ---------------------------------------------------------------------------
// Kernel 1 (MFMA): feature GEMM out = elus(W @ in + bias), bf16 output.
// tq=0: out[b][m][n] bf16 K + fused per-block ksum partials (shfl reduce).
// tq=1: out[b][n][m] bf16 QT (short4 along m).
// ---------------------------------------------------------------------------
__global__ __launch_bounds__(256) void feat_mfma(
    const float* __restrict__ in, const float* __restrict__ W,
    const float* __restrict__ bias, short* __restrict__ out, int tq,
    float* __restrict__ Ksumpart)
{
    const int n0 = blockIdx.x * 64;
    const int b  = blockIdx.z;

    __shared__ short Wlds[64][72];   // [m][k] bf16, 144B row stride
    __shared__ short Xlds[64][72];   // [n][k] bf16 (transposed tile)

    const int tid  = threadIdx.x;
    const int lane = tid & 63;
    const int w    = tid >> 6;       // wave id 0..3 -> m rows w*16..+15
    const int lrow = lane & 15;
    const int lkg  = lane >> 4;

    const float* inb = in + (size_t)b * C_ * N_;

    f32x4 acc[4] = {{0.f,0.f,0.f,0.f},{0.f,0.f,0.f,0.f},{0.f,0.f,0.f,0.f},{0.f,0.f,0.f,0.f}};

    const int kq = tid >> 4;   // 0..15 -> k base kq*4 (X transpose staging)
    const int nq = tid & 15;   // 0..15 -> n base nq*4

    for (int kc = 0; kc < C_ / 64; ++kc) {
        const int k0 = kc * 64;
        __syncthreads();   // previous chunk's frag reads done
        #pragma unroll
        for (int i = 0; i < 4; ++i) {
            int f = tid + i * 256;
            int r = f >> 4, c4 = (f & 15) * 4;
            f32x4 v = *reinterpret_cast<const f32x4*>(&W[(size_t)r * C_ + k0 + c4]);
            short4 s;
            s.x = f2bf(v[0]); s.y = f2bf(v[1]); s.z = f2bf(v[2]); s.w = f2bf(v[3]);
            *reinterpret_cast<short4*>(&Wlds[r][c4]) = s;
        }
        f32x4 v0 = *reinterpret_cast<const f32x4*>(&inb[(size_t)(k0 + kq * 4 + 0) * N_ + n0 + nq * 4]);
        f32x4 v1 = *reinterpret_cast<const f32x4*>(&inb[(size_t)(k0 + kq * 4 + 1) * N_ + n0 + nq * 4]);
        f32x4 v2 = *reinterpret_cast<const f32x4*>(&inb[(size_t)(k0 + kq * 4 + 2) * N_ + n0 + nq * 4]);
        f32x4 v3 = *reinterpret_cast<const f32x4*>(&inb[(size_t)(k0 + kq * 4 + 3) * N_ + n0 + nq * 4]);
        #pragma unroll
        for (int c = 0; c < 4; ++c) {
            short4 s;
            s.x = f2bf(v0[c]); s.y = f2bf(v1[c]); s.z = f2bf(v2[c]); s.w = f2bf(v3[c]);
            *reinterpret_cast<short4*>(&Xlds[nq * 4 + c][kq * 4]) = s;
        }
        __syncthreads();
        #pragma unroll
        for (int ks = 0; ks < 2; ++ks) {
            bf16x8 a = *reinterpret_cast<const bf16x8*>(&Wlds[w * 16 + lrow][ks * 32 + lkg * 8]);
            #pragma unroll
            for (int ns = 0; ns < 4; ++ns) {
                bf16x8 bx = *reinterpret_cast<const bf16x8*>(&Xlds[ns * 16 + lrow][ks * 32 + lkg * 8]);
                acc[ns] = __builtin_amdgcn_mfma_f32_16x16x32_bf16(a, bx, acc[ns], 0, 0, 0);
            }
        }
    }

    if (!tq) {
        // K branch: bf16 store + fused column-sum partials.
        short* outb = out + (size_t)b * M_ * N_;
        #pragma unroll
        for (int r = 0; r < 4; ++r) {
            int m = w * 16 + lkg * 4 + r;
            float bi = bias[m];
            float sv = 0.f;
            #pragma unroll
            for (int ns = 0; ns < 4; ++ns) {
                int n = n0 + ns * 16 + lrow;
                float e = elus(acc[ns][r] + bi);
                outb[(size_t)m * N_ + n] = f2bf(e);
                sv += e;
            }
            // reduce over the 16 lrow lanes (xor bits 0..3 stay in-group)
            sv += __shfl_xor(sv, 1);
            sv += __shfl_xor(sv, 2);
            sv += __shfl_xor(sv, 4);
            sv += __shfl_xor(sv, 8);
            if (lrow == 0)
                Ksumpart[(((size_t)b * 64) + blockIdx.x) * M_ + m] = sv;
        }
    } else {
        // QT[b][n][m] bf16: 4 consecutive m per lane -> short4 store
        short* outb = out + (size_t)b * N_ * M_;
        int mbase = w * 16 + lkg * 4;
        float bi[4];
        #pragma unroll
        for (int r = 0; r < 4; ++r) bi[r] = bias[mbase + r];
        #pragma unroll
        for (int ns = 0; ns < 4; ++ns) {
            int n = n0 + ns * 16 + lrow;
            short4 s;
            s.x = f2bf(elus(acc[ns][0] + bi[0]));
            s.y = f2bf(elus(acc[ns][1] + bi[1]));
            s.z = f2bf(elus(acc[ns][2] + bi[2]));
            s.w = f2bf(elus(acc[ns][3] + bi[3]));
            *reinterpret_cast<short4*>(&outb[(size_t)n * M_ + mbase]) = s;
        }
    }
}

// ---------------------------------------------------------------------------
// Kernel 2: Ksum[b][br][m] = sum_nb Ksumpart[b][nb][m]  (fixed order)
// ---------------------------------------------------------------------------
__global__ __launch_bounds__(256) void ksum_finalize(const float* __restrict__ Ksumpart,
                                                     float* __restrict__ Ksum, int br)
{
    int i = blockIdx.x * 256 + threadIdx.x;   // 0..511 = (b, m)
    if (i >= B_ * M_) return;
    int b = i >> 6, m = i & 63;
    float s = 0.f;
    #pragma unroll 8
    for (int nb = 0; nb < 64; ++nb)
        s += Ksumpart[(((size_t)b * 64) + nb) * M_ + m];
    Ksum[((size_t)b * 3 + br) * M_ + m] = s;
}

// ---------------------------------------------------------------------------
// Kernel 3a (MFMA): split-N partial KX.  Kbuf is now bf16 (direct 16B copies).
// ---------------------------------------------------------------------------
__global__ __launch_bounds__(256) void kx_mfma_kernel(const short* __restrict__ Kbuf,
                                                      const float* __restrict__ x,
                                                      float* __restrict__ KXpart)
{
    const int c0 = blockIdx.x * 32;
    const int nc = blockIdx.y;
    const int b  = blockIdx.z;
    const int nbeg = nc * (N_ / NCHUNK_);

    __shared__ short Klds[64][72];
    __shared__ short Xlds[32][72];

    const int tid  = threadIdx.x;
    const int lane = tid & 63;
    const int w    = tid >> 6;
    const int lrow = lane & 15;
    const int lkg  = lane >> 4;

    const short* kb = Kbuf + (size_t)b * M_ * N_;
    const float* xb = x + ((size_t)b * C_ + c0) * N_;

    f32x4 acc0 = {0.f, 0.f, 0.f, 0.f};
    f32x4 acc1 = {0.f, 0.f, 0.f, 0.f};

    for (int it = 0; it < (N_ / NCHUNK_) / 64; ++it) {
        const int n0 = nbeg + it * 64;
        __syncthreads();
        // K tile: already bf16 — straight 16B copies (64 rows x 64 shorts)
        #pragma unroll
        for (int i = 0; i < 2; ++i) {
            int f = tid + i * 256;              // 0..511
            int r = f >> 3, c8 = (f & 7) * 8;
            *reinterpret_cast<int4*>(&Klds[r][c8]) =
                *reinterpret_cast<const int4*>(&kb[(size_t)r * N_ + n0 + c8]);
        }
        // X tile: fp32 -> bf16
        #pragma unroll
        for (int i = 0; i < 2; ++i) {
            int f = tid + i * 256;              // 0..511
            int r = f >> 4, c4 = (f & 15) * 4;
            float4 v = *reinterpret_cast<const float4*>(&xb[(size_t)r * N_ + n0 + c4]);
            short4 s;
            s.x = f2bf(v.x); s.y = f2bf(v.y); s.z = f2bf(v.z); s.w = f2bf(v.w);
            *reinterpret_cast<short4*>(&Xlds[r][c4]) = s;
        }
        __syncthreads();
        #pragma unroll
        for (int s = 0; s < 2; ++s) {
            bf16x8 a  = *reinterpret_cast<const bf16x8*>(&Klds[w * 16 + lrow][s * 32 + lkg * 8]);
            bf16x8 b0 = *reinterpret_cast<const bf16x8*>(&Xlds[lrow][s * 32 + lkg * 8]);
            bf16x8 b1 = *reinterpret_cast<const bf16x8*>(&Xlds[16 + lrow][s * 32 + lkg * 8]);
            acc0 = __builtin_amdgcn_mfma_f32_16x16x32_bf16(a, b0, acc0, 0, 0, 0);
            acc1 = __builtin_amdgcn_mfma_f32_16x16x32_bf16(a, b1, acc1, 0, 0, 0);
        }
    }

    float* outp = KXpart + ((size_t)nc * B_ + b) * M_ * C_;
    #pragma unroll
    for (int r = 0; r < 4; ++r) {
        int m = w * 16 + lkg * 4 + r;
        outp[(size_t)m * C_ + c0 + lrow]      = acc0[r];
        outp[(size_t)m * C_ + c0 + 16 + lrow] = acc1[r];
    }
}

// ---------------------------------------------------------------------------
// Kernel 3b: reduce partials (fixed order — deterministic).
// ---------------------------------------------------------------------------
__global__ __launch_bounds__(256) void kx_reduce_kernel(const float* __restrict__ KXpart,
                                                        float* __restrict__ KX, int br)
{
    const size_t BMC = (size_t)B_ * M_ * C_;
    size_t i = (size_t)blockIdx.x * 256 + threadIdx.x;
    if (i >= BMC) return;
    float s = 0.f;
    #pragma unroll
    for (int nc = 0; nc < NCHUNK_; ++nc) s += KXpart[nc * BMC + i];
    size_t b = i / ((size_t)M_ * C_);
    size_t rem = i - b * (size_t)M_ * C_;
    KX[((size_t)b * 3 + br) * M_ * C_ + rem] = s;
}

// ---------------------------------------------------------------------------
// Kernel 4a (MFMA): WlWvPart[pc][c][k] = sum_{p in chunk pc} Wl[c][p]*Wv[p][k]
// ---------------------------------------------------------------------------
__global__ __launch_bounds__(256) void wlwv_mfma(const float* __restrict__ Wl,
                                                 const float* __restrict__ Wv,
                                                 float* __restrict__ part)
{
    const int k0 = blockIdx.x * 64;
    const int c0 = blockIdx.y * 64;
    const int pc = blockIdx.z;

    __shared__ short Al[64][72];
    __shared__ short Bt[64][72];

    const int tid  = threadIdx.x;
    const int lane = tid & 63;
    const int w    = tid >> 6;
    const int lrow = lane & 15;
    const int lkg  = lane >> 4;
    const int pq = tid >> 4;
    const int nq = tid & 15;

    f32x4 acc[4] = {{0.f,0.f,0.f,0.f},{0.f,0.f,0.f,0.f},{0.f,0.f,0.f,0.f},{0.f,0.f,0.f,0.f}};

    for (int it = 0; it < 2; ++it) {
        const int p0 = pc * 128 + it * 64;
        __syncthreads();
        #pragma unroll
        for (int i = 0; i < 4; ++i) {
            int f = tid + i * 256;
            int r = f >> 4, c4 = (f & 15) * 4;
            f32x4 v = *reinterpret_cast<const f32x4*>(&Wl[(size_t)(c0 + r) * C_ + p0 + c4]);
            short4 s;
            s.x = f2bf(v[0]); s.y = f2bf(v[1]); s.z = f2bf(v[2]); s.w = f2bf(v[3]);
            *reinterpret_cast<short4*>(&Al[r][c4]) = s;
        }
        f32x4 v0 = *reinterpret_cast<const f32x4*>(&Wv[(size_t)(p0 + pq * 4 + 0) * C_ + k0 + nq * 4]);
        f32x4 v1 = *reinterpret_cast<const f32x4*>(&Wv[(size_t)(p0 + pq * 4 + 1) * C_ + k0 + nq * 4]);
        f32x4 v2 = *reinterpret_cast<const f32x4*>(&Wv[(size_t)(p0 + pq * 4 + 2) * C_ + k0 + nq * 4]);
        f32x4 v3 = *reinterpret_cast<const f32x4*>(&Wv[(size_t)(p0 + pq * 4 + 3) * C_ + k0 + nq * 4]);
        #pragma unroll
        for (int c = 0; c < 4; ++c) {
            short4 s;
            s.x = f2bf(v0[c]); s.y = f2bf(v1[c]); s.z = f2bf(v2[c]); s.w = f2bf(v3[c]);
            *reinterpret_cast<short4*>(&Bt[nq * 4 + c][pq * 4]) = s;
        }
        __syncthreads();
        #pragma unroll
        for (int ks = 0; ks < 2; ++ks) {
            bf16x8 a = *reinterpret_cast<const bf16x8*>(&Al[w * 16 + lrow][ks * 32 + lkg * 8]);
            #pragma unroll
            for (int ns = 0; ns < 4; ++ns) {
                bf16x8 bx = *reinterpret_cast<const bf16x8*>(&Bt[ns * 16 + lrow][ks * 32 + lkg * 8]);
                acc[ns] = __builtin_amdgcn_mfma_f32_16x16x32_bf16(a, bx, acc[ns], 0, 0, 0);
            }
        }
    }

    float* pp = part + (size_t)pc * C_ * C_;
    #pragma unroll
    for (int r = 0; r < 4; ++r) {
        int c = c0 + w * 16 + lkg * 4 + r;
        #pragma unroll
        for (int ns = 0; ns < 4; ++ns) {
            int k = k0 + ns * 16 + lrow;
            pp[(size_t)c * C_ + k] = acc[ns][r];
        }
    }
}

// Kernel 4b: WlWv[i] = sum_pc part[pc][i]  (fixed order)
__global__ __launch_bounds__(256) void wlwv_reduce(const float* __restrict__ part,
                                                   float* __restrict__ WlWv)
{
    const size_t CC = (size_t)C_ * C_;
    size_t i = (size_t)blockIdx.x * 256 + threadIdx.x;
    if (i >= CC) return;
    float s = 0.f;
    #pragma unroll
    for (int pc = 0; pc < 4; ++pc) s += part[pc * CC + i];
    WlWv[i] = s;
}

// Wlbv[c] = sum_p Wl[c][p] * bv[p]
__global__ __launch_bounds__(256) void wlbv_kernel(const float* __restrict__ Wl,
                                                   const float* __restrict__ bv,
                                                   float* __restrict__ Wlbv)
{
    int c = blockIdx.x * 256 + threadIdx.x;
    if (c < C_) {
        float s = 0.f;
        for (int p = 0; p < C_; ++p) s = fmaf(Wl[(size_t)c * C_ + p], bv[p], s);
        Wlbv[c] = s;
    }
}

// ---------------------------------------------------------------------------
// Kernel 5 (MFMA): Wf[b][br][c][m] = sum_k WlWv[c][k]*KX[b][br][m][k]
//                                    + Ksum[b][br][m]*Wlbv[c]
// ---------------------------------------------------------------------------
__global__ __launch_bounds__(256) void wfused_mfma(const float* __restrict__ WlWv,
                                                   const float* __restrict__ KX,
                                                   const float* __restrict__ Ksum,
                                                   const float* __restrict__ Wlbv,
                                                   float* __restrict__ Wf)
{
    const int c0 = blockIdx.x * 64;
    const int br = blockIdx.y;
    const int b  = blockIdx.z;

    __shared__ short Al[64][72];   // WlWv[c][k] bf16
    __shared__ short Bl[64][72];   // KX[m][k] bf16

    const int tid  = threadIdx.x;
    const int lane = tid & 63;
    const int w    = tid >> 6;
    const int lrow = lane & 15;
    const int lkg  = lane >> 4;

    const float* kxb = KX + ((size_t)b * 3 + br) * M_ * C_;

    f32x4 acc[4] = {{0.f,0.f,0.f,0.f},{0.f,0.f,0.f,0.f},{0.f,0.f,0.f,0.f},{0.f,0.f,0.f,0.f}};

    for (int kc = 0; kc < C_ / 64; ++kc) {
        const int k0 = kc * 64;
        __syncthreads();
        #pragma unroll
        for (int i = 0; i < 4; ++i) {
            int f = tid + i * 256;
            int r = f >> 4, c4 = (f & 15) * 4;
            f32x4 v = *reinterpret_cast<const f32x4*>(&WlWv[(size_t)(c0 + r) * C_ + k0 + c4]);
            short4 s;
            s.x = f2bf(v[0]); s.y = f2bf(v[1]); s.z = f2bf(v[2]); s.w = f2bf(v[3]);
            *reinterpret_cast<short4*>(&Al[r][c4]) = s;
        }
        #pragma unroll
        for (int i = 0; i < 4; ++i) {
            int f = tid + i * 256;
            int r = f >> 4, c4 = (f & 15) * 4;
            f32x4 v = *reinterpret_cast<const f32x4*>(&kxb[(size_t)r * C_ + k0 + c4]);
            short4 s;
            s.x = f2bf(v[0]); s.y = f2bf(v[1]); s.z = f2bf(v[2]); s.w = f2bf(v[3]);
            *reinterpret_cast<short4*>(&Bl[r][c4]) = s;
        }
        __syncthreads();
        #pragma unroll
        for (int ks = 0; ks < 2; ++ks) {
            bf16x8 a = *reinterpret_cast<const bf16x8*>(&Al[w * 16 + lrow][ks * 32 + lkg * 8]);
            #pragma unroll
            for (int ns = 0; ns < 4; ++ns) {
                bf16x8 bx = *reinterpret_cast<const bf16x8*>(&Bl[ns * 16 + lrow][ks * 32 + lkg * 8]);
                acc[ns] = __builtin_amdgcn_mfma_f32_16x16x32_bf16(a, bx, acc[ns], 0, 0, 0);
            }
        }
    }

    const float* ks_ = Ksum + ((size_t)b * 3 + br) * M_;
    float* wfb = Wf + (((size_t)b * 3 + br) * C_) * M_;
    #pragma unroll
    for (int r = 0; r < 4; ++r) {
        int c = c0 + w * 16 + lkg * 4 + r;
        float wb = Wlbv[c];
        #pragma unroll
        for (int ns = 0; ns < 4; ++ns) {
            int m = ns * 16 + lrow;
            wfb[(size_t)c * M_ + m] = acc[ns][r] + ks_[m] * wb;
        }
    }
}

// ---------------------------------------------------------------------------
// Kernel 6 (MFMA): out = x + gamma*(bl + sum_br norm_br * (Wf_br @ QT^T)).
// QT is bf16 [b][n][m] — direct 16B staging copies.
// ---------------------------------------------------------------------------
__global__ __launch_bounds__(256) void final_mfma_kernel(
    const short* __restrict__ QT, const float* __restrict__ Wf,
    const float* __restrict__ Ksum, const float* __restrict__ x,
    const float* __restrict__ bl, const float* __restrict__ gamma,
    float* __restrict__ out)
{
    const int n0 = blockIdx.x * 64;
    const int c0 = blockIdx.y * 64;
    const int b  = blockIdx.z;

    __shared__ short Qs[64][72];      // [n][m] bf16
    __shared__ short Wfs[3][64][72];  // [br][c][m] bf16
    __shared__ float norms[3][64];
    __shared__ float ksef[3][64];

    const int tid  = threadIdx.x;
    const int lane = tid & 63;
    const int w    = tid >> 6;
    const int lrow = lane & 15;
    const int lkg  = lane >> 4;

    const short* qtb = QT + (size_t)b * N_ * M_;
    #pragma unroll
    for (int i = 0; i < 2; ++i) {
        int f = tid + i * 256;              // 0..511
        int r = f >> 3, m8 = (f & 7) * 8;
        *reinterpret_cast<int4*>(&Qs[r][m8]) =
            *reinterpret_cast<const int4*>(&qtb[(size_t)(n0 + r) * M_ + m8]);
    }
    #pragma unroll
    for (int br = 0; br < 3; ++br) {
        const float* wfb = Wf + (((size_t)b * 3 + br) * C_ + c0) * M_;
        #pragma unroll
        for (int i = 0; i < 4; ++i) {
            int f = tid + i * 256;
            int r = f >> 4, m4 = (f & 15) * 4;
            float4 v = *reinterpret_cast<const float4*>(&wfb[(size_t)r * M_ + m4]);
            short4 s;
            s.x = f2bf(v.x); s.y = f2bf(v.y); s.z = f2bf(v.z); s.w = f2bf(v.w);
            *reinterpret_cast<short4*>(&Wfs[br][r][m4]) = s;
        }
    }
    if (tid < 192) {
        int br = tid >> 6, m = tid & 63;
        ksef[br][m] = Ksum[((size_t)b * 3 + br) * M_ + m] + EPS_;
    }
    __syncthreads();
    if (tid < 192) {
        int br = tid >> 6, n = tid & 63;
        float s = 0.f;
        #pragma unroll 16
        for (int m = 0; m < 64; ++m) s = fmaf(bf2f(Qs[n][m]), ksef[br][m], s);
        norms[br][n] = 1.0f / s;
    }
    __syncthreads();

    f32x4 tot[4] = {{0.f,0.f,0.f,0.f},{0.f,0.f,0.f,0.f},{0.f,0.f,0.f,0.f},{0.f,0.f,0.f,0.f}};
    for (int br = 0; br < 3; ++br) {
        f32x4 acc[4] = {{0.f,0.f,0.f,0.f},{0.f,0.f,0.f,0.f},{0.f,0.f,0.f,0.f},{0.f,0.f,0.f,0.f}};
        #pragma unroll
        for (int ks = 0; ks < 2; ++ks) {
            bf16x8 a = *reinterpret_cast<const bf16x8*>(&Wfs[br][w * 16 + lrow][ks * 32 + lkg * 8]);
            #pragma unroll
            for (int ns = 0; ns < 4; ++ns) {
                bf16x8 bq = *reinterpret_cast<const bf16x8*>(&Qs[ns * 16 + lrow][ks * 32 + lkg * 8]);
                acc[ns] = __builtin_amdgcn_mfma_f32_16x16x32_bf16(a, bq, acc[ns], 0, 0, 0);
            }
        }
        #pragma unroll
        for (int ns = 0; ns < 4; ++ns) {
            float nf = norms[br][ns * 16 + lrow];
            #pragma unroll
            for (int r = 0; r < 4; ++r) tot[ns][r] = fmaf(nf, acc[ns][r], tot[ns][r]);
        }
    }

    const float g = gamma[0];
    const float* xb = x + (size_t)b * C_ * N_;
    float* ob = out + (size_t)b * C_ * N_;
    #pragma unroll
    for (int r = 0; r < 4; ++r) {
        int c = c0 + w * 16 + lkg * 4 + r;
        float blc = bl[c];
        #pragma unroll
        for (int ns = 0; ns < 4; ++ns) {
            int n = n0 + ns * 16 + lrow;
            ob[(size_t)c * N_ + n] = fmaf(g, tot[ns][r] + blc, xb[(size_t)c * N_ + n]);
        }
    }
}

// ---------------------------------------------------------------------------
extern "C" void kernel_launch(void* const* d_in, const int* in_sizes, int n_in,
                              void* d_out, int out_size, void* d_ws, size_t ws_size,
                              hipStream_t stream)
{
    const float* x   = (const float*)d_in[0];
    const float* y   = (const float*)d_in[1];
    const float* z   = (const float*)d_in[2];
    const float* Wq  = (const float*)d_in[3];
    const float* bq  = (const float*)d_in[4];
    const float* Wk1 = (const float*)d_in[5];
    const float* bk1 = (const float*)d_in[6];
    const float* Wk2 = (const float*)d_in[7];
    const float* bk2 = (const float*)d_in[8];
    const float* Wk3 = (const float*)d_in[9];
    const float* bk3 = (const float*)d_in[10];
    const float* Wv  = (const float*)d_in[11];
    const float* bv  = (const float*)d_in[12];
    const float* Wl  = (const float*)d_in[13];
    const float* bl  = (const float*)d_in[14];
    const float* gamma = (const float*)d_in[15];
    float* out = (float*)d_out;

    // workspace layout — QT/Kbuf now bf16; total ~16.9 MB.
    float* ws = (float*)d_ws;
    const size_t QSZ  = (size_t)B_ * M_ * N_;        // 2,097,152 elements
    const size_t BMC  = (size_t)B_ * M_ * C_;        //   262,144
    short* QTs   = (short*)ws;                        // [B][N][M] bf16 (QSZ shorts)
    short* Kbufs = QTs + QSZ;                         // [B][M][N] bf16 (QSZ shorts)
    float* KX    = ws + QSZ;                          // after the 2 short buffers
    float* Ksum  = KX + 3 * BMC;                      // [B][3][M]
    float* WlWv  = Ksum + (size_t)B_ * 3 * M_;        // [C][C]
    float* Wlbv  = WlWv + (size_t)C_ * C_;            // [C]
    float* Ksumpart = Wlbv + C_;                      // [B][64][M]
    float* KXpart = Ksumpart + (size_t)B_ * 64 * M_;  // shared 4MB slot
    float* WlWvPart = KXpart;                         // alias
    float* Wf   = KXpart;                             // alias

    dim3 blk(256);
    const dim3 featGrid(N_ / 64, 1, B_);

    // Q features (bf16 transposed output)
    feat_mfma<<<featGrid, blk, 0, stream>>>(x, Wq, bq, QTs, 1, nullptr);

    // K branches, sequenced through Kbufs (bf16)
    const float* kin[3]  = { x, y, z };
    const float* kW[3]   = { Wk1, Wk2, Wk3 };
    const float* kb_[3]  = { bk1, bk2, bk3 };
    for (int br = 0; br < 3; ++br) {
        feat_mfma<<<featGrid, blk, 0, stream>>>(kin[br], kW[br], kb_[br], Kbufs, 0, Ksumpart);
        ksum_finalize<<<dim3((B_ * M_ + 255) / 256), blk, 0, stream>>>(Ksumpart, Ksum, br);
        kx_mfma_kernel<<<dim3(C_ / 32, NCHUNK_, B_), blk, 0, stream>>>(Kbufs, x, KXpart);
        kx_reduce_kernel<<<dim3(((int)BMC + 255) / 256), blk, 0, stream>>>(KXpart, KX, br);
    }

    // batch-independent fused weights
    wlwv_mfma<<<dim3(C_ / 64, C_ / 64, 4), blk, 0, stream>>>(Wl, Wv, WlWvPart);
    wlwv_reduce<<<dim3(((int)((size_t)C_ * C_) + 255) / 256), blk, 0, stream>>>(WlWvPart, WlWv);
    wlbv_kernel<<<dim3((C_ + 255) / 256), blk, 0, stream>>>(Wl, bv, Wlbv);
    // per-batch fused weights
    wfused_mfma<<<dim3(C_ / 64, 3, B_), blk, 0, stream>>>(WlWv, KX, Ksum, Wlbv, Wf);
    // final: norms + MFMA GEMM + bias + residual
    final_mfma_kernel<<<dim3(N_ / 64, C_ / 64, B_), blk, 0, stream>>>(
        QTs, Wf, Ksum, x, bl, gamma, out);
}

// Round 14
// 169.228 us; speedup vs baseline: 11.3556x; 1.2656x over previous
//
#include <hip/hip_runtime.h>
#include <hip/hip_bf16.h>
#include <math.h>

// Problem constants
constexpr int B_ = 8;
constexpr int C_ = 512;
constexpr int M_ = 64;     // C/8
constexpr int N_ = 4096;   // H*W
constexpr int NCHUNK_ = 4; // split-N factor for kx
constexpr float EPS_ = 1e-10f;
constexpr float PARAM_ = 10.0f;

typedef __attribute__((ext_vector_type(4))) float f32x4;
typedef __attribute__((ext_vector_type(8))) short bf16x8;   // 8 bf16 in 4 VGPRs

// elus feature map: t>0 ? 10t+1 : exp(10t)
__device__ __forceinline__ float elus(float t) {
    return (t > 0.f) ? fmaf(PARAM_, t, 1.f) : expf(PARAM_ * t);
}

// fp32 -> bf16 round-to-nearest-even (finite inputs only)
__device__ __forceinline__ short f2bf(float f) {
    unsigned u = __builtin_bit_cast(unsigned, f);
    u += 0x7FFFu + ((u >> 16) & 1u);
    return (short)(u >> 16);
}
// bf16 bits -> fp32
__device__ __forceinline__ float bf2f(short s) {
    unsigned u = ((unsigned)(unsigned short)s) << 16;
    return __builtin_bit_cast(float, u);
}

// ---------------------------------------------------------------------------
// Kernel 1 (MFMA): ALL FOUR feature GEMMs in one launch.
// blockIdx.y: 0 -> Q (writes QT[b][n][m] bf16), 1..3 -> K branch br=y-1
// (writes Kbuf3[br] bf16 [b][m][n] + fused ksum partials).
// ---------------------------------------------------------------------------
__global__ __launch_bounds__(256) void feat_mfma(
    const float* __restrict__ x, const float* __restrict__ y,
    const float* __restrict__ z,
    const float* __restrict__ Wq, const float* __restrict__ bq,
    const float* __restrict__ Wk1, const float* __restrict__ bk1,
    const float* __restrict__ Wk2, const float* __restrict__ bk2,
    const float* __restrict__ Wk3, const float* __restrict__ bk3,
    short* __restrict__ QT, short* __restrict__ Kbuf3,
    float* __restrict__ Ksumpart)
{
    const int n0 = blockIdx.x * 64;
    const int which = blockIdx.y;
    const int b  = blockIdx.z;

    const float* in; const float* W; const float* bias;
    if (which == 0)      { in = x; W = Wq;  bias = bq;  }
    else if (which == 1) { in = x; W = Wk1; bias = bk1; }
    else if (which == 2) { in = y; W = Wk2; bias = bk2; }
    else                 { in = z; W = Wk3; bias = bk3; }

    __shared__ short Wlds[64][72];   // [m][k] bf16, 144B row stride
    __shared__ short Xlds[64][72];   // [n][k] bf16 (transposed tile)

    const int tid  = threadIdx.x;
    const int lane = tid & 63;
    const int w    = tid >> 6;       // wave id 0..3 -> m rows w*16..+15
    const int lrow = lane & 15;
    const int lkg  = lane >> 4;

    const float* inb = in + (size_t)b * C_ * N_;

    f32x4 acc[4] = {{0.f,0.f,0.f,0.f},{0.f,0.f,0.f,0.f},{0.f,0.f,0.f,0.f},{0.f,0.f,0.f,0.f}};

    const int kq = tid >> 4;   // 0..15 -> k base kq*4 (X transpose staging)
    const int nq = tid & 15;   // 0..15 -> n base nq*4

    for (int kc = 0; kc < C_ / 64; ++kc) {
        const int k0 = kc * 64;
        __syncthreads();   // previous chunk's frag reads done
        #pragma unroll
        for (int i = 0; i < 4; ++i) {
            int f = tid + i * 256;
            int r = f >> 4, c4 = (f & 15) * 4;
            f32x4 v = *reinterpret_cast<const f32x4*>(&W[(size_t)r * C_ + k0 + c4]);
            short4 s;
            s.x = f2bf(v[0]); s.y = f2bf(v[1]); s.z = f2bf(v[2]); s.w = f2bf(v[3]);
            *reinterpret_cast<short4*>(&Wlds[r][c4]) = s;
        }
        f32x4 v0 = *reinterpret_cast<const f32x4*>(&inb[(size_t)(k0 + kq * 4 + 0) * N_ + n0 + nq * 4]);
        f32x4 v1 = *reinterpret_cast<const f32x4*>(&inb[(size_t)(k0 + kq * 4 + 1) * N_ + n0 + nq * 4]);
        f32x4 v2 = *reinterpret_cast<const f32x4*>(&inb[(size_t)(k0 + kq * 4 + 2) * N_ + n0 + nq * 4]);
        f32x4 v3 = *reinterpret_cast<const f32x4*>(&inb[(size_t)(k0 + kq * 4 + 3) * N_ + n0 + nq * 4]);
        #pragma unroll
        for (int c = 0; c < 4; ++c) {
            short4 s;
            s.x = f2bf(v0[c]); s.y = f2bf(v1[c]); s.z = f2bf(v2[c]); s.w = f2bf(v3[c]);
            *reinterpret_cast<short4*>(&Xlds[nq * 4 + c][kq * 4]) = s;
        }
        __syncthreads();
        #pragma unroll
        for (int ks = 0; ks < 2; ++ks) {
            bf16x8 a = *reinterpret_cast<const bf16x8*>(&Wlds[w * 16 + lrow][ks * 32 + lkg * 8]);
            #pragma unroll
            for (int ns = 0; ns < 4; ++ns) {
                bf16x8 bx = *reinterpret_cast<const bf16x8*>(&Xlds[ns * 16 + lrow][ks * 32 + lkg * 8]);
                acc[ns] = __builtin_amdgcn_mfma_f32_16x16x32_bf16(a, bx, acc[ns], 0, 0, 0);
            }
        }
    }

    if (which != 0) {
        // K branch: bf16 store + fused column-sum partials.
        const int br = which - 1;
        short* outb = Kbuf3 + ((size_t)br * B_ + b) * M_ * N_;
        float* ksp  = Ksumpart + ((size_t)br * B_ + b) * 64 * M_;  // [nblk][m]
        #pragma unroll
        for (int r = 0; r < 4; ++r) {
            int m = w * 16 + lkg * 4 + r;
            float bi = bias[m];
            float sv = 0.f;
            #pragma unroll
            for (int ns = 0; ns < 4; ++ns) {
                int n = n0 + ns * 16 + lrow;
                float e = elus(acc[ns][r] + bi);
                outb[(size_t)m * N_ + n] = f2bf(e);
                sv += e;
            }
            // reduce over the 16 lrow lanes (xor bits 0..3 stay in-group)
            sv += __shfl_xor(sv, 1);
            sv += __shfl_xor(sv, 2);
            sv += __shfl_xor(sv, 4);
            sv += __shfl_xor(sv, 8);
            if (lrow == 0)
                ksp[(size_t)blockIdx.x * M_ + m] = sv;
        }
    } else {
        // QT[b][n][m] bf16: 4 consecutive m per lane -> short4 store
        short* outb = QT + (size_t)b * N_ * M_;
        int mbase = w * 16 + lkg * 4;
        float bi[4];
        #pragma unroll
        for (int r = 0; r < 4; ++r) bi[r] = bias[mbase + r];
        #pragma unroll
        for (int ns = 0; ns < 4; ++ns) {
            int n = n0 + ns * 16 + lrow;
            short4 s;
            s.x = f2bf(elus(acc[ns][0] + bi[0]));
            s.y = f2bf(elus(acc[ns][1] + bi[1]));
            s.z = f2bf(elus(acc[ns][2] + bi[2]));
            s.w = f2bf(elus(acc[ns][3] + bi[3]));
            *reinterpret_cast<short4*>(&outb[(size_t)n * M_ + mbase]) = s;
        }
    }
}

// ---------------------------------------------------------------------------
// Kernel 2: Ksum[b][br][m] = sum_nb Ksumpart[br][b][nb][m]  (all branches)
// ---------------------------------------------------------------------------
__global__ __launch_bounds__(256) void ksum_finalize(const float* __restrict__ Ksumpart,
                                                     float* __restrict__ Ksum)
{
    int i = blockIdx.x * 256 + threadIdx.x;   // 0..1535 = (br, b, m)
    if (i >= 3 * B_ * M_) return;
    int br = i / (B_ * M_);
    int rem = i - br * (B_ * M_);
    int b = rem >> 6, m = rem & 63;
    const float* ksp = Ksumpart + ((size_t)br * B_ + b) * 64 * M_;
    float s = 0.f;
    #pragma unroll 8
    for (int nb = 0; nb < 64; ++nb) s += ksp[(size_t)nb * M_ + m];
    Ksum[((size_t)b * 3 + br) * M_ + m] = s;
}

// ---------------------------------------------------------------------------
// Kernel 3a (MFMA): split-N partial KX for ALL THREE branches in one pass.
// Stages each x tile ONCE, MFMAs against 3 K tiles (x traffic / staging 3x
// amortized vs per-branch kx).  LDS: Klds[3][64][72] + Xlds[32][72] = 31.5KB.
// KXpart3[br][nc][b][m][c].
// ---------------------------------------------------------------------------
__global__ __launch_bounds__(256) void kx3_mfma(const short* __restrict__ Kbuf3,
                                                const float* __restrict__ x,
                                                float* __restrict__ KXpart3)
{
    const int c0 = blockIdx.x * 32;
    const int nc = blockIdx.y;
    const int b  = blockIdx.z;
    const int nbeg = nc * (N_ / NCHUNK_);

    __shared__ short Klds[3][64][72];
    __shared__ short Xlds[32][72];

    const int tid  = threadIdx.x;
    const int lane = tid & 63;
    const int w    = tid >> 6;
    const int lrow = lane & 15;
    const int lkg  = lane >> 4;

    const float* xb = x + ((size_t)b * C_ + c0) * N_;

    f32x4 acc[3][2] = {};

    for (int it = 0; it < (N_ / NCHUNK_) / 64; ++it) {
        const int n0 = nbeg + it * 64;
        __syncthreads();
        // 3 K tiles: already bf16 — straight 16B copies (64 rows x 64 shorts each)
        #pragma unroll
        for (int br = 0; br < 3; ++br) {
            const short* kb = Kbuf3 + ((size_t)br * B_ + b) * M_ * N_;
            #pragma unroll
            for (int i = 0; i < 2; ++i) {
                int f = tid + i * 256;              // 0..511
                int r = f >> 3, c8 = (f & 7) * 8;
                *reinterpret_cast<int4*>(&Klds[br][r][c8]) =
                    *reinterpret_cast<const int4*>(&kb[(size_t)r * N_ + n0 + c8]);
            }
        }
        // X tile: fp32 -> bf16 (staged once for all 3 branches)
        #pragma unroll
        for (int i = 0; i < 2; ++i) {
            int f = tid + i * 256;              // 0..511
            int r = f >> 4, c4 = (f & 15) * 4;
            float4 v = *reinterpret_cast<const float4*>(&xb[(size_t)r * N_ + n0 + c4]);
            short4 s;
            s.x = f2bf(v.x); s.y = f2bf(v.y); s.z = f2bf(v.z); s.w = f2bf(v.w);
            *reinterpret_cast<short4*>(&Xlds[r][c4]) = s;
        }
        __syncthreads();
        #pragma unroll
        for (int s = 0; s < 2; ++s) {
            bf16x8 b0 = *reinterpret_cast<const bf16x8*>(&Xlds[lrow][s * 32 + lkg * 8]);
            bf16x8 b1 = *reinterpret_cast<const bf16x8*>(&Xlds[16 + lrow][s * 32 + lkg * 8]);
            #pragma unroll
            for (int br = 0; br < 3; ++br) {
                bf16x8 a = *reinterpret_cast<const bf16x8*>(&Klds[br][w * 16 + lrow][s * 32 + lkg * 8]);
                acc[br][0] = __builtin_amdgcn_mfma_f32_16x16x32_bf16(a, b0, acc[br][0], 0, 0, 0);
                acc[br][1] = __builtin_amdgcn_mfma_f32_16x16x32_bf16(a, b1, acc[br][1], 0, 0, 0);
            }
        }
    }

    #pragma unroll
    for (int br = 0; br < 3; ++br) {
        float* outp = KXpart3 + (((size_t)br * NCHUNK_ + nc) * B_ + b) * M_ * C_;
        #pragma unroll
        for (int r = 0; r < 4; ++r) {
            int m = w * 16 + lkg * 4 + r;
            outp[(size_t)m * C_ + c0 + lrow]      = acc[br][0][r];
            outp[(size_t)m * C_ + c0 + 16 + lrow] = acc[br][1][r];
        }
    }
}

// ---------------------------------------------------------------------------
// Kernel 3b: reduce partials for all branches (fixed order — deterministic).
// ---------------------------------------------------------------------------
__global__ __launch_bounds__(256) void kx3_reduce(const float* __restrict__ KXpart3,
                                                  float* __restrict__ KX)
{
    const size_t BMC = (size_t)B_ * M_ * C_;
    size_t i = (size_t)blockIdx.x * 256 + threadIdx.x;
    if (i >= 3 * BMC) return;
    int br = (int)(i / BMC);
    size_t rem = i - (size_t)br * BMC;           // [b][m][c]
    float s = 0.f;
    #pragma unroll
    for (int nc = 0; nc < NCHUNK_; ++nc)
        s += KXpart3[((size_t)br * NCHUNK_ + nc) * BMC + rem];
    size_t b = rem / ((size_t)M_ * C_);
    size_t mc = rem - b * (size_t)M_ * C_;
    KX[((size_t)b * 3 + br) * M_ * C_ + mc] = s;
}

// ---------------------------------------------------------------------------
// Kernel 4a (MFMA): WlWvPart[pc][c][k] = sum_{p in chunk pc} Wl[c][p]*Wv[p][k]
// ---------------------------------------------------------------------------
__global__ __launch_bounds__(256) void wlwv_mfma(const float* __restrict__ Wl,
                                                 const float* __restrict__ Wv,
                                                 float* __restrict__ part)
{
    const int k0 = blockIdx.x * 64;
    const int c0 = blockIdx.y * 64;
    const int pc = blockIdx.z;

    __shared__ short Al[64][72];
    __shared__ short Bt[64][72];

    const int tid  = threadIdx.x;
    const int lane = tid & 63;
    const int w    = tid >> 6;
    const int lrow = lane & 15;
    const int lkg  = lane >> 4;
    const int pq = tid >> 4;
    const int nq = tid & 15;

    f32x4 acc[4] = {{0.f,0.f,0.f,0.f},{0.f,0.f,0.f,0.f},{0.f,0.f,0.f,0.f},{0.f,0.f,0.f,0.f}};

    for (int it = 0; it < 2; ++it) {
        const int p0 = pc * 128 + it * 64;
        __syncthreads();
        #pragma unroll
        for (int i = 0; i < 4; ++i) {
            int f = tid + i * 256;
            int r = f >> 4, c4 = (f & 15) * 4;
            f32x4 v = *reinterpret_cast<const f32x4*>(&Wl[(size_t)(c0 + r) * C_ + p0 + c4]);
            short4 s;
            s.x = f2bf(v[0]); s.y = f2bf(v[1]); s.z = f2bf(v[2]); s.w = f2bf(v[3]);
            *reinterpret_cast<short4*>(&Al[r][c4]) = s;
        }
        f32x4 v0 = *reinterpret_cast<const f32x4*>(&Wv[(size_t)(p0 + pq * 4 + 0) * C_ + k0 + nq * 4]);
        f32x4 v1 = *reinterpret_cast<const f32x4*>(&Wv[(size_t)(p0 + pq * 4 + 1) * C_ + k0 + nq * 4]);
        f32x4 v2 = *reinterpret_cast<const f32x4*>(&Wv[(size_t)(p0 + pq * 4 + 2) * C_ + k0 + nq * 4]);
        f32x4 v3 = *reinterpret_cast<const f32x4*>(&Wv[(size_t)(p0 + pq * 4 + 3) * C_ + k0 + nq * 4]);
        #pragma unroll
        for (int c = 0; c < 4; ++c) {
            short4 s;
            s.x = f2bf(v0[c]); s.y = f2bf(v1[c]); s.z = f2bf(v2[c]); s.w = f2bf(v3[c]);
            *reinterpret_cast<short4*>(&Bt[nq * 4 + c][pq * 4]) = s;
        }
        __syncthreads();
        #pragma unroll
        for (int ks = 0; ks < 2; ++ks) {
            bf16x8 a = *reinterpret_cast<const bf16x8*>(&Al[w * 16 + lrow][ks * 32 + lkg * 8]);
            #pragma unroll
            for (int ns = 0; ns < 4; ++ns) {
                bf16x8 bx = *reinterpret_cast<const bf16x8*>(&Bt[ns * 16 + lrow][ks * 32 + lkg * 8]);
                acc[ns] = __builtin_amdgcn_mfma_f32_16x16x32_bf16(a, bx, acc[ns], 0, 0, 0);
            }
        }
    }

    float* pp = part + (size_t)pc * C_ * C_;
    #pragma unroll
    for (int r = 0; r < 4; ++r) {
        int c = c0 + w * 16 + lkg * 4 + r;
        #pragma unroll
        for (int ns = 0; ns < 4; ++ns) {
            int k = k0 + ns * 16 + lrow;
            pp[(size_t)c * C_ + k] = acc[ns][r];
        }
    }
}

// Kernel 4b: WlWv[i] = sum_pc part[pc][i]  (fixed order)
__global__ __launch_bounds__(256) void wlwv_reduce(const float* __restrict__ part,
                                                   float* __restrict__ WlWv)
{
    const size_t CC = (size_t)C_ * C_;
    size_t i = (size_t)blockIdx.x * 256 + threadIdx.x;
    if (i >= CC) return;
    float s = 0.f;
    #pragma unroll
    for (int pc = 0; pc < 4; ++pc) s += part[pc * CC + i];
    WlWv[i] = s;
}

// Wlbv[c] = sum_p Wl[c][p] * bv[p]
__global__ __launch_bounds__(256) void wlbv_kernel(const float* __restrict__ Wl,
                                                   const float* __restrict__ bv,
                                                   float* __restrict__ Wlbv)
{
    int c = blockIdx.x * 256 + threadIdx.x;
    if (c < C_) {
        float s = 0.f;
        for (int p = 0; p < C_; ++p) s = fmaf(Wl[(size_t)c * C_ + p], bv[p], s);
        Wlbv[c] = s;
    }
}

// ---------------------------------------------------------------------------
// Kernel 5 (MFMA): Wf[b][br][c][m] = sum_k WlWv[c][k]*KX[b][br][m][k]
//                                    + Ksum[b][br][m]*Wlbv[c]
// ---------------------------------------------------------------------------
__global__ __launch_bounds__(256) void wfused_mfma(const float* __restrict__ WlWv,
                                                   const float* __restrict__ KX,
                                                   const float* __restrict__ Ksum,
                                                   const float* __restrict__ Wlbv,
                                                   float* __restrict__ Wf)
{
    const int c0 = blockIdx.x * 64;
    const int br = blockIdx.y;
    const int b  = blockIdx.z;

    __shared__ short Al[64][72];   // WlWv[c][k] bf16
    __shared__ short Bl[64][72];   // KX[m][k] bf16

    const int tid  = threadIdx.x;
    const int lane = tid & 63;
    const int w    = tid >> 6;
    const int lrow = lane & 15;
    const int lkg  = lane >> 4;

    const float* kxb = KX + ((size_t)b * 3 + br) * M_ * C_;

    f32x4 acc[4] = {{0.f,0.f,0.f,0.f},{0.f,0.f,0.f,0.f},{0.f,0.f,0.f,0.f},{0.f,0.f,0.f,0.f}};

    for (int kc = 0; kc < C_ / 64; ++kc) {
        const int k0 = kc * 64;
        __syncthreads();
        #pragma unroll
        for (int i = 0; i < 4; ++i) {
            int f = tid + i * 256;
            int r = f >> 4, c4 = (f & 15) * 4;
            f32x4 v = *reinterpret_cast<const f32x4*>(&WlWv[(size_t)(c0 + r) * C_ + k0 + c4]);
            short4 s;
            s.x = f2bf(v[0]); s.y = f2bf(v[1]); s.z = f2bf(v[2]); s.w = f2bf(v[3]);
            *reinterpret_cast<short4*>(&Al[r][c4]) = s;
        }
        #pragma unroll
        for (int i = 0; i < 4; ++i) {
            int f = tid + i * 256;
            int r = f >> 4, c4 = (f & 15) * 4;
            f32x4 v = *reinterpret_cast<const f32x4*>(&kxb[(size_t)r * C_ + k0 + c4]);
            short4 s;
            s.x = f2bf(v[0]); s.y = f2bf(v[1]); s.z = f2bf(v[2]); s.w = f2bf(v[3]);
            *reinterpret_cast<short4*>(&Bl[r][c4]) = s;
        }
        __syncthreads();
        #pragma unroll
        for (int ks = 0; ks < 2; ++ks) {
            bf16x8 a = *reinterpret_cast<const bf16x8*>(&Al[w * 16 + lrow][ks * 32 + lkg * 8]);
            #pragma unroll
            for (int ns = 0; ns < 4; ++ns) {
                bf16x8 bx = *reinterpret_cast<const bf16x8*>(&Bl[ns * 16 + lrow][ks * 32 + lkg * 8]);
                acc[ns] = __builtin_amdgcn_mfma_f32_16x16x32_bf16(a, bx, acc[ns], 0, 0, 0);
            }
        }
    }

    const float* ks_ = Ksum + ((size_t)b * 3 + br) * M_;
    float* wfb = Wf + (((size_t)b * 3 + br) * C_) * M_;
    #pragma unroll
    for (int r = 0; r < 4; ++r) {
        int c = c0 + w * 16 + lkg * 4 + r;
        float wb = Wlbv[c];
        #pragma unroll
        for (int ns = 0; ns < 4; ++ns) {
            int m = ns * 16 + lrow;
            wfb[(size_t)c * M_ + m] = acc[ns][r] + ks_[m] * wb;
        }
    }
}

// ---------------------------------------------------------------------------
// Kernel 6 (MFMA): out = x + gamma*(bl + sum_br norm_br * (Wf_br @ QT^T)).
// ---------------------------------------------------------------------------
__global__ __launch_bounds__(256) void final_mfma_kernel(
    const short* __restrict__ QT, const float* __restrict__ Wf,
    const float* __restrict__ Ksum, const float* __restrict__ x,
    const float* __restrict__ bl, const float* __restrict__ gamma,
    float* __restrict__ out)
{
    const int n0 = blockIdx.x * 64;
    const int c0 = blockIdx.y * 64;
    const int b  = blockIdx.z;

    __shared__ short Qs[64][72];      // [n][m] bf16
    __shared__ short Wfs[3][64][72];  // [br][c][m] bf16
    __shared__ float norms[3][64];
    __shared__ float ksef[3][64];

    const int tid  = threadIdx.x;
    const int lane = tid & 63;
    const int w    = tid >> 6;
    const int lrow = lane & 15;
    const int lkg  = lane >> 4;

    const short* qtb = QT + (size_t)b * N_ * M_;
    #pragma unroll
    for (int i = 0; i < 2; ++i) {
        int f = tid + i * 256;              // 0..511
        int r = f >> 3, m8 = (f & 7) * 8;
        *reinterpret_cast<int4*>(&Qs[r][m8]) =
            *reinterpret_cast<const int4*>(&qtb[(size_t)(n0 + r) * M_ + m8]);
    }
    #pragma unroll
    for (int br = 0; br < 3; ++br) {
        const float* wfb = Wf + (((size_t)b * 3 + br) * C_ + c0) * M_;
        #pragma unroll
        for (int i = 0; i < 4; ++i) {
            int f = tid + i * 256;
            int r = f >> 4, m4 = (f & 15) * 4;
            float4 v = *reinterpret_cast<const float4*>(&wfb[(size_t)r * M_ + m4]);
            short4 s;
            s.x = f2bf(v.x); s.y = f2bf(v.y); s.z = f2bf(v.z); s.w = f2bf(v.w);
            *reinterpret_cast<short4*>(&Wfs[br][r][m4]) = s;
        }
    }
    if (tid < 192) {
        int br = tid >> 6, m = tid & 63;
        ksef[br][m] = Ksum[((size_t)b * 3 + br) * M_ + m] + EPS_;
    }
    __syncthreads();
    if (tid < 192) {
        int br = tid >> 6, n = tid & 63;
        float s = 0.f;
        #pragma unroll 16
        for (int m = 0; m < 64; ++m) s = fmaf(bf2f(Qs[n][m]), ksef[br][m], s);
        norms[br][n] = 1.0f / s;
    }
    __syncthreads();

    f32x4 tot[4] = {{0.f,0.f,0.f,0.f},{0.f,0.f,0.f,0.f},{0.f,0.f,0.f,0.f},{0.f,0.f,0.f,0.f}};
    for (int br = 0; br < 3; ++br) {
        f32x4 acc[4] = {{0.f,0.f,0.f,0.f},{0.f,0.f,0.f,0.f},{0.f,0.f,0.f,0.f},{0.f,0.f,0.f,0.f}};
        #pragma unroll
        for (int ks = 0; ks < 2; ++ks) {
            bf16x8 a = *reinterpret_cast<const bf16x8*>(&Wfs[br][w * 16 + lrow][ks * 32 + lkg * 8]);
            #pragma unroll
            for (int ns = 0; ns < 4; ++ns) {
                bf16x8 bq = *reinterpret_cast<const bf16x8*>(&Qs[ns * 16 + lrow][ks * 32 + lkg * 8]);
                acc[ns] = __builtin_amdgcn_mfma_f32_16x16x32_bf16(a, bq, acc[ns], 0, 0, 0);
            }
        }
        #pragma unroll
        for (int ns = 0; ns < 4; ++ns) {
            float nf = norms[br][ns * 16 + lrow];
            #pragma unroll
            for (int r = 0; r < 4; ++r) tot[ns][r] = fmaf(nf, acc[ns][r], tot[ns][r]);
        }
    }

    const float g = gamma[0];
    const float* xb = x + (size_t)b * C_ * N_;
    float* ob = out + (size_t)b * C_ * N_;
    #pragma unroll
    for (int r = 0; r < 4; ++r) {
        int c = c0 + w * 16 + lkg * 4 + r;
        float blc = bl[c];
        #pragma unroll
        for (int ns = 0; ns < 4; ++ns) {
            int n = n0 + ns * 16 + lrow;
            ob[(size_t)c * N_ + n] = fmaf(g, tot[ns][r] + blc, xb[(size_t)c * N_ + n]);
        }
    }
}

// ---------------------------------------------------------------------------
extern "C" void kernel_launch(void* const* d_in, const int* in_sizes, int n_in,
                              void* d_out, int out_size, void* d_ws, size_t ws_size,
                              hipStream_t stream)
{
    const float* x   = (const float*)d_in[0];
    const float* y   = (const float*)d_in[1];
    const float* z   = (const float*)d_in[2];
    const float* Wq  = (const float*)d_in[3];
    const float* bq  = (const float*)d_in[4];
    const float* Wk1 = (const float*)d_in[5];
    const float* bk1 = (const float*)d_in[6];
    const float* Wk2 = (const float*)d_in[7];
    const float* bk2 = (const float*)d_in[8];
    const float* Wk3 = (const float*)d_in[9];
    const float* bk3 = (const float*)d_in[10];
    const float* Wv  = (const float*)d_in[11];
    const float* bv  = (const float*)d_in[12];
    const float* Wl  = (const float*)d_in[13];
    const float* bl  = (const float*)d_in[14];
    const float* gamma = (const float*)d_in[15];
    float* out = (float*)d_out;

    // workspace layout — ws_size is 256 MiB (measured: harness poison-fill
    // WRITE_SIZE = 262144 KB); we use ~34 MB.  All 3 K branches now live
    // simultaneously in bf16 so the branch chains are batched.
    float* ws = (float*)d_ws;
    const size_t QSZ  = (size_t)B_ * M_ * N_;        // 2,097,152 elements
    const size_t BMC  = (size_t)B_ * M_ * C_;        //   262,144
    short* QTs   = (short*)ws;                        // [B][N][M] bf16
    short* Kbuf3 = QTs + QSZ;                         // [3][B][M][N] bf16 (12 MB)
    float* fbase = ws + (QSZ / 2) + (3 * QSZ / 2);    // = ws + 2*QSZ floats
    float* KX    = fbase;                             // [B][3][M][C]
    float* Ksum  = KX + 3 * BMC;                      // [B][3][M]
    float* WlWv  = Ksum + (size_t)B_ * 3 * M_;        // [C][C]
    float* Wlbv  = WlWv + (size_t)C_ * C_;            // [C]
    float* Ksumpart = Wlbv + C_;                      // [3][B][64][M]
    float* KXpart3  = Ksumpart + (size_t)3 * B_ * 64 * M_;  // [3][4][B][M][C] (12MB)
    float* WlWvPart = KXpart3;                        // alias (4MB, dead before wlwv)
    float* Wf   = KXpart3;                            // alias (3MB, after kx3_reduce)

    dim3 blk(256);

    // 1) all four feature GEMMs in one launch (Q + 3 K branches)
    feat_mfma<<<dim3(N_ / 64, 4, B_), blk, 0, stream>>>(
        x, y, z, Wq, bq, Wk1, bk1, Wk2, bk2, Wk3, bk3, QTs, Kbuf3, Ksumpart);
    // 2) finalize ksum for all branches
    ksum_finalize<<<dim3((3 * B_ * M_ + 255) / 256), blk, 0, stream>>>(Ksumpart, Ksum);
    // 3) KX for all branches in one pass (x staged once per tile)
    kx3_mfma<<<dim3(C_ / 32, NCHUNK_, B_), blk, 0, stream>>>(Kbuf3, x, KXpart3);
    kx3_reduce<<<dim3((int)((3 * BMC + 255) / 256)), blk, 0, stream>>>(KXpart3, KX);

    // 4) batch-independent fused weights — NOTE: wlwv partials alias KXpart3,
    //    so they must run after kx3_reduce (stream-ordered).
    wlwv_mfma<<<dim3(C_ / 64, C_ / 64, 4), blk, 0, stream>>>(Wl, Wv, WlWvPart);
    wlwv_reduce<<<dim3(((int)((size_t)C_ * C_) + 255) / 256), blk, 0, stream>>>(WlWvPart, WlWv);
    wlbv_kernel<<<dim3((C_ + 255) / 256), blk, 0, stream>>>(Wl, bv, Wlbv);
    // 5) per-batch fused weights
    wfused_mfma<<<dim3(C_ / 64, 3, B_), blk, 0, stream>>>(WlWv, KX, Ksum, Wlbv, Wf);
    // 6) final: norms + MFMA GEMM + bias + residual
    final_mfma_kernel<<<dim3(N_ / 64, C_ / 64, B_), blk, 0, stream>>>(
        QTs, Wf, Ksum, x, bl, gamma, out);
}

// Round 16
// 165.056 us; speedup vs baseline: 11.6426x; 1.0253x over previous
//
#include <hip/hip_runtime.h>
#include <hip/hip_bf16.h>
#include <math.h>

// Problem constants
constexpr int B_ = 8;
constexpr int C_ = 512;
constexpr int M_ = 64;     // C/8
constexpr int N_ = 4096;   // H*W
constexpr int NCHUNK_ = 4; // split-N factor for kx
constexpr float EPS_ = 1e-10f;
constexpr float PARAM_ = 10.0f;

typedef __attribute__((ext_vector_type(4))) float f32x4;
typedef __attribute__((ext_vector_type(8))) short bf16x8;   // 8 bf16 in 4 VGPRs

// elus feature map: t>0 ? 10t+1 : exp(10t)
__device__ __forceinline__ float elus(float t) {
    return (t > 0.f) ? fmaf(PARAM_, t, 1.f) : expf(PARAM_ * t);
}

// fp32 -> bf16 RTNE via the intrinsic the compiler can pack into
// v_cvt_pk_bf16_f32 (hand-rolled bit-twiddle defeated that fusion).
__device__ __forceinline__ short f2bf(float f) {
    return __builtin_bit_cast(short, __float2bfloat16(f));
}
// bf16 bits -> fp32
__device__ __forceinline__ float bf2f(short s) {
    unsigned u = ((unsigned)(unsigned short)s) << 16;
    return __builtin_bit_cast(float, u);
}

// ---------------------------------------------------------------------------
// Kernel 0: convert the 4 feature weight matrices to bf16 once.
// Wbf layout: [4][M][C]  (0=Wq, 1=Wk1, 2=Wk2, 3=Wk3)
// ---------------------------------------------------------------------------
__global__ __launch_bounds__(256) void prep_w(const float* __restrict__ Wq,
                                              const float* __restrict__ Wk1,
                                              const float* __restrict__ Wk2,
                                              const float* __restrict__ Wk3,
                                              short* __restrict__ Wbf)
{
    int i = blockIdx.x * 256 + threadIdx.x;
    const int MC = M_ * C_;
    if (i < MC) {
        Wbf[i]          = f2bf(Wq[i]);
        Wbf[MC + i]     = f2bf(Wk1[i]);
        Wbf[2 * MC + i] = f2bf(Wk2[i]);
        Wbf[3 * MC + i] = f2bf(Wk3[i]);
    }
}

// ---------------------------------------------------------------------------
// Kernel 1 (MFMA): feature GEMMs.
// blockIdx.y = 0: x branch — computes BOTH Q (QT output) and K1 (x staged once,
//                 two W tiles, 2x MFMA).
// blockIdx.y = 1: y -> K2.   blockIdx.y = 2: z -> K3.
// W is pre-converted bf16 (raw int4 LDS copies, no per-block conversion).
// ---------------------------------------------------------------------------
__global__ __launch_bounds__(256) void feat_mfma(
    const float* __restrict__ x, const float* __restrict__ y,
    const float* __restrict__ z, const short* __restrict__ Wbf,
    const float* __restrict__ bq, const float* __restrict__ bk1,
    const float* __restrict__ bk2, const float* __restrict__ bk3,
    short* __restrict__ QT, short* __restrict__ Kbuf3,
    float* __restrict__ Ksumpart)
{
    const int n0 = blockIdx.x * 64;
    const int which = blockIdx.y;       // 0:x->(Q,K1)  1:y->K2  2:z->K3
    const int b  = blockIdx.z;
    const int MC = M_ * C_;

    const float* in = (which == 0) ? x : (which == 1) ? y : z;
    const short* Ws0 = Wbf + (size_t)((which == 0) ? 0 : which + 1) * MC;
    const short* Ws1 = Wbf + (size_t)MC;   // Wk1 (fused path only)

    __shared__ short Wlds[2][64][72];
    __shared__ short Xlds[64][72];

    const int tid  = threadIdx.x;
    const int lane = tid & 63;
    const int w    = tid >> 6;
    const int lrow = lane & 15;
    const int lkg  = lane >> 4;

    const float* inb = in + (size_t)b * C_ * N_;

    f32x4 accA[4] = {{0.f,0.f,0.f,0.f},{0.f,0.f,0.f,0.f},{0.f,0.f,0.f,0.f},{0.f,0.f,0.f,0.f}};
    f32x4 accB[4] = {{0.f,0.f,0.f,0.f},{0.f,0.f,0.f,0.f},{0.f,0.f,0.f,0.f},{0.f,0.f,0.f,0.f}};

    const int kq = tid >> 4;   // 0..15 -> k base kq*4 (X transpose staging)
    const int nq = tid & 15;   // 0..15 -> n base nq*4

    for (int kc = 0; kc < C_ / 64; ++kc) {
        const int k0 = kc * 64;
        __syncthreads();   // previous chunk's frag reads done
        // stage W tile(s): bf16 source, raw int4 copies (0-conflict pattern)
        #pragma unroll
        for (int i = 0; i < 2; ++i) {
            int f = tid + i * 256;
            int r = f >> 3, c8 = (f & 7) * 8;
            *reinterpret_cast<int4*>(&Wlds[0][r][c8]) =
                *reinterpret_cast<const int4*>(&Ws0[(size_t)r * C_ + k0 + c8]);
        }
        if (which == 0) {
            #pragma unroll
            for (int i = 0; i < 2; ++i) {
                int f = tid + i * 256;
                int r = f >> 3, c8 = (f & 7) * 8;
                *reinterpret_cast<int4*>(&Wlds[1][r][c8]) =
                    *reinterpret_cast<const int4*>(&Ws1[(size_t)r * C_ + k0 + c8]);
            }
        }
        // stage X tile transposed (4x4 in-register transpose, fp32 -> bf16)
        f32x4 v0 = *reinterpret_cast<const f32x4*>(&inb[(size_t)(k0 + kq * 4 + 0) * N_ + n0 + nq * 4]);
        f32x4 v1 = *reinterpret_cast<const f32x4*>(&inb[(size_t)(k0 + kq * 4 + 1) * N_ + n0 + nq * 4]);
        f32x4 v2 = *reinterpret_cast<const f32x4*>(&inb[(size_t)(k0 + kq * 4 + 2) * N_ + n0 + nq * 4]);
        f32x4 v3 = *reinterpret_cast<const f32x4*>(&inb[(size_t)(k0 + kq * 4 + 3) * N_ + n0 + nq * 4]);
        #pragma unroll
        for (int c = 0; c < 4; ++c) {
            short4 s;
            s.x = f2bf(v0[c]); s.y = f2bf(v1[c]); s.z = f2bf(v2[c]); s.w = f2bf(v3[c]);
            *reinterpret_cast<short4*>(&Xlds[nq * 4 + c][kq * 4]) = s;
        }
        __syncthreads();
        #pragma unroll
        for (int ks = 0; ks < 2; ++ks) {
            bf16x8 a0 = *reinterpret_cast<const bf16x8*>(&Wlds[0][w * 16 + lrow][ks * 32 + lkg * 8]);
            bf16x8 a1;
            if (which == 0)
                a1 = *reinterpret_cast<const bf16x8*>(&Wlds[1][w * 16 + lrow][ks * 32 + lkg * 8]);
            #pragma unroll
            for (int ns = 0; ns < 4; ++ns) {
                bf16x8 bx = *reinterpret_cast<const bf16x8*>(&Xlds[ns * 16 + lrow][ks * 32 + lkg * 8]);
                accA[ns] = __builtin_amdgcn_mfma_f32_16x16x32_bf16(a0, bx, accA[ns], 0, 0, 0);
                if (which == 0)
                    accB[ns] = __builtin_amdgcn_mfma_f32_16x16x32_bf16(a1, bx, accB[ns], 0, 0, 0);
            }
        }
    }

    // --- epilogues ---
    // K-branch writer (Kbuf3[br] bf16 + ksum partials via 16-lane shfl reduce)
    auto writeK = [&](const f32x4* acc, const float* bias, int br) {
        short* outb = Kbuf3 + ((size_t)br * B_ + b) * M_ * N_;
        float* ksp  = Ksumpart + ((size_t)br * B_ + b) * 64 * M_;  // [nblk][m]
        #pragma unroll
        for (int r = 0; r < 4; ++r) {
            int m = w * 16 + lkg * 4 + r;
            float bi = bias[m];
            float sv = 0.f;
            #pragma unroll
            for (int ns = 0; ns < 4; ++ns) {
                int n = n0 + ns * 16 + lrow;
                float e = elus(acc[ns][r] + bi);
                outb[(size_t)m * N_ + n] = f2bf(e);
                sv += e;
            }
            sv += __shfl_xor(sv, 1);
            sv += __shfl_xor(sv, 2);
            sv += __shfl_xor(sv, 4);
            sv += __shfl_xor(sv, 8);
            if (lrow == 0)
                ksp[(size_t)blockIdx.x * M_ + m] = sv;
        }
    };

    if (which == 0) {
        // Q from accA -> QT[b][n][m] bf16 (short4 along m)
        short* outb = QT + (size_t)b * N_ * M_;
        int mbase = w * 16 + lkg * 4;
        float bi[4];
        #pragma unroll
        for (int r = 0; r < 4; ++r) bi[r] = bq[mbase + r];
        #pragma unroll
        for (int ns = 0; ns < 4; ++ns) {
            int n = n0 + ns * 16 + lrow;
            short4 s;
            s.x = f2bf(elus(accA[ns][0] + bi[0]));
            s.y = f2bf(elus(accA[ns][1] + bi[1]));
            s.z = f2bf(elus(accA[ns][2] + bi[2]));
            s.w = f2bf(elus(accA[ns][3] + bi[3]));
            *reinterpret_cast<short4*>(&outb[(size_t)n * M_ + mbase]) = s;
        }
        // K1 from accB
        writeK(accB, bk1, 0);
    } else {
        writeK(accA, (which == 1) ? bk2 : bk3, which);
    }
}

// ---------------------------------------------------------------------------
// Kernel 2: Ksum[b][br][m] = sum_nb Ksumpart[br][b][nb][m]  (all branches)
// ---------------------------------------------------------------------------
__global__ __launch_bounds__(256) void ksum_finalize(const float* __restrict__ Ksumpart,
                                                     float* __restrict__ Ksum)
{
    int i = blockIdx.x * 256 + threadIdx.x;   // (br, b, m)
    if (i >= 3 * B_ * M_) return;
    int br = i / (B_ * M_);
    int rem = i - br * (B_ * M_);
    int b = rem >> 6, m = rem & 63;
    const float* ksp = Ksumpart + ((size_t)br * B_ + b) * 64 * M_;
    float s = 0.f;
    #pragma unroll 8
    for (int nb = 0; nb < 64; ++nb) s += ksp[(size_t)nb * M_ + m];
    Ksum[((size_t)b * 3 + br) * M_ + m] = s;
}

// ---------------------------------------------------------------------------
// Kernel 3a (MFMA): split-N partial KX for ALL THREE branches in one pass.
// ---------------------------------------------------------------------------
__global__ __launch_bounds__(256) void kx3_mfma(const short* __restrict__ Kbuf3,
                                                const float* __restrict__ x,
                                                float* __restrict__ KXpart3)
{
    const int c0 = blockIdx.x * 32;
    const int nc = blockIdx.y;
    const int b  = blockIdx.z;
    const int nbeg = nc * (N_ / NCHUNK_);

    __shared__ short Klds[3][64][72];
    __shared__ short Xlds[32][72];

    const int tid  = threadIdx.x;
    const int lane = tid & 63;
    const int w    = tid >> 6;
    const int lrow = lane & 15;
    const int lkg  = lane >> 4;

    const float* xb = x + ((size_t)b * C_ + c0) * N_;

    f32x4 acc[3][2] = {};

    for (int it = 0; it < (N_ / NCHUNK_) / 64; ++it) {
        const int n0 = nbeg + it * 64;
        __syncthreads();
        #pragma unroll
        for (int br = 0; br < 3; ++br) {
            const short* kb = Kbuf3 + ((size_t)br * B_ + b) * M_ * N_;
            #pragma unroll
            for (int i = 0; i < 2; ++i) {
                int f = tid + i * 256;
                int r = f >> 3, c8 = (f & 7) * 8;
                *reinterpret_cast<int4*>(&Klds[br][r][c8]) =
                    *reinterpret_cast<const int4*>(&kb[(size_t)r * N_ + n0 + c8]);
            }
        }
        #pragma unroll
        for (int i = 0; i < 2; ++i) {
            int f = tid + i * 256;
            int r = f >> 4, c4 = (f & 15) * 4;
            float4 v = *reinterpret_cast<const float4*>(&xb[(size_t)r * N_ + n0 + c4]);
            short4 s;
            s.x = f2bf(v.x); s.y = f2bf(v.y); s.z = f2bf(v.z); s.w = f2bf(v.w);
            *reinterpret_cast<short4*>(&Xlds[r][c4]) = s;
        }
        __syncthreads();
        #pragma unroll
        for (int s = 0; s < 2; ++s) {
            bf16x8 b0 = *reinterpret_cast<const bf16x8*>(&Xlds[lrow][s * 32 + lkg * 8]);
            bf16x8 b1 = *reinterpret_cast<const bf16x8*>(&Xlds[16 + lrow][s * 32 + lkg * 8]);
            #pragma unroll
            for (int br = 0; br < 3; ++br) {
                bf16x8 a = *reinterpret_cast<const bf16x8*>(&Klds[br][w * 16 + lrow][s * 32 + lkg * 8]);
                acc[br][0] = __builtin_amdgcn_mfma_f32_16x16x32_bf16(a, b0, acc[br][0], 0, 0, 0);
                acc[br][1] = __builtin_amdgcn_mfma_f32_16x16x32_bf16(a, b1, acc[br][1], 0, 0, 0);
            }
        }
    }

    #pragma unroll
    for (int br = 0; br < 3; ++br) {
        float* outp = KXpart3 + (((size_t)br * NCHUNK_ + nc) * B_ + b) * M_ * C_;
        #pragma unroll
        for (int r = 0; r < 4; ++r) {
            int m = w * 16 + lkg * 4 + r;
            outp[(size_t)m * C_ + c0 + lrow]      = acc[br][0][r];
            outp[(size_t)m * C_ + c0 + 16 + lrow] = acc[br][1][r];
        }
    }
}

// ---------------------------------------------------------------------------
// Kernel 3b: reduce partials for all branches (fixed order — deterministic).
// ---------------------------------------------------------------------------
__global__ __launch_bounds__(256) void kx3_reduce(const float* __restrict__ KXpart3,
                                                  float* __restrict__ KX)
{
    const size_t BMC = (size_t)B_ * M_ * C_;
    size_t i = (size_t)blockIdx.x * 256 + threadIdx.x;
    if (i >= 3 * BMC) return;
    int br = (int)(i / BMC);
    size_t rem = i - (size_t)br * BMC;
    float s = 0.f;
    #pragma unroll
    for (int nc = 0; nc < NCHUNK_; ++nc)
        s += KXpart3[((size_t)br * NCHUNK_ + nc) * BMC + rem];
    size_t b = rem / ((size_t)M_ * C_);
    size_t mc = rem - b * (size_t)M_ * C_;
    KX[((size_t)b * 3 + br) * M_ * C_ + mc] = s;
}

// ---------------------------------------------------------------------------
// Kernel 4a (MFMA): WlWvPart[pc][c][k] = sum_{p in chunk pc} Wl[c][p]*Wv[p][k]
// ---------------------------------------------------------------------------
__global__ __launch_bounds__(256) void wlwv_mfma(const float* __restrict__ Wl,
                                                 const float* __restrict__ Wv,
                                                 float* __restrict__ part)
{
    const int k0 = blockIdx.x * 64;
    const int c0 = blockIdx.y * 64;
    const int pc = blockIdx.z;

    __shared__ short Al[64][72];
    __shared__ short Bt[64][72];

    const int tid  = threadIdx.x;
    const int lane = tid & 63;
    const int w    = tid >> 6;
    const int lrow = lane & 15;
    const int lkg  = lane >> 4;
    const int pq = tid >> 4;
    const int nq = tid & 15;

    f32x4 acc[4] = {{0.f,0.f,0.f,0.f},{0.f,0.f,0.f,0.f},{0.f,0.f,0.f,0.f},{0.f,0.f,0.f,0.f}};

    for (int it = 0; it < 2; ++it) {
        const int p0 = pc * 128 + it * 64;
        __syncthreads();
        #pragma unroll
        for (int i = 0; i < 4; ++i) {
            int f = tid + i * 256;
            int r = f >> 4, c4 = (f & 15) * 4;
            f32x4 v = *reinterpret_cast<const f32x4*>(&Wl[(size_t)(c0 + r) * C_ + p0 + c4]);
            short4 s;
            s.x = f2bf(v[0]); s.y = f2bf(v[1]); s.z = f2bf(v[2]); s.w = f2bf(v[3]);
            *reinterpret_cast<short4*>(&Al[r][c4]) = s;
        }
        f32x4 v0 = *reinterpret_cast<const f32x4*>(&Wv[(size_t)(p0 + pq * 4 + 0) * C_ + k0 + nq * 4]);
        f32x4 v1 = *reinterpret_cast<const f32x4*>(&Wv[(size_t)(p0 + pq * 4 + 1) * C_ + k0 + nq * 4]);
        f32x4 v2 = *reinterpret_cast<const f32x4*>(&Wv[(size_t)(p0 + pq * 4 + 2) * C_ + k0 + nq * 4]);
        f32x4 v3 = *reinterpret_cast<const f32x4*>(&Wv[(size_t)(p0 + pq * 4 + 3) * C_ + k0 + nq * 4]);
        #pragma unroll
        for (int c = 0; c < 4; ++c) {
            short4 s;
            s.x = f2bf(v0[c]); s.y = f2bf(v1[c]); s.z = f2bf(v2[c]); s.w = f2bf(v3[c]);
            *reinterpret_cast<short4*>(&Bt[nq * 4 + c][pq * 4]) = s;
        }
        __syncthreads();
        #pragma unroll
        for (int ks = 0; ks < 2; ++ks) {
            bf16x8 a = *reinterpret_cast<const bf16x8*>(&Al[w * 16 + lrow][ks * 32 + lkg * 8]);
            #pragma unroll
            for (int ns = 0; ns < 4; ++ns) {
                bf16x8 bx = *reinterpret_cast<const bf16x8*>(&Bt[ns * 16 + lrow][ks * 32 + lkg * 8]);
                acc[ns] = __builtin_amdgcn_mfma_f32_16x16x32_bf16(a, bx, acc[ns], 0, 0, 0);
            }
        }
    }

    float* pp = part + (size_t)pc * C_ * C_;
    #pragma unroll
    for (int r = 0; r < 4; ++r) {
        int c = c0 + w * 16 + lkg * 4 + r;
        #pragma unroll
        for (int ns = 0; ns < 4; ++ns) {
            int k = k0 + ns * 16 + lrow;
            pp[(size_t)c * C_ + k] = acc[ns][r];
        }
    }
}

// Kernel 4b: WlWv[i] = sum_pc part[pc][i]  (fixed order)
__global__ __launch_bounds__(256) void wlwv_reduce(const float* __restrict__ part,
                                                   float* __restrict__ WlWv)
{
    const size_t CC = (size_t)C_ * C_;
    size_t i = (size_t)blockIdx.x * 256 + threadIdx.x;
    if (i >= CC) return;
    float s = 0.f;
    #pragma unroll
    for (int pc = 0; pc < 4; ++pc) s += part[pc * CC + i];
    WlWv[i] = s;
}

// Wlbv[c] = sum_p Wl[c][p] * bv[p]
__global__ __launch_bounds__(256) void wlbv_kernel(const float* __restrict__ Wl,
                                                   const float* __restrict__ bv,
                                                   float* __restrict__ Wlbv)
{
    int c = blockIdx.x * 256 + threadIdx.x;
    if (c < C_) {
        float s = 0.f;
        for (int p = 0; p < C_; ++p) s = fmaf(Wl[(size_t)c * C_ + p], bv[p], s);
        Wlbv[c] = s;
    }
}

// ---------------------------------------------------------------------------
// Kernel 5 (MFMA): Wf[b][br][c][m] = sum_k WlWv[c][k]*KX[b][br][m][k]
//                                    + Ksum[b][br][m]*Wlbv[c]
// ---------------------------------------------------------------------------
__global__ __launch_bounds__(256) void wfused_mfma(const float* __restrict__ WlWv,
                                                   const float* __restrict__ KX,
                                                   const float* __restrict__ Ksum,
                                                   const float* __restrict__ Wlbv,
                                                   float* __restrict__ Wf)
{
    const int c0 = blockIdx.x * 64;
    const int br = blockIdx.y;
    const int b  = blockIdx.z;

    __shared__ short Al[64][72];   // WlWv[c][k] bf16
    __shared__ short Bl[64][72];   // KX[m][k] bf16

    const int tid  = threadIdx.x;
    const int lane = tid & 63;
    const int w    = tid >> 6;
    const int lrow = lane & 15;
    const int lkg  = lane >> 4;

    const float* kxb = KX + ((size_t)b * 3 + br) * M_ * C_;

    f32x4 acc[4] = {{0.f,0.f,0.f,0.f},{0.f,0.f,0.f,0.f},{0.f,0.f,0.f,0.f},{0.f,0.f,0.f,0.f}};

    for (int kc = 0; kc < C_ / 64; ++kc) {
        const int k0 = kc * 64;
        __syncthreads();
        #pragma unroll
        for (int i = 0; i < 4; ++i) {
            int f = tid + i * 256;
            int r = f >> 4, c4 = (f & 15) * 4;
            f32x4 v = *reinterpret_cast<const f32x4*>(&WlWv[(size_t)(c0 + r) * C_ + k0 + c4]);
            short4 s;
            s.x = f2bf(v[0]); s.y = f2bf(v[1]); s.z = f2bf(v[2]); s.w = f2bf(v[3]);
            *reinterpret_cast<short4*>(&Al[r][c4]) = s;
        }
        #pragma unroll
        for (int i = 0; i < 4; ++i) {
            int f = tid + i * 256;
            int r = f >> 4, c4 = (f & 15) * 4;
            f32x4 v = *reinterpret_cast<const f32x4*>(&kxb[(size_t)r * C_ + k0 + c4]);
            short4 s;
            s.x = f2bf(v[0]); s.y = f2bf(v[1]); s.z = f2bf(v[2]); s.w = f2bf(v[3]);
            *reinterpret_cast<short4*>(&Bl[r][c4]) = s;
        }
        __syncthreads();
        #pragma unroll
        for (int ks = 0; ks < 2; ++ks) {
            bf16x8 a = *reinterpret_cast<const bf16x8*>(&Al[w * 16 + lrow][ks * 32 + lkg * 8]);
            #pragma unroll
            for (int ns = 0; ns < 4; ++ns) {
                bf16x8 bx = *reinterpret_cast<const bf16x8*>(&Bl[ns * 16 + lrow][ks * 32 + lkg * 8]);
                acc[ns] = __builtin_amdgcn_mfma_f32_16x16x32_bf16(a, bx, acc[ns], 0, 0, 0);
            }
        }
    }

    const float* ks_ = Ksum + ((size_t)b * 3 + br) * M_;
    float* wfb = Wf + (((size_t)b * 3 + br) * C_) * M_;
    #pragma unroll
    for (int r = 0; r < 4; ++r) {
        int c = c0 + w * 16 + lkg * 4 + r;
        float wb = Wlbv[c];
        #pragma unroll
        for (int ns = 0; ns < 4; ++ns) {
            int m = ns * 16 + lrow;
            wfb[(size_t)c * M_ + m] = acc[ns][r] + ks_[m] * wb;
        }
    }
}

// ---------------------------------------------------------------------------
// Kernel 6 (MFMA): out = x + gamma*(bl + sum_br norm_br * (Wf_br @ QT^T)).
// ---------------------------------------------------------------------------
__global__ __launch_bounds__(256) void final_mfma_kernel(
    const short* __restrict__ QT, const float* __restrict__ Wf,
    const float* __restrict__ Ksum, const float* __restrict__ x,
    const float* __restrict__ bl, const float* __restrict__ gamma,
    float* __restrict__ out)
{
    const int n0 = blockIdx.x * 64;
    const int c0 = blockIdx.y * 64;
    const int b  = blockIdx.z;

    __shared__ short Qs[64][72];      // [n][m] bf16
    __shared__ short Wfs[3][64][72];  // [br][c][m] bf16
    __shared__ float norms[3][64];
    __shared__ float ksef[3][64];

    const int tid  = threadIdx.x;
    const int lane = tid & 63;
    const int w    = tid >> 6;
    const int lrow = lane & 15;
    const int lkg  = lane >> 4;

    const short* qtb = QT + (size_t)b * N_ * M_;
    #pragma unroll
    for (int i = 0; i < 2; ++i) {
        int f = tid + i * 256;
        int r = f >> 3, m8 = (f & 7) * 8;
        *reinterpret_cast<int4*>(&Qs[r][m8]) =
            *reinterpret_cast<const int4*>(&qtb[(size_t)(n0 + r) * M_ + m8]);
    }
    #pragma unroll
    for (int br = 0; br < 3; ++br) {
        const float* wfb = Wf + (((size_t)b * 3 + br) * C_ + c0) * M_;
        #pragma unroll
        for (int i = 0; i < 4; ++i) {
            int f = tid + i * 256;
            int r = f >> 4, m4 = (f & 15) * 4;
            float4 v = *reinterpret_cast<const float4*>(&wfb[(size_t)r * M_ + m4]);
            short4 s;
            s.x = f2bf(v.x); s.y = f2bf(v.y); s.z = f2bf(v.z); s.w = f2bf(v.w);
            *reinterpret_cast<short4*>(&Wfs[br][r][m4]) = s;
        }
    }
    if (tid < 192) {
        int br = tid >> 6, m = tid & 63;
        ksef[br][m] = Ksum[((size_t)b * 3 + br) * M_ + m] + EPS_;
    }
    __syncthreads();
    if (tid < 192) {
        int br = tid >> 6, n = tid & 63;
        float s = 0.f;
        #pragma unroll 16
        for (int m = 0; m < 64; ++m) s = fmaf(bf2f(Qs[n][m]), ksef[br][m], s);
        norms[br][n] = 1.0f / s;
    }
    __syncthreads();

    f32x4 tot[4] = {{0.f,0.f,0.f,0.f},{0.f,0.f,0.f,0.f},{0.f,0.f,0.f,0.f},{0.f,0.f,0.f,0.f}};
    for (int br = 0; br < 3; ++br) {
        f32x4 acc[4] = {{0.f,0.f,0.f,0.f},{0.f,0.f,0.f,0.f},{0.f,0.f,0.f,0.f},{0.f,0.f,0.f,0.f}};
        #pragma unroll
        for (int ks = 0; ks < 2; ++ks) {
            bf16x8 a = *reinterpret_cast<const bf16x8*>(&Wfs[br][w * 16 + lrow][ks * 32 + lkg * 8]);
            #pragma unroll
            for (int ns = 0; ns < 4; ++ns) {
                bf16x8 bq = *reinterpret_cast<const bf16x8*>(&Qs[ns * 16 + lrow][ks * 32 + lkg * 8]);
                acc[ns] = __builtin_amdgcn_mfma_f32_16x16x32_bf16(a, bq, acc[ns], 0, 0, 0);
            }
        }
        #pragma unroll
        for (int ns = 0; ns < 4; ++ns) {
            float nf = norms[br][ns * 16 + lrow];
            #pragma unroll
            for (int r = 0; r < 4; ++r) tot[ns][r] = fmaf(nf, acc[ns][r], tot[ns][r]);
        }
    }

    const float g = gamma[0];
    const float* xb = x + (size_t)b * C_ * N_;
    float* ob = out + (size_t)b * C_ * N_;
    #pragma unroll
    for (int r = 0; r < 4; ++r) {
        int c = c0 + w * 16 + lkg * 4 + r;
        float blc = bl[c];
        #pragma unroll
        for (int ns = 0; ns < 4; ++ns) {
            int n = n0 + ns * 16 + lrow;
            ob[(size_t)c * N_ + n] = fmaf(g, tot[ns][r] + blc, xb[(size_t)c * N_ + n]);
        }
    }
}

// ---------------------------------------------------------------------------
extern "C" void kernel_launch(void* const* d_in, const int* in_sizes, int n_in,
                              void* d_out, int out_size, void* d_ws, size_t ws_size,
                              hipStream_t stream)
{
    const float* x   = (const float*)d_in[0];
    const float* y   = (const float*)d_in[1];
    const float* z   = (const float*)d_in[2];
    const float* Wq  = (const float*)d_in[3];
    const float* bq  = (const float*)d_in[4];
    const float* Wk1 = (const float*)d_in[5];
    const float* bk1 = (const float*)d_in[6];
    const float* Wk2 = (const float*)d_in[7];
    const float* bk2 = (const float*)d_in[8];
    const float* Wk3 = (const float*)d_in[9];
    const float* bk3 = (const float*)d_in[10];
    const float* Wv  = (const float*)d_in[11];
    const float* bv  = (const float*)d_in[12];
    const float* Wl  = (const float*)d_in[13];
    const float* bl  = (const float*)d_in[14];
    const float* gamma = (const float*)d_in[15];
    float* out = (float*)d_out;

    // workspace layout (~35 MB of the 256 MiB d_ws).
    float* ws = (float*)d_ws;
    const size_t QSZ  = (size_t)B_ * M_ * N_;        // 2,097,152 elements
    const size_t BMC  = (size_t)B_ * M_ * C_;        //   262,144
    short* QTs   = (short*)ws;                        // [B][N][M] bf16
    short* Kbuf3 = QTs + QSZ;                         // [3][B][M][N] bf16 (12 MB)
    float* fbase = ws + 2 * QSZ;                      // float region
    float* KX    = fbase;                             // [B][3][M][C]
    float* Ksum  = KX + 3 * BMC;                      // [B][3][M]
    float* WlWv  = Ksum + (size_t)B_ * 3 * M_;        // [C][C]
    float* Wlbv  = WlWv + (size_t)C_ * C_;            // [C]
    float* Ksumpart = Wlbv + C_;                      // [3][B][64][M]
    float* KXpart3  = Ksumpart + (size_t)3 * B_ * 64 * M_;  // [3][4][B][M][C] (12MB)
    float* WlWvPart = KXpart3;                        // alias (4MB, dead before wlwv)
    float* Wf   = KXpart3;                            // alias (3MB, after kx3_reduce)
    short* Wbf  = (short*)(KXpart3 + (size_t)3 * NCHUNK_ * BMC);  // [4][M][C] bf16

    dim3 blk(256);

    // 0) one-time bf16 conversion of the 4 feature weight matrices
    prep_w<<<dim3((M_ * C_ + 255) / 256), blk, 0, stream>>>(Wq, Wk1, Wk2, Wk3, Wbf);
    // 1) feature GEMMs: y=0 computes Q+K1 off one x staging; y=1,2 -> K2,K3
    feat_mfma<<<dim3(N_ / 64, 3, B_), blk, 0, stream>>>(
        x, y, z, Wbf, bq, bk1, bk2, bk3, QTs, Kbuf3, Ksumpart);
    // 2) finalize ksum for all branches
    ksum_finalize<<<dim3((3 * B_ * M_ + 255) / 256), blk, 0, stream>>>(Ksumpart, Ksum);
    // 3) KX for all branches in one pass (x staged once per tile)
    kx3_mfma<<<dim3(C_ / 32, NCHUNK_, B_), blk, 0, stream>>>(Kbuf3, x, KXpart3);
    kx3_reduce<<<dim3((int)((3 * BMC + 255) / 256)), blk, 0, stream>>>(KXpart3, KX);

    // 4) batch-independent fused weights (partials alias KXpart3 — after kx3_reduce)
    wlwv_mfma<<<dim3(C_ / 64, C_ / 64, 4), blk, 0, stream>>>(Wl, Wv, WlWvPart);
    wlwv_reduce<<<dim3(((int)((size_t)C_ * C_) + 255) / 256), blk, 0, stream>>>(WlWvPart, WlWv);
    wlbv_kernel<<<dim3((C_ + 255) / 256), blk, 0, stream>>>(Wl, bv, Wlbv);
    // 5) per-batch fused weights
    wfused_mfma<<<dim3(C_ / 64, 3, B_), blk, 0, stream>>>(WlWv, KX, Ksum, Wlbv, Wf);
    // 6) final: norms + MFMA GEMM + bias + residual
    final_mfma_kernel<<<dim3(N_ / 64, C_ / 64, B_), blk, 0, stream>>>(
        QTs, Wf, Ksum, x, bl, gamma, out);
}